// Round 2
// baseline (1640.333 us; speedup 1.0000x reference)
//
#include <hip/hip_runtime.h>

#define N_NODES  100000
#define N_EDGES  1600000
#define N_GRAPHS 128

typedef unsigned short u16;
typedef unsigned int   u32;
typedef __attribute__((ext_vector_type(8))) short short8;
typedef __attribute__((ext_vector_type(4))) float f32x4;

__device__ __forceinline__ float bf2f(u16 v) {
  union { u32 i; float f; } u; u.i = ((u32)v) << 16; return u.f;
}
__device__ __forceinline__ u16 f2bf(float f) {
  union { float f; u32 i; } u; u.f = f;
  u32 r = (u.i + 0x7fffu + ((u.i >> 16) & 1u)) >> 16;
  return (u16)r;
}
__device__ __forceinline__ float sigmoid_f(float x) { return 1.f / (1.f + __expf(-x)); }
__device__ __forceinline__ float tanh_f(float x) {
  x = fminf(15.f, fmaxf(-15.f, x));
  float e = __expf(2.f * x);
  return (e - 1.f) / (e + 1.f);
}

// Integer load honoring runtime int64/int32 layout (int64 little-endian: value in low word)
__device__ __forceinline__ int geti(const int* __restrict__ p, int i, int is64) {
  return p[is64 ? (2 * i) : i];
}

// Detect whether edge_index / batch are int64 (all sampled odd words == 0) or int32.
__global__ void detect_i64_kernel(const int* __restrict__ ei, const int* __restrict__ batch,
                                  int* __restrict__ flags) {
  int lane = threadIdx.x;  // 64
  {
    long long q = (long long)lane * (3200000 / 2 - 1) / 63;
    int pos = (int)(2 * q + 1);           // odd word index, always in-bounds for both layouts
    unsigned long long m = __ballot(ei[pos] != 0);
    if (lane == 0) flags[0] = (m == 0ull) ? 1 : 0;
  }
  {
    long long q = (long long)lane * (100000 / 2 - 1) / 63;
    int pos = (int)(2 * q + 1);
    unsigned long long m = __ballot(batch[pos] != 0);
    if (lane == 0) flags[1] = (m == 0ull) ? 1 : 0;
  }
}

// ---------------- CSR build ----------------
__global__ void hist_kernel(const int* __restrict__ ei, const int* __restrict__ flags,
                            int* __restrict__ counts) {
  int e = blockIdx.x * 256 + threadIdx.x;
  if (e < N_EDGES) {
    int f = flags[0];
    atomicAdd(&counts[geti(ei, N_EDGES + e, f)], 1);
  }
}

__global__ __launch_bounds__(1024)
void scan_kernel(const int* __restrict__ counts, int* __restrict__ offsets) {
  __shared__ int buf[1024];
  const int t = threadIdx.x;
  const int CH = (N_NODES + 1023) / 1024;  // 98
  const int base = t * CH;
  int s = 0;
  for (int i = 0; i < CH; ++i) { int idx = base + i; if (idx < N_NODES) s += counts[idx]; }
  buf[t] = s;
  __syncthreads();
  for (int off = 1; off < 1024; off <<= 1) {
    int add = (t >= off) ? buf[t - off] : 0;
    __syncthreads();
    buf[t] += add;
    __syncthreads();
  }
  int run = (t > 0) ? buf[t - 1] : 0;   // exclusive prefix
  for (int i = 0; i < CH; ++i) {
    int idx = base + i;
    if (idx < N_NODES) { offsets[idx] = run; run += counts[idx]; }
  }
  if (t == 1023) offsets[N_NODES] = buf[1023];
}

__global__ void scatter_kernel(const int* __restrict__ ei, const int* __restrict__ flags,
                               const int* __restrict__ offsets,
                               int* __restrict__ cursor, int* __restrict__ ssrc) {
  int e = blockIdx.x * 256 + threadIdx.x;
  if (e < N_EDGES) {
    int f = flags[0];
    int d = geti(ei, N_EDGES + e, f);
    int pos = offsets[d] + atomicAdd(&cursor[d], 1);
    ssrc[pos] = geti(ei, e, f);
  }
}

// ---------------- weight / input prep (f32 -> bf16) ----------------
__global__ void convert_kernel(const float* __restrict__ in, u16* __restrict__ out, int n) {
  int i = blockIdx.x * 256 + threadIdx.x;
  if (i < n) out[i] = f2bf(in[i]);
}

// in f32 [K][N] row-major -> out bf16 [N][K]
__global__ void transpose_kernel(const float* __restrict__ in, u16* __restrict__ out, int K, int N) {
  int i = blockIdx.x * 256 + threadIdx.x;
  if (i < K * N) {
    int k = i / N, n = i % N;
    out[n * K + k] = f2bf(in[i]);
  }
}

// Fused GRU weight B2^T [512][256] (bf16):
// cols 0..127: ir+hr | 128..255: iz+hz | 256..383: in (k<128) | 384..511: hn (k>=128)
__global__ void build_b2t_kernel(const float* __restrict__ w_ih, const float* __restrict__ w_hh,
                                 u16* __restrict__ b2t) {
  int i = blockIdx.x * 256 + threadIdx.x;  // i = c*256 + k
  if (i >= 512 * 256) return;
  int c = i >> 8, k = i & 255;
  float v = 0.f;
  if (c < 256)      v = (k < 128) ? w_ih[k * 384 + c] : w_hh[(k - 128) * 384 + c];
  else if (c < 384) v = (k < 128) ? w_ih[k * 384 + c] : 0.f;
  else              v = (k < 128) ? 0.f : w_hh[(k - 128) * 384 + (c - 128)];
  b2t[i] = f2bf(v);
}

// ---------------- MFMA GEMM ----------------
// C[M][N] = A[M][K] @ B[K][N]. A, BT are bf16; BT pre-transposed [N][K]; bias f32.
// EPI 0: +bias, relu, bf16 out.  EPI 1: plain, bf16 out.
// EPI 2: GRU epilogue; A=agg (k<128), Ah=h (k>=128); writes h_new IN PLACE over Ah.
template<int K_DIM, int N_DIM, int EPI>
__global__ __launch_bounds__(256)
void gemm_mfma(const u16* __restrict__ A, const u16* __restrict__ Ah,
               const u16* __restrict__ BT, const float* __restrict__ bias,
               const float* __restrict__ bias2, u16* __restrict__ out, int M)
{
  constexpr int NT = N_DIM / 16;
  constexpr int NCHUNK = K_DIM / 32;
  __shared__ u16 B_lds[N_DIM * 40];  // [n][32 k + 8 pad] -> 2-way bank alias only (free)

  const int tid  = threadIdx.x;
  const int lane = tid & 63;
  const int w    = tid >> 6;
  const int strip = blockIdx.x * 64;
  const int ksub = (lane >> 4) * 8;

  union Frag { uint4 u; short8 s; };
  Frag af[NCHUNK];
  const int m_node = strip + w * 16 + (lane & 15);
  const bool avalid = (m_node < M);
#pragma unroll
  for (int ci = 0; ci < NCHUNK; ++ci) {
    int k0 = ci * 32 + ksub;
    uint4 v; v.x = v.y = v.z = v.w = 0u;
    if (avalid) {
      const u16* p;
      if (EPI == 2) p = (k0 < 128) ? (A + (size_t)m_node * 128 + k0)
                                   : (Ah + (size_t)m_node * 128 + (k0 - 128));
      else          p = A + (size_t)m_node * K_DIM + k0;
      v = *(const uint4*)p;
    }
    af[ci].u = v;
  }
  // In-place (EPI 2): guarantee every thread's A/Ah loads completed before any
  // thread in the block can reach its epilogue stores.
  asm volatile("s_waitcnt vmcnt(0)" ::: "memory");
  __syncthreads();

  f32x4 acc[NT];
#pragma unroll
  for (int t = 0; t < NT; ++t) acc[t] = {0.f, 0.f, 0.f, 0.f};

  const int boff = (lane & 15) * 40 + ksub;

  for (int ci = 0; ci < NCHUNK; ++ci) {
    if (ci) __syncthreads();
    for (int g = tid; g < N_DIM * 4; g += 256) {   // stage BT chunk, 16B copies
      int n = g >> 2, ko = g & 3;
      uint4 bv = *(const uint4*)(BT + (size_t)n * K_DIM + ci * 32 + ko * 8);
      *(uint4*)(&B_lds[n * 40 + ko * 8]) = bv;
    }
    __syncthreads();
    short8 a = af[ci].s;
#pragma unroll
    for (int t = 0; t < NT; ++t) {
      const short8 b = *(const short8*)(&B_lds[t * 16 * 40 + boff]);
      acc[t] = __builtin_amdgcn_mfma_f32_16x16x32_bf16(a, b, acc[t], 0, 0, 0);
    }
  }

  const int mrow = (lane >> 4) * 4;
  if (EPI == 2) {
#pragma unroll
    for (int t = 0; t < 8; ++t) {
      int c = t * 16 + (lane & 15);
      float b_r  = bias[c]       + bias2[c];
      float b_z  = bias[128 + c] + bias2[128 + c];
      float b_in = bias[256 + c];
      float b_hn = bias2[256 + c];
#pragma unroll
      for (int r = 0; r < 4; ++r) {
        int node = strip + w * 16 + mrow + r;
        if (node < M) {
          float rg = sigmoid_f(acc[t][r] + b_r);
          float zg = sigmoid_f(acc[t + 8][r] + b_z);
          float hn = acc[t + 24][r] + b_hn;
          float ng = tanh_f(acc[t + 16][r] + b_in + rg * hn);
          float hp = bf2f(Ah[(size_t)node * 128 + c]);
          out[(size_t)node * 128 + c] = f2bf((1.f - zg) * ng + zg * hp);
        }
      }
    }
  } else {
#pragma unroll
    for (int t = 0; t < NT; ++t) {
      int col = t * 16 + (lane & 15);
      float bv = bias ? bias[col] : 0.f;
#pragma unroll
      for (int r = 0; r < 4; ++r) {
        int node = strip + w * 16 + mrow + r;
        if (node < M) {
          float v = acc[t][r] + bv;
          if (EPI == 0) v = fmaxf(v, 0.f);
          out[(size_t)node * N_DIM + col] = f2bf(v);
        }
      }
    }
  }
}

// ---------------- CSR aggregation: agg[n] = sum over in-edges of m[src] ----------------
__global__ __launch_bounds__(256)
void agg_kernel(const u16* __restrict__ m, const int* __restrict__ ssrc,
                const int* __restrict__ offsets, u16* __restrict__ agg)
{
  int node = blockIdx.x * 4 + (threadIdx.x >> 6);
  int lane = threadIdx.x & 63;
  if (node >= N_NODES) return;
  int beg = offsets[node], end = offsets[node + 1];
  float s0 = 0.f, s1 = 0.f;
  for (int e = beg; e < end; ++e) {
    int src = ssrc[e];
    u32 v = *(const u32*)(m + (size_t)src * 128 + lane * 2);  // coalesced 256B/row per wave
    s0 += bf2f((u16)(v & 0xffffu));
    s1 += bf2f((u16)(v >> 16));
  }
  u32 packed = (u32)f2bf(s0) | ((u32)f2bf(s1) << 16);
  *(u32*)(agg + (size_t)node * 128 + lane * 2) = packed;
}

// ---------------- pooling + doc + LN + fusion + heads, all f32 (one block per graph) ----------------
__global__ __launch_bounds__(256)
void head_kernel(const u16* __restrict__ h, const int* __restrict__ batch,
                 const int* __restrict__ flags,
                 const float* __restrict__ doc, const float* __restrict__ doc_w, const float* __restrict__ doc_b,
                 const float* __restrict__ ln_g, const float* __restrict__ ln_b,
                 const float* __restrict__ fus_w, const float* __restrict__ fus_b,
                 const float* __restrict__ task_w, const float* __restrict__ task_b,
                 const float* __restrict__ time_w, const float* __restrict__ time_b,
                 float* __restrict__ out_task, float* __restrict__ out_time)
{
  const int g = blockIdx.x;
  const int t = threadIdx.x;
  __shared__ float fusion[256];
  __shared__ float fh[128];
  __shared__ int seg[2];

  if (t < 2) {  // lower_bound(batch, g) / lower_bound(batch, g+1)
    int f = flags[1];
    int target = g + t, lo = 0, hi = N_NODES;
    while (lo < hi) { int mid = (lo + hi) >> 1; if (geti(batch, mid, f) < target) lo = mid + 1; else hi = mid; }
    seg[t] = lo;
  }
  __syncthreads();
  const int beg = seg[0], end = seg[1];

  if (t < 128) {  // mean-pool column t
    float s = 0.f;
    for (int n = beg; n < end; ++n) s += bf2f(h[(size_t)n * 128 + t]);
    float cnt = (float)(end - beg);
    fusion[t] = s / fmaxf(cnt, 1.f);
  } else {        // doc_emb column t-128, full f32
    int c = t - 128;
    float s = 0.f;
    for (int k = 0; k < 768; ++k) s += doc[g * 768 + k] * doc_w[k * 128 + c];
    s += doc_b[c];
    fusion[t] = fmaxf(s, 0.f);
  }
  __syncthreads();

  float mu = 0.f;
  for (int i = 0; i < 256; ++i) mu += fusion[i];
  mu *= (1.f / 256.f);
  float var = 0.f;
  for (int i = 0; i < 256; ++i) { float d = fusion[i] - mu; var += d * d; }
  var *= (1.f / 256.f);
  float inv = rsqrtf(var + 1e-5f);
  float norm = (fusion[t] - mu) * inv * ln_g[t] + ln_b[t];
  __syncthreads();
  fusion[t] = norm;
  __syncthreads();

  if (t < 128) {
    float s = 0.f;
    for (int k = 0; k < 256; ++k) s += fusion[k] * fus_w[k * 128 + t];
    s += fus_b[t];
    fh[t] = fmaxf(s, 0.f);
  }
  __syncthreads();

  if (t < 32) {
    float s = 0.f;
    for (int k = 0; k < 128; ++k) s += fh[k] * task_w[k * 32 + t];
    s += task_b[t];
    out_task[g * 32 + t] = s;
  }
  if (t == 32) {
    float s = 0.f;
    for (int k = 0; k < 128; ++k) s += fh[k] * time_w[k];
    s += time_b[0];
    out_time[g] = s;
  }
}

// ---------------- launch ----------------
extern "C" void kernel_launch(void* const* d_in, const int* in_sizes, int n_in,
                              void* d_out, int out_size, void* d_ws, size_t ws_size,
                              hipStream_t stream)
{
  const float* x        = (const float*)d_in[0];
  const float* doc      = (const float*)d_in[1];
  const int*   ei       = (const int*)d_in[2];
  const int*   batch    = (const int*)d_in[3];
  const float* node_w   = (const float*)d_in[4];
  const float* node_b   = (const float*)d_in[5];
  const float* ggnn_w   = (const float*)d_in[6];
  const float* gru_w_ih = (const float*)d_in[7];
  const float* gru_b_ih = (const float*)d_in[8];
  const float* gru_w_hh = (const float*)d_in[9];
  const float* gru_b_hh = (const float*)d_in[10];
  const float* doc_w    = (const float*)d_in[11];
  const float* doc_b    = (const float*)d_in[12];
  const float* ln_g     = (const float*)d_in[13];
  const float* ln_b     = (const float*)d_in[14];
  const float* fus_w    = (const float*)d_in[15];
  const float* fus_b    = (const float*)d_in[16];
  const float* task_w   = (const float*)d_in[17];
  const float* task_b   = (const float*)d_in[18];
  const float* time_w   = (const float*)d_in[19];
  const float* time_b   = (const float*)d_in[20];

  char* ws = (char*)d_ws;
  size_t off = 0;
  auto alloc = [&](size_t bytes) -> void* {
    void* p = ws + off;
    off = (off + bytes + 255) & ~(size_t)255;
    return p;
  };
  u16* aggb   = (u16*)alloc((size_t)N_NODES * 128 * 2);  // xb aliases this region
  u16* xb     = aggb;                                     // [N][64] bf16, dead before first agg
  u16* hA     = (u16*)alloc((size_t)N_NODES * 128 * 2);
  u16* mbuf   = (u16*)alloc((size_t)N_NODES * 128 * 2);
  u16* nwT    = (u16*)alloc(64 * 128 * 2);
  u16* gwT    = (u16*)alloc(3 * 128 * 128 * 2);
  u16* b2T    = (u16*)alloc(512 * 256 * 2);
  int* counts = (int*)alloc((size_t)N_NODES * 4);
  int* cursor = (int*)alloc((size_t)N_NODES * 4);
  int* offs   = (int*)alloc((size_t)(N_NODES + 1) * 4);
  int* ssrc   = (int*)alloc((size_t)N_EDGES * 4);
  int* flags  = (int*)alloc(2 * 4);

  hipMemsetAsync(counts, 0, (size_t)N_NODES * 4, stream);
  hipMemsetAsync(cursor, 0, (size_t)N_NODES * 4, stream);

  detect_i64_kernel<<<1, 64, 0, stream>>>(ei, batch, flags);
  hist_kernel<<<(N_EDGES + 255) / 256, 256, 0, stream>>>(ei, flags, counts);
  scan_kernel<<<1, 1024, 0, stream>>>(counts, offs);
  scatter_kernel<<<(N_EDGES + 255) / 256, 256, 0, stream>>>(ei, flags, offs, cursor, ssrc);

  convert_kernel<<<(N_NODES * 64 + 255) / 256, 256, 0, stream>>>(x, xb, N_NODES * 64);
  transpose_kernel<<<(64 * 128 + 255) / 256, 256, 0, stream>>>(node_w, nwT, 64, 128);
  for (int l = 0; l < 3; ++l)
    transpose_kernel<<<(128 * 128 + 255) / 256, 256, 0, stream>>>(ggnn_w + l * 128 * 128,
                                                                  gwT + l * 128 * 128, 128, 128);
  build_b2t_kernel<<<512, 256, 0, stream>>>(gru_w_ih, gru_w_hh, b2T);

  const int GB = (N_NODES + 63) / 64;  // 1563
  gemm_mfma<64, 128, 0><<<GB, 256, 0, stream>>>(xb, nullptr, nwT, node_b, nullptr, hA, N_NODES);

  for (int l = 0; l < 3; ++l) {
    gemm_mfma<128, 128, 1><<<GB, 256, 0, stream>>>(hA, nullptr, gwT + l * 128 * 128,
                                                   nullptr, nullptr, mbuf, N_NODES);
    agg_kernel<<<(N_NODES + 3) / 4, 256, 0, stream>>>(mbuf, ssrc, offs, aggb);
    gemm_mfma<256, 512, 2><<<GB, 256, 0, stream>>>(aggb, hA, b2T, gru_b_ih, gru_b_hh,
                                                   hA, N_NODES);  // in-place h update
  }

  float* out_task = (float*)d_out;
  float* out_time = out_task + N_GRAPHS * 32;
  head_kernel<<<N_GRAPHS, 256, 0, stream>>>(hA, batch, flags, doc, doc_w, doc_b, ln_g, ln_b,
                                            fus_w, fus_b, task_w, task_b, time_w, time_b,
                                            out_task, out_time);
}

// Round 3
// 1448.606 us; speedup vs baseline: 1.1324x; 1.1324x over previous
//
#include <hip/hip_runtime.h>

#define N_NODES  100000
#define N_EDGES  1600000
#define N_GRAPHS 128

typedef unsigned short u16;
typedef unsigned int   u32;
typedef __attribute__((ext_vector_type(8))) short short8;
typedef __attribute__((ext_vector_type(4))) float f32x4;

__device__ __forceinline__ float bf2f(u16 v) {
  union { u32 i; float f; } u; u.i = ((u32)v) << 16; return u.f;
}
__device__ __forceinline__ u16 f2bf(float f) {
  union { float f; u32 i; } u; u.f = f;
  u32 r = (u.i + 0x7fffu + ((u.i >> 16) & 1u)) >> 16;
  return (u16)r;
}
__device__ __forceinline__ float sigmoid_f(float x) { return 1.f / (1.f + __expf(-x)); }
__device__ __forceinline__ float tanh_f(float x) {
  x = fminf(15.f, fmaxf(-15.f, x));
  float e = __expf(2.f * x);
  return (e - 1.f) / (e + 1.f);
}

// Integer load honoring runtime int64/int32 layout (int64 little-endian: value in low word)
__device__ __forceinline__ int geti(const int* __restrict__ p, int i, int is64) {
  return p[is64 ? (2 * i) : i];
}

// Detect whether edge_index / batch are int64 (all sampled odd words == 0) or int32.
__global__ void detect_i64_kernel(const int* __restrict__ ei, const int* __restrict__ batch,
                                  int* __restrict__ flags) {
  int lane = threadIdx.x;  // 64
  {
    long long q = (long long)lane * (3200000 / 2 - 1) / 63;
    int pos = (int)(2 * q + 1);
    unsigned long long m = __ballot(ei[pos] != 0);
    if (lane == 0) flags[0] = (m == 0ull) ? 1 : 0;
  }
  {
    long long q = (long long)lane * (100000 / 2 - 1) / 63;
    int pos = (int)(2 * q + 1);
    unsigned long long m = __ballot(batch[pos] != 0);
    if (lane == 0) flags[1] = (m == 0ull) ? 1 : 0;
  }
}

// ---------------- CSR build ----------------
__global__ void hist_kernel(const int* __restrict__ ei, const int* __restrict__ flags,
                            int* __restrict__ counts) {
  int e = blockIdx.x * 256 + threadIdx.x;
  if (e < N_EDGES) {
    int f = flags[0];
    atomicAdd(&counts[geti(ei, N_EDGES + e, f)], 1);
  }
}

__global__ __launch_bounds__(1024)
void scan_kernel(const int* __restrict__ counts, int* __restrict__ offsets) {
  __shared__ int buf[1024];
  const int t = threadIdx.x;
  const int CH = (N_NODES + 1023) / 1024;  // 98
  const int base = t * CH;
  int s = 0;
  for (int i = 0; i < CH; ++i) { int idx = base + i; if (idx < N_NODES) s += counts[idx]; }
  buf[t] = s;
  __syncthreads();
  for (int off = 1; off < 1024; off <<= 1) {
    int add = (t >= off) ? buf[t - off] : 0;
    __syncthreads();
    buf[t] += add;
    __syncthreads();
  }
  int run = (t > 0) ? buf[t - 1] : 0;   // exclusive prefix
  for (int i = 0; i < CH; ++i) {
    int idx = base + i;
    if (idx < N_NODES) { offsets[idx] = run; run += counts[idx]; }
  }
  if (t == 1023) offsets[N_NODES] = buf[1023];
}

__global__ void scatter_kernel(const int* __restrict__ ei, const int* __restrict__ flags,
                               const int* __restrict__ offsets,
                               int* __restrict__ cursor, int* __restrict__ ssrc) {
  int e = blockIdx.x * 256 + threadIdx.x;
  if (e < N_EDGES) {
    int f = flags[0];
    int d = geti(ei, N_EDGES + e, f);
    int pos = offsets[d] + atomicAdd(&cursor[d], 1);
    ssrc[pos] = geti(ei, e, f);
  }
}

// ---------------- weight / input prep ----------------
__global__ void convert_kernel(const float* __restrict__ in, u16* __restrict__ out, int n) {
  int i = blockIdx.x * 256 + threadIdx.x;
  if (i < n) out[i] = f2bf(in[i]);
}

// f32 [K][N] row-major -> bf16 [N][K]
__global__ void transpose_kernel(const float* __restrict__ in, u16* __restrict__ out, int K, int N) {
  int i = blockIdx.x * 256 + threadIdx.x;
  if (i < K * N) {
    int k = i / N, n = i % N;
    out[n * K + k] = f2bf(in[i]);
  }
}

// W'_l[k][c] = sum_j ggnn_w[l][k][j] * w_ih[j][c]   (f32, [3][128][384])
// segment_sum commutes with the linear map, so agg(h@W)@w_ih == agg(h)@(W@w_ih).
__global__ void wprime_kernel(const float* __restrict__ ggnn_w, const float* __restrict__ w_ih,
                              float* __restrict__ wp) {
  int i = blockIdx.x * 256 + threadIdx.x;  // l*128*384 + k*384 + c
  if (i >= 3 * 128 * 384) return;
  int l = i / (128 * 384), r = i % (128 * 384), k = r / 384, c = r % 384;
  const float* W = ggnn_w + l * 128 * 128;
  float s = 0.f;
  for (int j = 0; j < 128; ++j) s += W[k * 128 + j] * w_ih[j * 384 + c];
  wp[i] = s;
}

// Fused GRU weight B2^T [512][256] (bf16) for one layer, built from W' (f32) + w_hh:
// cols 0..127: r | 128..255: z | 256..383: in (k<128 only) | 384..511: hn (k>=128 only)
__global__ void build_b2t_kernel(const float* __restrict__ wp, const float* __restrict__ w_hh,
                                 u16* __restrict__ b2t) {
  int i = blockIdx.x * 256 + threadIdx.x;  // i = c*256 + k
  if (i >= 512 * 256) return;
  int c = i >> 8, k = i & 255;
  float v = 0.f;
  if (c < 384) v = (k < 128) ? wp[k * 384 + c] : ((c < 256) ? w_hh[(k - 128) * 384 + c] : 0.f);
  else         v = (k < 128) ? 0.f : w_hh[(k - 128) * 384 + (c - 128)];
  b2t[i] = f2bf(v);
}

// ---------------- MFMA GEMM ----------------
// EPI 0: +bias, relu, bf16 out.  EPI 2: GRU epilogue; A=aggH (k<128), Ah=h (k>=128),
// writes h_new IN PLACE over Ah (per-wave row ownership makes this race-free).
template<int K_DIM, int N_DIM, int EPI>
__global__ __launch_bounds__(256)
void gemm_mfma(const u16* __restrict__ A, const u16* __restrict__ Ah,
               const u16* __restrict__ BT, const float* __restrict__ bias,
               const float* __restrict__ bias2, u16* __restrict__ out, int M)
{
  constexpr int NT = N_DIM / 16;
  constexpr int NCHUNK = K_DIM / 32;
  __shared__ u16 B_lds[N_DIM * 40];  // [n][32 k + 8 pad] -> 2-way bank alias only (free)

  const int tid  = threadIdx.x;
  const int lane = tid & 63;
  const int w    = tid >> 6;
  const int strip = blockIdx.x * 64;
  const int ksub = (lane >> 4) * 8;

  union Frag { uint4 u; short8 s; };
  Frag af[NCHUNK];
  const int m_node = strip + w * 16 + (lane & 15);
  const bool avalid = (m_node < M);
#pragma unroll
  for (int ci = 0; ci < NCHUNK; ++ci) {
    int k0 = ci * 32 + ksub;
    uint4 v; v.x = v.y = v.z = v.w = 0u;
    if (avalid) {
      const u16* p;
      if (EPI == 2) p = (k0 < 128) ? (A + (size_t)m_node * 128 + k0)
                                   : (Ah + (size_t)m_node * 128 + (k0 - 128));
      else          p = A + (size_t)m_node * K_DIM + k0;
      v = *(const uint4*)p;
    }
    af[ci].u = v;
  }
  asm volatile("s_waitcnt vmcnt(0)" ::: "memory");
  __syncthreads();

  f32x4 acc[NT];
#pragma unroll
  for (int t = 0; t < NT; ++t) acc[t] = {0.f, 0.f, 0.f, 0.f};

  const int boff = (lane & 15) * 40 + ksub;

  for (int ci = 0; ci < NCHUNK; ++ci) {
    if (ci) __syncthreads();
    for (int g = tid; g < N_DIM * 4; g += 256) {   // stage BT chunk, 16B copies
      int n = g >> 2, ko = g & 3;
      uint4 bv = *(const uint4*)(BT + (size_t)n * K_DIM + ci * 32 + ko * 8);
      *(uint4*)(&B_lds[n * 40 + ko * 8]) = bv;
    }
    __syncthreads();
    short8 a = af[ci].s;
#pragma unroll
    for (int t = 0; t < NT; ++t) {
      const short8 b = *(const short8*)(&B_lds[t * 16 * 40 + boff]);
      acc[t] = __builtin_amdgcn_mfma_f32_16x16x32_bf16(a, b, acc[t], 0, 0, 0);
    }
  }

  const int mrow = (lane >> 4) * 4;
  if (EPI == 2) {
#pragma unroll
    for (int t = 0; t < 8; ++t) {
      int c = t * 16 + (lane & 15);
      float b_r  = bias[c]       + bias2[c];
      float b_z  = bias[128 + c] + bias2[128 + c];
      float b_in = bias[256 + c];
      float b_hn = bias2[256 + c];
#pragma unroll
      for (int r = 0; r < 4; ++r) {
        int node = strip + w * 16 + mrow + r;
        if (node < M) {
          float rg = sigmoid_f(acc[t][r] + b_r);
          float zg = sigmoid_f(acc[t + 8][r] + b_z);
          float hn = acc[t + 24][r] + b_hn;
          float ng = tanh_f(acc[t + 16][r] + b_in + rg * hn);
          float hp = bf2f(Ah[(size_t)node * 128 + c]);
          out[(size_t)node * 128 + c] = f2bf((1.f - zg) * ng + zg * hp);
        }
      }
    }
  } else {
#pragma unroll
    for (int t = 0; t < NT; ++t) {
      int col = t * 16 + (lane & 15);
      float bv = bias ? bias[col] : 0.f;
#pragma unroll
      for (int r = 0; r < 4; ++r) {
        int node = strip + w * 16 + mrow + r;
        if (node < M) {
          float v = acc[t][r] + bv;
          if (EPI == 0) v = fmaxf(v, 0.f);
          out[(size_t)node * N_DIM + col] = f2bf(v);
        }
      }
    }
  }
}

// ---------------- CSR aggregation: agg[n] = sum over in-edges of h[src] ----------------
__global__ __launch_bounds__(256)
void agg_kernel(const u16* __restrict__ m, const int* __restrict__ ssrc,
                const int* __restrict__ offsets, u16* __restrict__ agg)
{
  int node = blockIdx.x * 4 + (threadIdx.x >> 6);
  int lane = threadIdx.x & 63;
  if (node >= N_NODES) return;
  int beg = offsets[node], end = offsets[node + 1];
  float s0 = 0.f, s1 = 0.f;
  for (int e = beg; e < end; ++e) {
    int src = ssrc[e];
    u32 v = *(const u32*)(m + (size_t)src * 128 + lane * 2);  // coalesced 256B/row per wave
    s0 += bf2f((u16)(v & 0xffffu));
    s1 += bf2f((u16)(v >> 16));
  }
  u32 packed = (u32)f2bf(s0) | ((u32)f2bf(s1) << 16);
  *(u32*)(agg + (size_t)node * 128 + lane * 2) = packed;
}

// ---------------- parallel segmented mean-pool (batch is sorted) ----------------
__global__ __launch_bounds__(256)
void pool_kernel(const u16* __restrict__ h, const int* __restrict__ batch,
                 const int* __restrict__ flags, float* __restrict__ sums)
{
  const int c = threadIdx.x & 127;
  const int half = threadIdx.x >> 7;
  const int base = blockIdx.x * 128;
  const int f = flags[1];
  int gcur = -1; float s = 0.f;
  for (int i = half; i < 128; i += 2) {
    int n = base + i;
    if (n >= N_NODES) break;
    int g = geti(batch, n, f);
    if (g != gcur) {
      if (gcur >= 0) atomicAdd(&sums[gcur * 128 + c], s);
      s = 0.f; gcur = g;
    }
    s += bf2f(h[(size_t)n * 128 + c]);
  }
  if (gcur >= 0) atomicAdd(&sums[gcur * 128 + c], s);
}

// ---------------- doc proj + LN + fusion + heads, f32 (one block per graph) ----------------
__global__ __launch_bounds__(256)
void head2_kernel(const float* __restrict__ sums, const int* __restrict__ batch,
                  const int* __restrict__ flags,
                  const float* __restrict__ doc, const float* __restrict__ doc_w, const float* __restrict__ doc_b,
                  const float* __restrict__ ln_g, const float* __restrict__ ln_b,
                  const float* __restrict__ fus_w, const float* __restrict__ fus_b,
                  const float* __restrict__ task_w, const float* __restrict__ task_b,
                  const float* __restrict__ time_w, const float* __restrict__ time_b,
                  float* __restrict__ out_task, float* __restrict__ out_time)
{
  const int g = blockIdx.x;
  const int t = threadIdx.x;
  __shared__ float fusion[256];
  __shared__ float fh[128];
  __shared__ float dpart[256];
  __shared__ int seg[2];

  if (t < 2) {  // lower_bound(batch, g) / lower_bound(batch, g+1)
    int f = flags[1];
    int target = g + t, lo = 0, hi = N_NODES;
    while (lo < hi) { int mid = (lo + hi) >> 1; if (geti(batch, mid, f) < target) lo = mid + 1; else hi = mid; }
    seg[t] = lo;
  }
  {  // doc projection, K split across two thread-halves
    int c = t & 127, kh = t >> 7;
    float s = 0.f;
    for (int k = kh * 384; k < kh * 384 + 384; ++k) s += doc[g * 768 + k] * doc_w[k * 128 + c];
    dpart[t] = s;
  }
  __syncthreads();

  if (t < 128) {
    float cnt = (float)(seg[1] - seg[0]);
    fusion[t] = sums[g * 128 + t] / fmaxf(cnt, 1.f);
  } else {
    int c = t - 128;
    fusion[t] = fmaxf(dpart[c] + dpart[c + 128] + doc_b[c], 0.f);
  }
  __syncthreads();

  float mu = 0.f;
  for (int i = 0; i < 256; ++i) mu += fusion[i];
  mu *= (1.f / 256.f);
  float var = 0.f;
  for (int i = 0; i < 256; ++i) { float d = fusion[i] - mu; var += d * d; }
  var *= (1.f / 256.f);
  float inv = rsqrtf(var + 1e-5f);
  float norm = (fusion[t] - mu) * inv * ln_g[t] + ln_b[t];
  __syncthreads();
  fusion[t] = norm;
  __syncthreads();

  if (t < 128) {
    float s = 0.f;
    for (int k = 0; k < 256; ++k) s += fusion[k] * fus_w[k * 128 + t];
    s += fus_b[t];
    fh[t] = fmaxf(s, 0.f);
  }
  __syncthreads();

  if (t < 32) {
    float s = 0.f;
    for (int k = 0; k < 128; ++k) s += fh[k] * task_w[k * 32 + t];
    s += task_b[t];
    out_task[g * 32 + t] = s;
  }
  if (t == 32) {
    float s = 0.f;
    for (int k = 0; k < 128; ++k) s += fh[k] * time_w[k];
    s += time_b[0];
    out_time[g] = s;
  }
}

// ---------------- launch ----------------
extern "C" void kernel_launch(void* const* d_in, const int* in_sizes, int n_in,
                              void* d_out, int out_size, void* d_ws, size_t ws_size,
                              hipStream_t stream)
{
  const float* x        = (const float*)d_in[0];
  const float* doc      = (const float*)d_in[1];
  const int*   ei       = (const int*)d_in[2];
  const int*   batch    = (const int*)d_in[3];
  const float* node_w   = (const float*)d_in[4];
  const float* node_b   = (const float*)d_in[5];
  const float* ggnn_w   = (const float*)d_in[6];
  const float* gru_w_ih = (const float*)d_in[7];
  const float* gru_b_ih = (const float*)d_in[8];
  const float* gru_w_hh = (const float*)d_in[9];
  const float* gru_b_hh = (const float*)d_in[10];
  const float* doc_w    = (const float*)d_in[11];
  const float* doc_b    = (const float*)d_in[12];
  const float* ln_g     = (const float*)d_in[13];
  const float* ln_b     = (const float*)d_in[14];
  const float* fus_w    = (const float*)d_in[15];
  const float* fus_b    = (const float*)d_in[16];
  const float* task_w   = (const float*)d_in[17];
  const float* task_b   = (const float*)d_in[18];
  const float* time_w   = (const float*)d_in[19];
  const float* time_b   = (const float*)d_in[20];

  char* ws = (char*)d_ws;
  size_t off = 0;
  auto alloc = [&](size_t bytes) -> void* {
    void* p = ws + off;
    off = (off + bytes + 255) & ~(size_t)255;
    return p;
  };
  u16* aggb   = (u16*)alloc((size_t)N_NODES * 128 * 2);  // xb aliases this region
  u16* xb     = aggb;                                     // [N][64] bf16, dead before first agg
  u16* hA     = (u16*)alloc((size_t)N_NODES * 128 * 2);
  u16* nwT    = (u16*)alloc(64 * 128 * 2);
  u16* b2T    = (u16*)alloc(3 * 512 * 256 * 2);
  float* wp   = (float*)alloc(3 * 128 * 384 * 4);
  float* sums = (float*)alloc(N_GRAPHS * 128 * 4);
  int* counts = (int*)alloc((size_t)N_NODES * 4);
  int* cursor = (int*)alloc((size_t)N_NODES * 4);
  int* offs   = (int*)alloc((size_t)(N_NODES + 1) * 4);
  int* ssrc   = (int*)alloc((size_t)N_EDGES * 4);
  int* flags  = (int*)alloc(2 * 4);

  hipMemsetAsync(counts, 0, (size_t)N_NODES * 4, stream);
  hipMemsetAsync(cursor, 0, (size_t)N_NODES * 4, stream);
  hipMemsetAsync(sums, 0, (size_t)N_GRAPHS * 128 * 4, stream);

  detect_i64_kernel<<<1, 64, 0, stream>>>(ei, batch, flags);
  hist_kernel<<<(N_EDGES + 255) / 256, 256, 0, stream>>>(ei, flags, counts);
  scan_kernel<<<1, 1024, 0, stream>>>(counts, offs);
  scatter_kernel<<<(N_EDGES + 255) / 256, 256, 0, stream>>>(ei, flags, offs, cursor, ssrc);

  convert_kernel<<<(N_NODES * 64 + 255) / 256, 256, 0, stream>>>(x, xb, N_NODES * 64);
  transpose_kernel<<<(64 * 128 + 255) / 256, 256, 0, stream>>>(node_w, nwT, 64, 128);
  wprime_kernel<<<(3 * 128 * 384 + 255) / 256, 256, 0, stream>>>(ggnn_w, gru_w_ih, wp);
  for (int l = 0; l < 3; ++l)
    build_b2t_kernel<<<512, 256, 0, stream>>>(wp + l * 128 * 384, gru_w_hh, b2T + l * 512 * 256);

  const int GB = (N_NODES + 63) / 64;  // 1563
  gemm_mfma<64, 128, 0><<<GB, 256, 0, stream>>>(xb, nullptr, nwT, node_b, nullptr, hA, N_NODES);

  for (int l = 0; l < 3; ++l) {
    agg_kernel<<<(N_NODES + 3) / 4, 256, 0, stream>>>(hA, ssrc, offs, aggb);
    gemm_mfma<256, 512, 2><<<GB, 256, 0, stream>>>(aggb, hA, b2T + l * 512 * 256,
                                                   gru_b_ih, gru_b_hh, hA, N_NODES);
  }

  pool_kernel<<<(N_NODES + 127) / 128, 256, 0, stream>>>(hA, batch, flags, sums);

  float* out_task = (float*)d_out;
  float* out_time = out_task + N_GRAPHS * 32;
  head2_kernel<<<N_GRAPHS, 256, 0, stream>>>(sums, batch, flags, doc, doc_w, doc_b, ln_g, ln_b,
                                             fus_w, fus_b, task_w, task_b, time_w, time_b,
                                             out_task, out_time);
}

// Round 4
// 1089.188 us; speedup vs baseline: 1.5060x; 1.3300x over previous
//
#include <hip/hip_runtime.h>

#define N_NODES  100000
#define N_EDGES  1600000
#define N_GRAPHS 128
#define SCAN_BLOCKS 98   // ceil(100000/1024)

typedef unsigned short u16;
typedef unsigned int   u32;
typedef __attribute__((ext_vector_type(8))) short short8;
typedef __attribute__((ext_vector_type(4))) float f32x4;

__device__ __forceinline__ float bf2f(u16 v) {
  union { u32 i; float f; } u; u.i = ((u32)v) << 16; return u.f;
}
__device__ __forceinline__ u16 f2bf(float f) {
  union { float f; u32 i; } u; u.f = f;
  u32 r = (u.i + 0x7fffu + ((u.i >> 16) & 1u)) >> 16;
  return (u16)r;
}
__device__ __forceinline__ float sigmoid_f(float x) { return 1.f / (1.f + __expf(-x)); }
__device__ __forceinline__ float tanh_f(float x) {
  x = fminf(15.f, fmaxf(-15.f, x));
  float e = __expf(2.f * x);
  return (e - 1.f) / (e + 1.f);
}

// Integer load honoring runtime int64/int32 layout (int64 little-endian: value in low word)
__device__ __forceinline__ int geti(const int* __restrict__ p, int i, int is64) {
  return p[is64 ? (2 * i) : i];
}

// Detect whether edge_index / batch are int64 (all sampled odd words == 0) or int32.
__global__ void detect_i64_kernel(const int* __restrict__ ei, const int* __restrict__ batch,
                                  int* __restrict__ flags) {
  int lane = threadIdx.x;  // 64
  {
    long long q = (long long)lane * (3200000 / 2 - 1) / 63;
    int pos = (int)(2 * q + 1);
    unsigned long long m = __ballot(ei[pos] != 0);
    if (lane == 0) flags[0] = (m == 0ull) ? 1 : 0;
  }
  {
    long long q = (long long)lane * (100000 / 2 - 1) / 63;
    int pos = (int)(2 * q + 1);
    unsigned long long m = __ballot(batch[pos] != 0);
    if (lane == 0) flags[1] = (m == 0ull) ? 1 : 0;
  }
}

// ---------------- CSR build ----------------
__global__ void hist_kernel(const int* __restrict__ ei, const int* __restrict__ flags,
                            int* __restrict__ counts) {
  int e = blockIdx.x * 256 + threadIdx.x;
  if (e < N_EDGES) {
    int f = flags[0];
    atomicAdd(&counts[geti(ei, N_EDGES + e, f)], 1);
  }
}

// Phase A: per-block coalesced sum of 1024 counts -> blocksums[b]
__global__ __launch_bounds__(1024)
void scanA_kernel(const int* __restrict__ counts, int* __restrict__ blocksums) {
  __shared__ int red[16];
  int i = blockIdx.x * 1024 + threadIdx.x;
  int v = (i < N_NODES) ? counts[i] : 0;
  // wave reduce (64 lanes)
  for (int o = 32; o > 0; o >>= 1) v += __shfl_down(v, o, 64);
  int wv = threadIdx.x >> 6, lane = threadIdx.x & 63;
  if (lane == 0) red[wv] = v;
  __syncthreads();
  if (threadIdx.x < 16) {
    int s = red[threadIdx.x];
    for (int o = 8; o > 0; o >>= 1) s += __shfl_down(s, o, 64);
    if (threadIdx.x == 0) blocksums[blockIdx.x] = s;
  }
}

// Phase B: exclusive scan of SCAN_BLOCKS block sums; also writes offsets[N_NODES]
__global__ void scanB_kernel(const int* __restrict__ blocksums, int* __restrict__ blockbase,
                             int* __restrict__ offsets) {
  if (threadIdx.x == 0) {
    int run = 0;
    for (int b = 0; b < SCAN_BLOCKS; ++b) { blockbase[b] = run; run += blocksums[b]; }
    offsets[N_NODES] = run;
  }
}

// Phase C: per-block inclusive scan (coalesced) + blockbase -> exclusive offsets
__global__ __launch_bounds__(1024)
void scanC_kernel(const int* __restrict__ counts, const int* __restrict__ blockbase,
                  int* __restrict__ offsets) {
  __shared__ int buf[1024];
  int t = threadIdx.x;
  int i = blockIdx.x * 1024 + t;
  int v = (i < N_NODES) ? counts[i] : 0;
  buf[t] = v;
  __syncthreads();
  for (int o = 1; o < 1024; o <<= 1) {
    int add = (t >= o) ? buf[t - o] : 0;
    __syncthreads();
    buf[t] += add;
    __syncthreads();
  }
  if (i < N_NODES) offsets[i] = buf[t] - v + blockbase[blockIdx.x];
}

__global__ void scatter_kernel(const int* __restrict__ ei, const int* __restrict__ flags,
                               const int* __restrict__ offsets,
                               int* __restrict__ cursor, int* __restrict__ ssrc) {
  int e = blockIdx.x * 256 + threadIdx.x;
  if (e < N_EDGES) {
    int f = flags[0];
    int d = geti(ei, N_EDGES + e, f);
    int pos = offsets[d] + atomicAdd(&cursor[d], 1);
    ssrc[pos] = geti(ei, e, f);
  }
}

// ---------------- weight prep ----------------
// f32 [K][N] row-major -> bf16 [N][K]
__global__ void transpose_kernel(const float* __restrict__ in, u16* __restrict__ out, int K, int N) {
  int i = blockIdx.x * 256 + threadIdx.x;
  if (i < K * N) {
    int k = i / N, n = i % N;
    out[n * K + k] = f2bf(in[i]);
  }
}

// W'_l[k][c] = sum_j ggnn_w[l][k][j] * w_ih[j][c]   (f32, [3][128][384])
// segment_sum commutes with the linear map, so agg(h@W)@w_ih == agg(h)@(W@w_ih).
__global__ void wprime_kernel(const float* __restrict__ ggnn_w, const float* __restrict__ w_ih,
                              float* __restrict__ wp) {
  int i = blockIdx.x * 256 + threadIdx.x;  // l*128*384 + k*384 + c
  if (i >= 3 * 128 * 384) return;
  int l = i / (128 * 384), r = i % (128 * 384), k = r / 384, c = r % 384;
  const float* W = ggnn_w + l * 128 * 128;
  float s = 0.f;
  for (int j = 0; j < 128; ++j) s += W[k * 128 + j] * w_ih[j * 384 + c];
  wp[i] = s;
}

// Fused GRU weight B2^T [512][256] (bf16) for one layer, built from W' (f32) + w_hh:
// cols 0..127: r | 128..255: z | 256..383: in (k<128 only) | 384..511: hn (k>=128 only)
__global__ void build_b2t_kernel(const float* __restrict__ wp, const float* __restrict__ w_hh,
                                 u16* __restrict__ b2t) {
  int i = blockIdx.x * 256 + threadIdx.x;  // i = c*256 + k
  if (i >= 512 * 256) return;
  int c = i >> 8, k = i & 255;
  float v = 0.f;
  if (c < 384) v = (k < 128) ? wp[k * 384 + c] : ((c < 256) ? w_hh[(k - 128) * 384 + c] : 0.f);
  else         v = (k < 128) ? 0.f : w_hh[(k - 128) * 384 + (c - 128)];
  b2t[i] = f2bf(v);
}

// ---------------- MFMA GEMM ----------------
// EPI 0: +bias, relu, bf16 out.  EPI 2: GRU epilogue; A=aggH (k<128), Ah=h (k>=128),
// writes h_new IN PLACE over Ah (per-wave row ownership makes this race-free).
// AF32: A is f32, converted in-register to bf16 fragments.
template<int K_DIM, int N_DIM, int EPI, int AF32>
__global__ __launch_bounds__(256)
void gemm_mfma(const void* __restrict__ Av, const u16* __restrict__ Ah,
               const u16* __restrict__ BT, const float* __restrict__ bias,
               const float* __restrict__ bias2, u16* __restrict__ out, int M)
{
  constexpr int NT = N_DIM / 16;
  constexpr int NCHUNK = K_DIM / 32;
  __shared__ u16 B_lds[N_DIM * 40];  // [n][32 k + 8 pad] -> 2-way bank alias only (free)

  const int tid  = threadIdx.x;
  const int lane = tid & 63;
  const int w    = tid >> 6;
  const int strip = blockIdx.x * 64;
  const int ksub = (lane >> 4) * 8;

  union Frag { uint4 u; short8 s; };
  Frag af[NCHUNK];
  const int m_node = strip + w * 16 + (lane & 15);
  const bool avalid = (m_node < M);
#pragma unroll
  for (int ci = 0; ci < NCHUNK; ++ci) {
    int k0 = ci * 32 + ksub;
    if (AF32) {
      const float* A = (const float*)Av;
      short8 sv = {0,0,0,0,0,0,0,0};
      if (avalid) {
        const float* p = A + (size_t)m_node * K_DIM + k0;
        float4 f0 = *(const float4*)p;
        float4 f1 = *(const float4*)(p + 4);
        sv[0]=(short)f2bf(f0.x); sv[1]=(short)f2bf(f0.y); sv[2]=(short)f2bf(f0.z); sv[3]=(short)f2bf(f0.w);
        sv[4]=(short)f2bf(f1.x); sv[5]=(short)f2bf(f1.y); sv[6]=(short)f2bf(f1.z); sv[7]=(short)f2bf(f1.w);
      }
      af[ci].s = sv;
    } else {
      const u16* A = (const u16*)Av;
      uint4 v; v.x = v.y = v.z = v.w = 0u;
      if (avalid) {
        const u16* p;
        if (EPI == 2) p = (k0 < 128) ? (A + (size_t)m_node * 128 + k0)
                                     : (Ah + (size_t)m_node * 128 + (k0 - 128));
        else          p = A + (size_t)m_node * K_DIM + k0;
        v = *(const uint4*)p;
      }
      af[ci].u = v;
    }
  }
  asm volatile("s_waitcnt vmcnt(0)" ::: "memory");
  __syncthreads();

  f32x4 acc[NT];
#pragma unroll
  for (int t = 0; t < NT; ++t) acc[t] = {0.f, 0.f, 0.f, 0.f};

  const int boff = (lane & 15) * 40 + ksub;

  for (int ci = 0; ci < NCHUNK; ++ci) {
    if (ci) __syncthreads();
    for (int g = tid; g < N_DIM * 4; g += 256) {   // stage BT chunk, 16B copies
      int n = g >> 2, ko = g & 3;
      uint4 bv = *(const uint4*)(BT + (size_t)n * K_DIM + ci * 32 + ko * 8);
      *(uint4*)(&B_lds[n * 40 + ko * 8]) = bv;
    }
    __syncthreads();
    short8 a = af[ci].s;
#pragma unroll
    for (int t = 0; t < NT; ++t) {
      const short8 b = *(const short8*)(&B_lds[t * 16 * 40 + boff]);
      acc[t] = __builtin_amdgcn_mfma_f32_16x16x32_bf16(a, b, acc[t], 0, 0, 0);
    }
  }

  const int mrow = (lane >> 4) * 4;
  if (EPI == 2) {
#pragma unroll
    for (int t = 0; t < 8; ++t) {
      int c = t * 16 + (lane & 15);
      float b_r  = bias[c]       + bias2[c];
      float b_z  = bias[128 + c] + bias2[128 + c];
      float b_in = bias[256 + c];
      float b_hn = bias2[256 + c];
#pragma unroll
      for (int r = 0; r < 4; ++r) {
        int node = strip + w * 16 + mrow + r;
        if (node < M) {
          float rg = sigmoid_f(acc[t][r] + b_r);
          float zg = sigmoid_f(acc[t + 8][r] + b_z);
          float hn = acc[t + 24][r] + b_hn;
          float ng = tanh_f(acc[t + 16][r] + b_in + rg * hn);
          float hp = bf2f(Ah[(size_t)node * 128 + c]);
          out[(size_t)node * 128 + c] = f2bf((1.f - zg) * ng + zg * hp);
        }
      }
    }
  } else {
#pragma unroll
    for (int t = 0; t < NT; ++t) {
      int col = t * 16 + (lane & 15);
      float bv = bias ? bias[col] : 0.f;
#pragma unroll
      for (int r = 0; r < 4; ++r) {
        int node = strip + w * 16 + mrow + r;
        if (node < M) {
          float v = acc[t][r] + bv;
          if (EPI == 0) v = fmaxf(v, 0.f);
          out[(size_t)node * N_DIM + col] = f2bf(v);
        }
      }
    }
  }
}

// ---------------- CSR aggregation: agg[n] = sum over in-edges of h[src] ----------------
__global__ __launch_bounds__(256)
void agg_kernel(const u16* __restrict__ m, const int* __restrict__ ssrc,
                const int* __restrict__ offsets, u16* __restrict__ agg)
{
  int node = blockIdx.x * 4 + (threadIdx.x >> 6);
  int lane = threadIdx.x & 63;
  if (node >= N_NODES) return;
  int beg = offsets[node], end = offsets[node + 1];
  float s0 = 0.f, s1 = 0.f;
  int e = beg;
  for (; e + 1 < end; e += 2) {      // 2-way unroll for memory-level parallelism
    int srcA = ssrc[e], srcB = ssrc[e + 1];
    u32 va = *(const u32*)(m + (size_t)srcA * 128 + lane * 2);
    u32 vb = *(const u32*)(m + (size_t)srcB * 128 + lane * 2);
    s0 += bf2f((u16)(va & 0xffffu)) + bf2f((u16)(vb & 0xffffu));
    s1 += bf2f((u16)(va >> 16))     + bf2f((u16)(vb >> 16));
  }
  if (e < end) {
    int src = ssrc[e];
    u32 v = *(const u32*)(m + (size_t)src * 128 + lane * 2);
    s0 += bf2f((u16)(v & 0xffffu));
    s1 += bf2f((u16)(v >> 16));
  }
  u32 packed = (u32)f2bf(s0) | ((u32)f2bf(s1) << 16);
  *(u32*)(agg + (size_t)node * 128 + lane * 2) = packed;
}

// ---------------- parallel segmented mean-pool (batch is sorted) ----------------
__global__ __launch_bounds__(256)
void pool_kernel(const u16* __restrict__ h, const int* __restrict__ batch,
                 const int* __restrict__ flags, float* __restrict__ sums)
{
  const int c = threadIdx.x & 127;
  const int half = threadIdx.x >> 7;
  const int base = blockIdx.x * 128;
  const int f = flags[1];
  int gcur = -1; float s = 0.f;
  for (int i = half; i < 128; i += 2) {
    int n = base + i;
    if (n >= N_NODES) break;
    int g = geti(batch, n, f);
    if (g != gcur) {
      if (gcur >= 0) atomicAdd(&sums[gcur * 128 + c], s);
      s = 0.f; gcur = g;
    }
    s += bf2f(h[(size_t)n * 128 + c]);
  }
  if (gcur >= 0) atomicAdd(&sums[gcur * 128 + c], s);
}

// ---------------- doc proj + LN + fusion + heads, f32 (one block per graph) ----------------
__global__ __launch_bounds__(256)
void head2_kernel(const float* __restrict__ sums, const int* __restrict__ batch,
                  const int* __restrict__ flags,
                  const float* __restrict__ doc, const float* __restrict__ doc_w, const float* __restrict__ doc_b,
                  const float* __restrict__ ln_g, const float* __restrict__ ln_b,
                  const float* __restrict__ fus_w, const float* __restrict__ fus_b,
                  const float* __restrict__ task_w, const float* __restrict__ task_b,
                  const float* __restrict__ time_w, const float* __restrict__ time_b,
                  float* __restrict__ out_task, float* __restrict__ out_time)
{
  const int g = blockIdx.x;
  const int t = threadIdx.x;
  __shared__ float fusion[256];
  __shared__ float fh[128];
  __shared__ float dpart[256];
  __shared__ int seg[2];

  if (t < 2) {  // lower_bound(batch, g) / lower_bound(batch, g+1)
    int f = flags[1];
    int target = g + t, lo = 0, hi = N_NODES;
    while (lo < hi) { int mid = (lo + hi) >> 1; if (geti(batch, mid, f) < target) lo = mid + 1; else hi = mid; }
    seg[t] = lo;
  }
  {  // doc projection, K split across two thread-halves
    int c = t & 127, kh = t >> 7;
    float s = 0.f;
    for (int k = kh * 384; k < kh * 384 + 384; ++k) s += doc[g * 768 + k] * doc_w[k * 128 + c];
    dpart[t] = s;
  }
  __syncthreads();

  if (t < 128) {
    float cnt = (float)(seg[1] - seg[0]);
    fusion[t] = sums[g * 128 + t] / fmaxf(cnt, 1.f);
  } else {
    int c = t - 128;
    fusion[t] = fmaxf(dpart[c] + dpart[c + 128] + doc_b[c], 0.f);
  }
  __syncthreads();

  float mu = 0.f;
  for (int i = 0; i < 256; ++i) mu += fusion[i];
  mu *= (1.f / 256.f);
  float var = 0.f;
  for (int i = 0; i < 256; ++i) { float d = fusion[i] - mu; var += d * d; }
  var *= (1.f / 256.f);
  float inv = rsqrtf(var + 1e-5f);
  float norm = (fusion[t] - mu) * inv * ln_g[t] + ln_b[t];
  __syncthreads();
  fusion[t] = norm;
  __syncthreads();

  if (t < 128) {
    float s = 0.f;
    for (int k = 0; k < 256; ++k) s += fusion[k] * fus_w[k * 128 + t];
    s += fus_b[t];
    fh[t] = fmaxf(s, 0.f);
  }
  __syncthreads();

  if (t < 32) {
    float s = 0.f;
    for (int k = 0; k < 128; ++k) s += fh[k] * task_w[k * 32 + t];
    s += task_b[t];
    out_task[g * 32 + t] = s;
  }
  if (t == 32) {
    float s = 0.f;
    for (int k = 0; k < 128; ++k) s += fh[k] * time_w[k];
    s += time_b[0];
    out_time[g] = s;
  }
}

// ---------------- launch ----------------
extern "C" void kernel_launch(void* const* d_in, const int* in_sizes, int n_in,
                              void* d_out, int out_size, void* d_ws, size_t ws_size,
                              hipStream_t stream)
{
  const float* x        = (const float*)d_in[0];
  const float* doc      = (const float*)d_in[1];
  const int*   ei       = (const int*)d_in[2];
  const int*   batch    = (const int*)d_in[3];
  const float* node_w   = (const float*)d_in[4];
  const float* node_b   = (const float*)d_in[5];
  const float* ggnn_w   = (const float*)d_in[6];
  const float* gru_w_ih = (const float*)d_in[7];
  const float* gru_b_ih = (const float*)d_in[8];
  const float* gru_w_hh = (const float*)d_in[9];
  const float* gru_b_hh = (const float*)d_in[10];
  const float* doc_w    = (const float*)d_in[11];
  const float* doc_b    = (const float*)d_in[12];
  const float* ln_g     = (const float*)d_in[13];
  const float* ln_b     = (const float*)d_in[14];
  const float* fus_w    = (const float*)d_in[15];
  const float* fus_b    = (const float*)d_in[16];
  const float* task_w   = (const float*)d_in[17];
  const float* task_b   = (const float*)d_in[18];
  const float* time_w   = (const float*)d_in[19];
  const float* time_b   = (const float*)d_in[20];

  char* ws = (char*)d_ws;
  size_t off = 0;
  auto alloc = [&](size_t bytes) -> void* {
    void* p = ws + off;
    off = (off + bytes + 255) & ~(size_t)255;
    return p;
  };
  u16* aggb   = (u16*)alloc((size_t)N_NODES * 128 * 2);
  u16* hA     = (u16*)alloc((size_t)N_NODES * 128 * 2);
  u16* nwT    = (u16*)alloc(64 * 128 * 2);
  u16* b2T    = (u16*)alloc(3 * 512 * 256 * 2);
  float* wp   = (float*)alloc(3 * 128 * 384 * 4);
  float* sums = (float*)alloc(N_GRAPHS * 128 * 4);
  int* counts = (int*)alloc((size_t)N_NODES * 4);
  int* cursor = (int*)alloc((size_t)N_NODES * 4);
  int* offs   = (int*)alloc((size_t)(N_NODES + 1) * 4);
  int* ssrc   = (int*)alloc((size_t)N_EDGES * 4);
  int* bsum   = (int*)alloc(SCAN_BLOCKS * 4);
  int* bbase  = (int*)alloc(SCAN_BLOCKS * 4);
  int* flags  = (int*)alloc(2 * 4);

  hipMemsetAsync(counts, 0, (size_t)N_NODES * 4, stream);
  hipMemsetAsync(cursor, 0, (size_t)N_NODES * 4, stream);
  hipMemsetAsync(sums, 0, (size_t)N_GRAPHS * 128 * 4, stream);

  detect_i64_kernel<<<1, 64, 0, stream>>>(ei, batch, flags);
  hist_kernel<<<(N_EDGES + 255) / 256, 256, 0, stream>>>(ei, flags, counts);
  scanA_kernel<<<SCAN_BLOCKS, 1024, 0, stream>>>(counts, bsum);
  scanB_kernel<<<1, 64, 0, stream>>>(bsum, bbase, offs);
  scanC_kernel<<<SCAN_BLOCKS, 1024, 0, stream>>>(counts, bbase, offs);
  scatter_kernel<<<(N_EDGES + 255) / 256, 256, 0, stream>>>(ei, flags, offs, cursor, ssrc);

  transpose_kernel<<<(64 * 128 + 255) / 256, 256, 0, stream>>>(node_w, nwT, 64, 128);
  wprime_kernel<<<(3 * 128 * 384 + 255) / 256, 256, 0, stream>>>(ggnn_w, gru_w_ih, wp);
  for (int l = 0; l < 3; ++l)
    build_b2t_kernel<<<512, 256, 0, stream>>>(wp + l * 128 * 384, gru_w_hh, b2T + l * 512 * 256);

  const int GB = (N_NODES + 63) / 64;  // 1563
  gemm_mfma<64, 128, 0, 1><<<GB, 256, 0, stream>>>(x, nullptr, nwT, node_b, nullptr, hA, N_NODES);

  for (int l = 0; l < 3; ++l) {
    agg_kernel<<<(N_NODES + 3) / 4, 256, 0, stream>>>(hA, ssrc, offs, aggb);
    gemm_mfma<256, 512, 2, 0><<<GB, 256, 0, stream>>>(aggb, hA, b2T + l * 512 * 256,
                                                      gru_b_ih, gru_b_hh, hA, N_NODES);
  }

  pool_kernel<<<(N_NODES + 127) / 128, 256, 0, stream>>>(hA, batch, flags, sums);

  float* out_task = (float*)d_out;
  float* out_time = out_task + N_GRAPHS * 32;
  head2_kernel<<<N_GRAPHS, 256, 0, stream>>>(sums, batch, flags, doc, doc_w, doc_b, ln_g, ln_b,
                                             fus_w, fus_b, task_w, task_b, time_w, time_b,
                                             out_task, out_time);
}

// Round 5
// 1081.536 us; speedup vs baseline: 1.5167x; 1.0071x over previous
//
#include <hip/hip_runtime.h>

#define N_NODES  100000
#define N_EDGES  1600000
#define N_GRAPHS 128
#define SCAN_BLOCKS 98   // ceil(100000/1024)

typedef unsigned short u16;
typedef unsigned int   u32;
typedef __attribute__((ext_vector_type(8))) short short8;
typedef __attribute__((ext_vector_type(4))) float f32x4;

__device__ __forceinline__ float bf2f(u16 v) {
  union { u32 i; float f; } u; u.i = ((u32)v) << 16; return u.f;
}
__device__ __forceinline__ u16 f2bf(float f) {
  union { float f; u32 i; } u; u.f = f;
  u32 r = (u.i + 0x7fffu + ((u.i >> 16) & 1u)) >> 16;
  return (u16)r;
}
__device__ __forceinline__ float sigmoid_f(float x) { return 1.f / (1.f + __expf(-x)); }
__device__ __forceinline__ float tanh_f(float x) {
  x = fminf(15.f, fmaxf(-15.f, x));
  float e = __expf(2.f * x);
  return (e - 1.f) / (e + 1.f);
}
__device__ __forceinline__ int geti(const int* __restrict__ p, int i, int is64) {
  return p[is64 ? (2 * i) : i];
}

// Detect whether edge_index / batch are int64 (all sampled odd words == 0) or int32.
__global__ void detect_i64_kernel(const int* __restrict__ ei, const int* __restrict__ batch,
                                  int* __restrict__ flags) {
  int lane = threadIdx.x;  // 64
  {
    long long q = (long long)lane * (3200000 / 2 - 1) / 63;
    int pos = (int)(2 * q + 1);
    unsigned long long m = __ballot(ei[pos] != 0);
    if (lane == 0) flags[0] = (m == 0ull) ? 1 : 0;
  }
  {
    long long q = (long long)lane * (100000 / 2 - 1) / 63;
    int pos = (int)(2 * q + 1);
    unsigned long long m = __ballot(batch[pos] != 0);
    if (lane == 0) flags[1] = (m == 0ull) ? 1 : 0;
  }
}

// ---------------- CSR build ----------------
__global__ void hist_kernel(const int* __restrict__ ei, const int* __restrict__ flags,
                            int* __restrict__ counts) {
  int e = blockIdx.x * 256 + threadIdx.x;
  if (e < N_EDGES) {
    int f = flags[0];
    atomicAdd(&counts[geti(ei, N_EDGES + e, f)], 1);
  }
}

__global__ __launch_bounds__(1024)
void scanA_kernel(const int* __restrict__ counts, int* __restrict__ blocksums) {
  __shared__ int red[16];
  int i = blockIdx.x * 1024 + threadIdx.x;
  int v = (i < N_NODES) ? counts[i] : 0;
  for (int o = 32; o > 0; o >>= 1) v += __shfl_down(v, o, 64);
  int wv = threadIdx.x >> 6, lane = threadIdx.x & 63;
  if (lane == 0) red[wv] = v;
  __syncthreads();
  if (threadIdx.x < 16) {
    int s = red[threadIdx.x];
    for (int o = 8; o > 0; o >>= 1) s += __shfl_down(s, o, 64);
    if (threadIdx.x == 0) blocksums[blockIdx.x] = s;
  }
}

__global__ void scanB_kernel(const int* __restrict__ blocksums, int* __restrict__ blockbase,
                             int* __restrict__ offsets) {
  if (threadIdx.x == 0) {
    int run = 0;
    for (int b = 0; b < SCAN_BLOCKS; ++b) { blockbase[b] = run; run += blocksums[b]; }
    offsets[N_NODES] = run;
  }
}

__global__ __launch_bounds__(1024)
void scanC_kernel(const int* __restrict__ counts, const int* __restrict__ blockbase,
                  int* __restrict__ offsets) {
  __shared__ int buf[1024];
  int t = threadIdx.x;
  int i = blockIdx.x * 1024 + t;
  int v = (i < N_NODES) ? counts[i] : 0;
  buf[t] = v;
  __syncthreads();
  for (int o = 1; o < 1024; o <<= 1) {
    int add = (t >= o) ? buf[t - o] : 0;
    __syncthreads();
    buf[t] += add;
    __syncthreads();
  }
  if (i < N_NODES) offsets[i] = buf[t] - v + blockbase[blockIdx.x];
}

__global__ void scatter_kernel(const int* __restrict__ ei, const int* __restrict__ flags,
                               const int* __restrict__ offsets,
                               int* __restrict__ cursor, int* __restrict__ ssrc) {
  int e = blockIdx.x * 256 + threadIdx.x;
  if (e < N_EDGES) {
    int f = flags[0];
    int d = geti(ei, N_EDGES + e, f);
    int pos = offsets[d] + atomicAdd(&cursor[d], 1);
    ssrc[pos] = geti(ei, e, f);
  }
}

// ---------------- weight prep ----------------
// f32 [K][N] row-major -> bf16 [N][K]
__global__ void transpose_kernel(const float* __restrict__ in, u16* __restrict__ out, int K, int N) {
  int i = blockIdx.x * 256 + threadIdx.x;
  if (i < K * N) {
    int k = i / N, n = i % N;
    out[n * K + k] = f2bf(in[i]);
  }
}

// W'_l[k][c] = sum_j ggnn_w[l][k][j] * w_ih[j][c]   (f32, [3][128][384])
__global__ void wprime_kernel(const float* __restrict__ ggnn_w, const float* __restrict__ w_ih,
                              float* __restrict__ wp) {
  int i = blockIdx.x * 256 + threadIdx.x;
  if (i >= 3 * 128 * 384) return;
  int l = i / (128 * 384), r = i % (128 * 384), k = r / 384, c = r % 384;
  const float* W = ggnn_w + l * 128 * 128;
  float s = 0.f;
  for (int j = 0; j < 128; ++j) s += W[k * 128 + j] * w_ih[j * 384 + c];
  wp[i] = s;
}

// Packed GRU weight for the staging loop: b2p[ci][idx][e] u16, ci=0..7 (k-chunk),
// idx=0..1535 (idx = ko*384 + n_lin, staged 16B-per-thread in idx order),
// e=0..7 (k within the 16B group). Zero quadrants excluded:
//   ci<4 (k<128): rows n_lin=0..383 are W' cols 0..383 (r|z|in).
//   ci>=4 (k>=128): rows are w_hh cols 0..383 (r|z|hn) — col n of B2 = n_lin(+128 for hn).
__global__ void build_b2p_kernel(const float* __restrict__ wp, const float* __restrict__ w_hh,
                                 u16* __restrict__ b2p) {
  int g = blockIdx.x * 256 + threadIdx.x;   // one u16 element per thread
  if (g >= 8 * 1536 * 8) return;
  int e = g & 7;
  int grp = g >> 3;            // 0..12287
  int ci = grp / 1536;
  int idx = grp % 1536;
  int n_lin = idx % 384;
  int ko = idx / 384;
  int k = ci * 32 + ko * 8 + e;
  float v = (k < 128) ? wp[k * 384 + n_lin] : w_hh[(k - 128) * 384 + n_lin];
  b2p[g] = f2bf(v);
}

// ---------------- node projection GEMM (f32 A -> bf16 frags), small ----------------
__global__ __launch_bounds__(256)
void nodeproj_gemm(const float* __restrict__ A, const u16* __restrict__ BT,
                   const float* __restrict__ bias, u16* __restrict__ out, int M)
{
  constexpr int K_DIM = 64, N_DIM = 128, NT = 8, NCHUNK = 2;
  __shared__ u16 B_lds[N_DIM * 40];
  const int tid = threadIdx.x, lane = tid & 63, w = tid >> 6;
  const int strip = blockIdx.x * 64;
  const int ksub = (lane >> 4) * 8;
  union Frag { uint4 u; short8 s; };
  Frag af[NCHUNK];
  const int m_node = strip + w * 16 + (lane & 15);
  const bool avalid = (m_node < M);
#pragma unroll
  for (int ci = 0; ci < NCHUNK; ++ci) {
    int k0 = ci * 32 + ksub;
    short8 sv = {0,0,0,0,0,0,0,0};
    if (avalid) {
      const float* p = A + (size_t)m_node * K_DIM + k0;
      float4 f0 = *(const float4*)p;
      float4 f1 = *(const float4*)(p + 4);
      sv[0]=(short)f2bf(f0.x); sv[1]=(short)f2bf(f0.y); sv[2]=(short)f2bf(f0.z); sv[3]=(short)f2bf(f0.w);
      sv[4]=(short)f2bf(f1.x); sv[5]=(short)f2bf(f1.y); sv[6]=(short)f2bf(f1.z); sv[7]=(short)f2bf(f1.w);
    }
    af[ci].s = sv;
  }
  f32x4 acc[NT];
#pragma unroll
  for (int t = 0; t < NT; ++t) acc[t] = {0.f, 0.f, 0.f, 0.f};
  const int boff = (lane & 15) * 40 + ksub;
#pragma unroll
  for (int ci = 0; ci < NCHUNK; ++ci) {
    if (ci) __syncthreads();
    for (int g = tid; g < N_DIM * 4; g += 256) {
      int n = g >> 2, ko = g & 3;
      uint4 bv = *(const uint4*)(BT + (size_t)n * K_DIM + ci * 32 + ko * 8);
      *(uint4*)(&B_lds[n * 40 + ko * 8]) = bv;
    }
    __syncthreads();
    short8 a = af[ci].s;
#pragma unroll
    for (int t = 0; t < NT; ++t) {
      const short8 b = *(const short8*)(&B_lds[t * 16 * 40 + boff]);
      acc[t] = __builtin_amdgcn_mfma_f32_16x16x32_bf16(a, b, acc[t], 0, 0, 0);
    }
  }
  const int mrow = (lane >> 4) * 4;
#pragma unroll
  for (int t = 0; t < NT; ++t) {
    int col = t * 16 + (lane & 15);
    float bv = bias[col];
#pragma unroll
    for (int r = 0; r < 4; ++r) {
      int node = strip + w * 16 + mrow + r;
      if (node < M) out[(size_t)node * N_DIM + col] = f2bf(fmaxf(acc[t][r] + bv, 0.f));
    }
  }
}

// ---------------- GRU GEMM: [agg|h] @ B2 -> GRU epilogue ----------------
// Block: 256 thr = 4 waves; 64 rows/block. Wave w owns col-tiles t = w+4j (j=0..7)
// over the logical 512 cols; zero quadrants skipped (in: k<128 only; hn: k>=128 only).
__global__ __launch_bounds__(256, 3)
void gru_gemm(const u16* __restrict__ agg, const u16* __restrict__ h,
              const u16* __restrict__ b2p, const float* __restrict__ b_ih,
              const float* __restrict__ b_hh, u16* __restrict__ hout, int M)
{
  __shared__ u16 B_lds[384 * 40];   // [n_lin][32k + 8 pad]; writes & reads both clean 2-way
  const int tid  = threadIdx.x;
  const int lane = tid & 63;
  const int w    = tid >> 6;
  const int strip = blockIdx.x * 64;
  const int lrow = lane & 15;
  const int quad = lane >> 4;
  const int ksub = quad * 8;

  f32x4 acc[4][8];
#pragma unroll
  for (int s = 0; s < 4; ++s)
#pragma unroll
    for (int j = 0; j < 8; ++j) acc[s][j] = {0.f, 0.f, 0.f, 0.f};

  union Frag { uint4 u; short8 s8; };
  int node_a[4]; bool aval[4];
#pragma unroll
  for (int s = 0; s < 4; ++s) { node_a[s] = strip + s * 16 + lrow; aval[s] = node_a[s] < M; }

#pragma unroll
  for (int ci = 0; ci < 8; ++ci) {
    // A fragments for this k-chunk: agg (k<128) or h (k>=128), 16B per strip
    Frag a[4];
    const u16* abase = (ci < 4) ? (agg + ci * 32 + ksub) : (h + (ci - 4) * 32 + ksub);
#pragma unroll
    for (int s = 0; s < 4; ++s) {
      uint4 v = {0u, 0u, 0u, 0u};
      if (aval[s]) v = *(const uint4*)(abase + (size_t)node_a[s] * 128);
      a[s].u = v;
    }
    if (ci) __syncthreads();
    // stage packed B chunk: coalesced global 16B, conflict-free LDS writes
    const u16* gsrc = b2p + (size_t)ci * (1536 * 8);
#pragma unroll
    for (int it = 0; it < 6; ++it) {
      int idx = tid + it * 256;
      int n_lin = idx % 384, ko = idx / 384;
      uint4 bv = *(const uint4*)(gsrc + (size_t)idx * 8);
      *(uint4*)(&B_lds[n_lin * 40 + ko * 8]) = bv;
    }
    __syncthreads();
#pragma unroll
    for (int j = 0; j < 8; ++j) {
      const int t = w + 4 * j;
      const bool active = (ci < 4) ? (t < 24) : (t < 16 || t >= 24);
      if (!active) continue;   // wave-uniform
      const int rbase = (ci >= 4 && t >= 24) ? (t - 8) * 16 : t * 16;
      const short8 b = *(const short8*)(&B_lds[(rbase + lrow) * 40 + ksub]);
#pragma unroll
      for (int s = 0; s < 4; ++s)
        acc[s][j] = __builtin_amdgcn_mfma_f32_16x16x32_bf16(a[s].s8, b, acc[s][j], 0, 0, 0);
    }
  }

  // GRU epilogue: wave w covers h-cols (w+4j)*16.. for j=0,1
#pragma unroll
  for (int j = 0; j < 2; ++j) {
    const int c = (w + 4 * j) * 16 + lrow;
    const float br  = b_ih[c] + b_hh[c];
    const float bz  = b_ih[128 + c] + b_hh[128 + c];
    const float bin = b_ih[256 + c];
    const float bhn = b_hh[256 + c];
#pragma unroll
    for (int s = 0; s < 4; ++s) {
#pragma unroll
      for (int r = 0; r < 4; ++r) {
        const int node = strip + s * 16 + quad * 4 + r;
        if (node < M) {
          float rg = sigmoid_f(acc[s][j][r] + br);
          float zg = sigmoid_f(acc[s][j + 2][r] + bz);
          float hn = acc[s][j + 6][r] + bhn;
          float ng = tanh_f(acc[s][j + 4][r] + bin + rg * hn);
          float hp = bf2f(h[(size_t)node * 128 + c]);
          hout[(size_t)node * 128 + c] = f2bf((1.f - zg) * ng + zg * hp);
        }
      }
    }
  }
}

// ---------------- CSR aggregation: agg[n] = sum over in-edges of h[src], 8x MLP ----------------
__global__ __launch_bounds__(256)
void agg_kernel(const u16* __restrict__ m, const int* __restrict__ ssrc,
                const int* __restrict__ offsets, u16* __restrict__ agg)
{
  int node = blockIdx.x * 4 + (threadIdx.x >> 6);
  int lane = threadIdx.x & 63;
  if (node >= N_NODES) return;
  int beg = offsets[node], end = offsets[node + 1];
  float s0 = 0.f, s1 = 0.f;
  int e = beg;
  for (; e + 8 <= end; e += 8) {
    u32 v[8];
#pragma unroll
    for (int q = 0; q < 8; ++q) {
      int src = ssrc[e + q];
      v[q] = *(const u32*)(m + (size_t)src * 128 + lane * 2);
    }
#pragma unroll
    for (int q = 0; q < 8; ++q) {
      s0 += bf2f((u16)(v[q] & 0xffffu));
      s1 += bf2f((u16)(v[q] >> 16));
    }
  }
  for (; e < end; ++e) {
    int src = ssrc[e];
    u32 v = *(const u32*)(m + (size_t)src * 128 + lane * 2);
    s0 += bf2f((u16)(v & 0xffffu));
    s1 += bf2f((u16)(v >> 16));
  }
  u32 packed = (u32)f2bf(s0) | ((u32)f2bf(s1) << 16);
  *(u32*)(agg + (size_t)node * 128 + lane * 2) = packed;
}

// ---------------- parallel segmented mean-pool (batch is sorted) ----------------
__global__ __launch_bounds__(256)
void pool_kernel(const u16* __restrict__ h, const int* __restrict__ batch,
                 const int* __restrict__ flags, float* __restrict__ sums)
{
  const int c = threadIdx.x & 127;
  const int half = threadIdx.x >> 7;
  const int base = blockIdx.x * 128;
  const int f = flags[1];
  int gcur = -1; float s = 0.f;
  for (int i = half; i < 128; i += 2) {
    int n = base + i;
    if (n >= N_NODES) break;
    int g = geti(batch, n, f);
    if (g != gcur) {
      if (gcur >= 0) atomicAdd(&sums[gcur * 128 + c], s);
      s = 0.f; gcur = g;
    }
    s += bf2f(h[(size_t)n * 128 + c]);
  }
  if (gcur >= 0) atomicAdd(&sums[gcur * 128 + c], s);
}

// ---------------- doc proj + LN + fusion + heads, f32 (one block per graph) ----------------
__global__ __launch_bounds__(256)
void head2_kernel(const float* __restrict__ sums, const int* __restrict__ batch,
                  const int* __restrict__ flags,
                  const float* __restrict__ doc, const float* __restrict__ doc_w, const float* __restrict__ doc_b,
                  const float* __restrict__ ln_g, const float* __restrict__ ln_b,
                  const float* __restrict__ fus_w, const float* __restrict__ fus_b,
                  const float* __restrict__ task_w, const float* __restrict__ task_b,
                  const float* __restrict__ time_w, const float* __restrict__ time_b,
                  float* __restrict__ out_task, float* __restrict__ out_time)
{
  const int g = blockIdx.x;
  const int t = threadIdx.x;
  __shared__ float fusion[256];
  __shared__ float fh[128];
  __shared__ float dpart[256];
  __shared__ int seg[2];

  if (t < 2) {
    int f = flags[1];
    int target = g + t, lo = 0, hi = N_NODES;
    while (lo < hi) { int mid = (lo + hi) >> 1; if (geti(batch, mid, f) < target) lo = mid + 1; else hi = mid; }
    seg[t] = lo;
  }
  {
    int c = t & 127, kh = t >> 7;
    float s = 0.f;
    for (int k = kh * 384; k < kh * 384 + 384; ++k) s += doc[g * 768 + k] * doc_w[k * 128 + c];
    dpart[t] = s;
  }
  __syncthreads();

  if (t < 128) {
    float cnt = (float)(seg[1] - seg[0]);
    fusion[t] = sums[g * 128 + t] / fmaxf(cnt, 1.f);
  } else {
    int c = t - 128;
    fusion[t] = fmaxf(dpart[c] + dpart[c + 128] + doc_b[c], 0.f);
  }
  __syncthreads();

  float mu = 0.f;
  for (int i = 0; i < 256; ++i) mu += fusion[i];
  mu *= (1.f / 256.f);
  float var = 0.f;
  for (int i = 0; i < 256; ++i) { float d = fusion[i] - mu; var += d * d; }
  var *= (1.f / 256.f);
  float inv = rsqrtf(var + 1e-5f);
  float norm = (fusion[t] - mu) * inv * ln_g[t] + ln_b[t];
  __syncthreads();
  fusion[t] = norm;
  __syncthreads();

  if (t < 128) {
    float s = 0.f;
    for (int k = 0; k < 256; ++k) s += fusion[k] * fus_w[k * 128 + t];
    s += fus_b[t];
    fh[t] = fmaxf(s, 0.f);
  }
  __syncthreads();

  if (t < 32) {
    float s = 0.f;
    for (int k = 0; k < 128; ++k) s += fh[k] * task_w[k * 32 + t];
    s += task_b[t];
    out_task[g * 32 + t] = s;
  }
  if (t == 32) {
    float s = 0.f;
    for (int k = 0; k < 128; ++k) s += fh[k] * time_w[k];
    s += time_b[0];
    out_time[g] = s;
  }
}

// ---------------- launch ----------------
extern "C" void kernel_launch(void* const* d_in, const int* in_sizes, int n_in,
                              void* d_out, int out_size, void* d_ws, size_t ws_size,
                              hipStream_t stream)
{
  const float* x        = (const float*)d_in[0];
  const float* doc      = (const float*)d_in[1];
  const int*   ei       = (const int*)d_in[2];
  const int*   batch    = (const int*)d_in[3];
  const float* node_w   = (const float*)d_in[4];
  const float* node_b   = (const float*)d_in[5];
  const float* ggnn_w   = (const float*)d_in[6];
  const float* gru_w_ih = (const float*)d_in[7];
  const float* gru_b_ih = (const float*)d_in[8];
  const float* gru_w_hh = (const float*)d_in[9];
  const float* gru_b_hh = (const float*)d_in[10];
  const float* doc_w    = (const float*)d_in[11];
  const float* doc_b    = (const float*)d_in[12];
  const float* ln_g     = (const float*)d_in[13];
  const float* ln_b     = (const float*)d_in[14];
  const float* fus_w    = (const float*)d_in[15];
  const float* fus_b    = (const float*)d_in[16];
  const float* task_w   = (const float*)d_in[17];
  const float* task_b   = (const float*)d_in[18];
  const float* time_w   = (const float*)d_in[19];
  const float* time_b   = (const float*)d_in[20];

  char* ws = (char*)d_ws;
  size_t off = 0;
  auto alloc = [&](size_t bytes) -> void* {
    void* p = ws + off;
    off = (off + bytes + 255) & ~(size_t)255;
    return p;
  };
  u16* aggb   = (u16*)alloc((size_t)N_NODES * 128 * 2);
  u16* hA     = (u16*)alloc((size_t)N_NODES * 128 * 2);
  u16* hB     = (u16*)alloc((size_t)N_NODES * 128 * 2);
  u16* nwT    = (u16*)alloc(64 * 128 * 2);
  u16* b2p    = (u16*)alloc(3 * 8 * 1536 * 8 * 2);
  float* wp   = (float*)alloc(3 * 128 * 384 * 4);
  float* sums = (float*)alloc(N_GRAPHS * 128 * 4);
  int* counts = (int*)alloc((size_t)N_NODES * 4);
  int* cursor = (int*)alloc((size_t)N_NODES * 4);
  int* offs   = (int*)alloc((size_t)(N_NODES + 1) * 4);
  int* ssrc   = (int*)alloc((size_t)N_EDGES * 4);
  int* bsum   = (int*)alloc(SCAN_BLOCKS * 4);
  int* bbase  = (int*)alloc(SCAN_BLOCKS * 4);
  int* flags  = (int*)alloc(2 * 4);

  hipMemsetAsync(counts, 0, (size_t)N_NODES * 4, stream);
  hipMemsetAsync(cursor, 0, (size_t)N_NODES * 4, stream);
  hipMemsetAsync(sums, 0, (size_t)N_GRAPHS * 128 * 4, stream);

  detect_i64_kernel<<<1, 64, 0, stream>>>(ei, batch, flags);
  hist_kernel<<<(N_EDGES + 255) / 256, 256, 0, stream>>>(ei, flags, counts);
  scanA_kernel<<<SCAN_BLOCKS, 1024, 0, stream>>>(counts, bsum);
  scanB_kernel<<<1, 64, 0, stream>>>(bsum, bbase, offs);
  scanC_kernel<<<SCAN_BLOCKS, 1024, 0, stream>>>(counts, bbase, offs);
  scatter_kernel<<<(N_EDGES + 255) / 256, 256, 0, stream>>>(ei, flags, offs, cursor, ssrc);

  transpose_kernel<<<(64 * 128 + 255) / 256, 256, 0, stream>>>(node_w, nwT, 64, 128);
  wprime_kernel<<<(3 * 128 * 384 + 255) / 256, 256, 0, stream>>>(ggnn_w, gru_w_ih, wp);
  for (int l = 0; l < 3; ++l)
    build_b2p_kernel<<<(8 * 1536 * 8 + 255) / 256, 256, 0, stream>>>(
        wp + l * 128 * 384, gru_w_hh, b2p + (size_t)l * 8 * 1536 * 8);

  const int GB = (N_NODES + 63) / 64;  // 1563
  nodeproj_gemm<<<GB, 256, 0, stream>>>(x, nwT, node_b, hA, N_NODES);

  u16* hcur = hA;
  u16* hnext = hB;
  for (int l = 0; l < 3; ++l) {
    agg_kernel<<<(N_NODES + 3) / 4, 256, 0, stream>>>(hcur, ssrc, offs, aggb);
    gru_gemm<<<GB, 256, 0, stream>>>(aggb, hcur, b2p + (size_t)l * 8 * 1536 * 8,
                                     gru_b_ih, gru_b_hh, hnext, N_NODES);
    u16* tmp = hcur; hcur = hnext; hnext = tmp;
  }

  pool_kernel<<<(N_NODES + 127) / 128, 256, 0, stream>>>(hcur, batch, flags, sums);

  float* out_task = (float*)d_out;
  float* out_time = out_task + N_GRAPHS * 32;
  head2_kernel<<<N_GRAPHS, 256, 0, stream>>>(sums, batch, flags, doc, doc_w, doc_b, ln_g, ln_b,
                                             fus_w, fus_b, task_w, task_b, time_w, time_b,
                                             out_task, out_time);
}

// Round 6
// 833.930 us; speedup vs baseline: 1.9670x; 1.2969x over previous
//
#include <hip/hip_runtime.h>

#define N_NODES  100000
#define N_EDGES  1600000
#define N_GRAPHS 128
#define SCAN_BLOCKS 98   // ceil(100000/1024)

typedef unsigned short u16;
typedef unsigned int   u32;
typedef __attribute__((ext_vector_type(8))) short short8;
typedef __attribute__((ext_vector_type(4))) float f32x4;

__device__ __forceinline__ float bf2f(u16 v) {
  union { u32 i; float f; } u; u.i = ((u32)v) << 16; return u.f;
}
__device__ __forceinline__ u16 f2bf(float f) {
  union { float f; u32 i; } u; u.f = f;
  u32 r = (u.i + 0x7fffu + ((u.i >> 16) & 1u)) >> 16;
  return (u16)r;
}
__device__ __forceinline__ float sigmoid_f(float x) { return 1.f / (1.f + __expf(-x)); }
__device__ __forceinline__ float tanh_f(float x) {
  x = fminf(15.f, fmaxf(-15.f, x));
  float e = __expf(2.f * x);
  return (e - 1.f) / (e + 1.f);
}
__device__ __forceinline__ int geti(const int* __restrict__ p, int i, int is64) {
  return p[is64 ? (2 * i) : i];
}

// Detect whether edge_index / batch are int64 (all sampled odd words == 0) or int32.
__global__ void detect_i64_kernel(const int* __restrict__ ei, const int* __restrict__ batch,
                                  int* __restrict__ flags) {
  int lane = threadIdx.x;  // 64
  {
    long long q = (long long)lane * (3200000 / 2 - 1) / 63;
    int pos = (int)(2 * q + 1);
    unsigned long long m = __ballot(ei[pos] != 0);
    if (lane == 0) flags[0] = (m == 0ull) ? 1 : 0;
  }
  {
    long long q = (long long)lane * (100000 / 2 - 1) / 63;
    int pos = (int)(2 * q + 1);
    unsigned long long m = __ballot(batch[pos] != 0);
    if (lane == 0) flags[1] = (m == 0ull) ? 1 : 0;
  }
}

// ---------------- CSR build ----------------
__global__ void hist_kernel(const int* __restrict__ ei, const int* __restrict__ flags,
                            int* __restrict__ counts) {
  int e = blockIdx.x * 256 + threadIdx.x;
  if (e < N_EDGES) {
    int f = flags[0];
    atomicAdd(&counts[geti(ei, N_EDGES + e, f)], 1);
  }
}

__global__ __launch_bounds__(1024)
void scanA_kernel(const int* __restrict__ counts, int* __restrict__ blocksums) {
  __shared__ int red[16];
  int i = blockIdx.x * 1024 + threadIdx.x;
  int v = (i < N_NODES) ? counts[i] : 0;
  for (int o = 32; o > 0; o >>= 1) v += __shfl_down(v, o, 64);
  int wv = threadIdx.x >> 6, lane = threadIdx.x & 63;
  if (lane == 0) red[wv] = v;
  __syncthreads();
  if (threadIdx.x < 16) {
    int s = red[threadIdx.x];
    for (int o = 8; o > 0; o >>= 1) s += __shfl_down(s, o, 64);
    if (threadIdx.x == 0) blocksums[blockIdx.x] = s;
  }
}

__global__ void scanB_kernel(const int* __restrict__ blocksums, int* __restrict__ blockbase,
                             int* __restrict__ offsets) {
  if (threadIdx.x == 0) {
    int run = 0;
    for (int b = 0; b < SCAN_BLOCKS; ++b) { blockbase[b] = run; run += blocksums[b]; }
    offsets[N_NODES] = run;
  }
}

__global__ __launch_bounds__(1024)
void scanC_kernel(const int* __restrict__ counts, const int* __restrict__ blockbase,
                  int* __restrict__ offsets) {
  __shared__ int buf[1024];
  int t = threadIdx.x;
  int i = blockIdx.x * 1024 + t;
  int v = (i < N_NODES) ? counts[i] : 0;
  buf[t] = v;
  __syncthreads();
  for (int o = 1; o < 1024; o <<= 1) {
    int add = (t >= o) ? buf[t - o] : 0;
    __syncthreads();
    buf[t] += add;
    __syncthreads();
  }
  if (i < N_NODES) offsets[i] = buf[t] - v + blockbase[blockIdx.x];
}

__global__ void scatter_kernel(const int* __restrict__ ei, const int* __restrict__ flags,
                               const int* __restrict__ offsets,
                               int* __restrict__ cursor, int* __restrict__ ssrc) {
  int e = blockIdx.x * 256 + threadIdx.x;
  if (e < N_EDGES) {
    int f = flags[0];
    int d = geti(ei, N_EDGES + e, f);
    int pos = offsets[d] + atomicAdd(&cursor[d], 1);
    ssrc[pos] = geti(ei, e, f);
  }
}

// ---------------- weight prep ----------------
// f32 [K][N] row-major -> bf16 [N][K]
__global__ void transpose_kernel(const float* __restrict__ in, u16* __restrict__ out, int K, int N) {
  int i = blockIdx.x * 256 + threadIdx.x;
  if (i < K * N) {
    int k = i / N, n = i % N;
    out[n * K + k] = f2bf(in[i]);
  }
}

// W'_l[k][c] = sum_j ggnn_w[l][k][j] * w_ih[j][c]   (f32, [3][128][384])
__global__ void wprime_kernel(const float* __restrict__ ggnn_w, const float* __restrict__ w_ih,
                              float* __restrict__ wp) {
  int i = blockIdx.x * 256 + threadIdx.x;
  if (i >= 3 * 128 * 384) return;
  int l = i / (128 * 384), r = i % (128 * 384), k = r / 384, c = r % 384;
  const float* W = ggnn_w + l * 128 * 128;
  float s = 0.f;
  for (int j = 0; j < 128; ++j) s += W[k * 128 + j] * w_ih[j * 384 + c];
  wp[i] = s;
}

// Packed GRU weight: b2p[ci][idx][e] u16, ci=0..7 (k-chunk), idx = ko*384 + n_lin,
// e=0..7. Zero quadrants excluded (ci<4: W' cols r|z|in; ci>=4: w_hh cols r|z|hn).
__global__ void build_b2p_kernel(const float* __restrict__ wp, const float* __restrict__ w_hh,
                                 u16* __restrict__ b2p) {
  int g = blockIdx.x * 256 + threadIdx.x;
  if (g >= 8 * 1536 * 8) return;
  int e = g & 7;
  int grp = g >> 3;
  int ci = grp / 1536;
  int idx = grp % 1536;
  int n_lin = idx % 384;
  int ko = idx / 384;
  int k = ci * 32 + ko * 8 + e;
  float v = (k < 128) ? wp[k * 384 + n_lin] : w_hh[(k - 128) * 384 + n_lin];
  b2p[g] = f2bf(v);
}

// ---------------- node projection GEMM (f32 A -> bf16 frags) ----------------
__global__ __launch_bounds__(256)
void nodeproj_gemm(const float* __restrict__ A, const u16* __restrict__ BT,
                   const float* __restrict__ bias, u16* __restrict__ out, int M)
{
  constexpr int K_DIM = 64, N_DIM = 128, NT = 8, NCHUNK = 2;
  __shared__ u16 B_lds[N_DIM * 40];
  const int tid = threadIdx.x, lane = tid & 63, w = tid >> 6;
  const int strip = blockIdx.x * 64;
  const int ksub = (lane >> 4) * 8;
  union Frag { uint4 u; short8 s; };
  Frag af[NCHUNK];
  const int m_node = strip + w * 16 + (lane & 15);
  const bool avalid = (m_node < M);
#pragma unroll
  for (int ci = 0; ci < NCHUNK; ++ci) {
    int k0 = ci * 32 + ksub;
    short8 sv = {0,0,0,0,0,0,0,0};
    if (avalid) {
      const float* p = A + (size_t)m_node * K_DIM + k0;
      float4 f0 = *(const float4*)p;
      float4 f1 = *(const float4*)(p + 4);
      sv[0]=(short)f2bf(f0.x); sv[1]=(short)f2bf(f0.y); sv[2]=(short)f2bf(f0.z); sv[3]=(short)f2bf(f0.w);
      sv[4]=(short)f2bf(f1.x); sv[5]=(short)f2bf(f1.y); sv[6]=(short)f2bf(f1.z); sv[7]=(short)f2bf(f1.w);
    }
    af[ci].s = sv;
  }
  f32x4 acc[NT];
#pragma unroll
  for (int t = 0; t < NT; ++t) acc[t] = {0.f, 0.f, 0.f, 0.f};
  const int boff = (lane & 15) * 40 + ksub;
#pragma unroll
  for (int ci = 0; ci < NCHUNK; ++ci) {
    if (ci) __syncthreads();
    for (int g = tid; g < N_DIM * 4; g += 256) {
      int n = g >> 2, ko = g & 3;
      uint4 bv = *(const uint4*)(BT + (size_t)n * K_DIM + ci * 32 + ko * 8);
      *(uint4*)(&B_lds[n * 40 + ko * 8]) = bv;
    }
    __syncthreads();
    short8 a = af[ci].s;
#pragma unroll
    for (int t = 0; t < NT; ++t) {
      const short8 b = *(const short8*)(&B_lds[t * 16 * 40 + boff]);
      acc[t] = __builtin_amdgcn_mfma_f32_16x16x32_bf16(a, b, acc[t], 0, 0, 0);
    }
  }
  const int mrow = (lane >> 4) * 4;
#pragma unroll
  for (int t = 0; t < NT; ++t) {
    int col = t * 16 + (lane & 15);
    float bv = bias[col];
#pragma unroll
    for (int r = 0; r < 4; ++r) {
      int node = strip + w * 16 + mrow + r;
      if (node < M) out[(size_t)node * N_DIM + col] = f2bf(fmaxf(acc[t][r] + bv, 0.f));
    }
  }
}

// ---------------- GRU GEMM: [agg|h] @ B2 -> GRU epilogue ----------------
// 256 thr = 4 waves; 64 rows/block. Wave w owns col-tiles t = w+4j (j=0..7);
// zero quadrants skipped (in: k<128 only; hn: k>=128 only).
// NOTE: plain __launch_bounds__(256) — a min-waves/EU arg here caps the unified
// VGPR+AGPR budget below the 128-reg accumulator and forces scratch spill
// (round 5: VGPR_Count=84, WRITE_SIZE 325 MB of spill traffic, +17% dur).
__global__ __launch_bounds__(256)
void gru_gemm(const u16* __restrict__ agg, const u16* __restrict__ h,
              const u16* __restrict__ b2p, const float* __restrict__ b_ih,
              const float* __restrict__ b_hh, u16* __restrict__ hout, int M)
{
  __shared__ u16 B_lds[384 * 40];   // [n_lin][32k + 8 pad]; writes & reads both clean 2-way
  const int tid  = threadIdx.x;
  const int lane = tid & 63;
  const int w    = tid >> 6;
  const int strip = blockIdx.x * 64;
  const int lrow = lane & 15;
  const int quad = lane >> 4;
  const int ksub = quad * 8;

  f32x4 acc[4][8];
#pragma unroll
  for (int s = 0; s < 4; ++s)
#pragma unroll
    for (int j = 0; j < 8; ++j) acc[s][j] = {0.f, 0.f, 0.f, 0.f};

  union Frag { uint4 u; short8 s8; };
  int node_a[4]; bool aval[4];
#pragma unroll
  for (int s = 0; s < 4; ++s) { node_a[s] = strip + s * 16 + lrow; aval[s] = node_a[s] < M; }

#pragma unroll
  for (int ci = 0; ci < 8; ++ci) {
    Frag a[4];
    const u16* abase = (ci < 4) ? (agg + ci * 32 + ksub) : (h + (ci - 4) * 32 + ksub);
#pragma unroll
    for (int s = 0; s < 4; ++s) {
      uint4 v = {0u, 0u, 0u, 0u};
      if (aval[s]) v = *(const uint4*)(abase + (size_t)node_a[s] * 128);
      a[s].u = v;
    }
    if (ci) __syncthreads();
    const u16* gsrc = b2p + (size_t)ci * (1536 * 8);
#pragma unroll
    for (int it = 0; it < 6; ++it) {
      int idx = tid + it * 256;
      int n_lin = idx % 384, ko = idx / 384;
      uint4 bv = *(const uint4*)(gsrc + (size_t)idx * 8);
      *(uint4*)(&B_lds[n_lin * 40 + ko * 8]) = bv;
    }
    __syncthreads();
#pragma unroll
    for (int j = 0; j < 8; ++j) {
      const int t = w + 4 * j;
      const bool active = (ci < 4) ? (t < 24) : (t < 16 || t >= 24);
      if (!active) continue;   // wave-uniform
      const int rbase = (ci >= 4 && t >= 24) ? (t - 8) * 16 : t * 16;
      const short8 b = *(const short8*)(&B_lds[(rbase + lrow) * 40 + ksub]);
#pragma unroll
      for (int s = 0; s < 4; ++s)
        acc[s][j] = __builtin_amdgcn_mfma_f32_16x16x32_bf16(a[s].s8, b, acc[s][j], 0, 0, 0);
    }
  }

  // GRU epilogue: wave w covers h-cols (w+4j)*16.. for j=0,1
#pragma unroll
  for (int j = 0; j < 2; ++j) {
    const int c = (w + 4 * j) * 16 + lrow;
    const float br  = b_ih[c] + b_hh[c];
    const float bz  = b_ih[128 + c] + b_hh[128 + c];
    const float bin = b_ih[256 + c];
    const float bhn = b_hh[256 + c];
#pragma unroll
    for (int s = 0; s < 4; ++s) {
#pragma unroll
      for (int r = 0; r < 4; ++r) {
        const int node = strip + s * 16 + quad * 4 + r;
        if (node < M) {
          float rg = sigmoid_f(acc[s][j][r] + br);
          float zg = sigmoid_f(acc[s][j + 2][r] + bz);
          float hn = acc[s][j + 6][r] + bhn;
          float ng = tanh_f(acc[s][j + 4][r] + bin + rg * hn);
          float hp = bf2f(h[(size_t)node * 128 + c]);
          hout[(size_t)node * 128 + c] = f2bf((1.f - zg) * ng + zg * hp);
        }
      }
    }
  }
}

// ---------------- CSR aggregation: agg[n] = sum over in-edges of h[src], 8x MLP ----------------
__global__ __launch_bounds__(256)
void agg_kernel(const u16* __restrict__ m, const int* __restrict__ ssrc,
                const int* __restrict__ offsets, u16* __restrict__ agg)
{
  int node = blockIdx.x * 4 + (threadIdx.x >> 6);
  int lane = threadIdx.x & 63;
  if (node >= N_NODES) return;
  int beg = offsets[node], end = offsets[node + 1];
  float s0 = 0.f, s1 = 0.f;
  int e = beg;
  for (; e + 8 <= end; e += 8) {
    u32 v[8];
#pragma unroll
    for (int q = 0; q < 8; ++q) {
      int src = ssrc[e + q];
      v[q] = *(const u32*)(m + (size_t)src * 128 + lane * 2);
    }
#pragma unroll
    for (int q = 0; q < 8; ++q) {
      s0 += bf2f((u16)(v[q] & 0xffffu));
      s1 += bf2f((u16)(v[q] >> 16));
    }
  }
  for (; e < end; ++e) {
    int src = ssrc[e];
    u32 v = *(const u32*)(m + (size_t)src * 128 + lane * 2);
    s0 += bf2f((u16)(v & 0xffffu));
    s1 += bf2f((u16)(v >> 16));
  }
  u32 packed = (u32)f2bf(s0) | ((u32)f2bf(s1) << 16);
  *(u32*)(agg + (size_t)node * 128 + lane * 2) = packed;
}

// ---------------- parallel segmented mean-pool (batch is sorted) ----------------
__global__ __launch_bounds__(256)
void pool_kernel(const u16* __restrict__ h, const int* __restrict__ batch,
                 const int* __restrict__ flags, float* __restrict__ sums)
{
  const int c = threadIdx.x & 127;
  const int half = threadIdx.x >> 7;
  const int base = blockIdx.x * 128;
  const int f = flags[1];
  int gcur = -1; float s = 0.f;
  for (int i = half; i < 128; i += 2) {
    int n = base + i;
    if (n >= N_NODES) break;
    int g = geti(batch, n, f);
    if (g != gcur) {
      if (gcur >= 0) atomicAdd(&sums[gcur * 128 + c], s);
      s = 0.f; gcur = g;
    }
    s += bf2f(h[(size_t)n * 128 + c]);
  }
  if (gcur >= 0) atomicAdd(&sums[gcur * 128 + c], s);
}

// ---------------- doc proj + LN + fusion + heads, f32 (one block per graph) ----------------
__global__ __launch_bounds__(256)
void head2_kernel(const float* __restrict__ sums, const int* __restrict__ batch,
                  const int* __restrict__ flags,
                  const float* __restrict__ doc, const float* __restrict__ doc_w, const float* __restrict__ doc_b,
                  const float* __restrict__ ln_g, const float* __restrict__ ln_b,
                  const float* __restrict__ fus_w, const float* __restrict__ fus_b,
                  const float* __restrict__ task_w, const float* __restrict__ task_b,
                  const float* __restrict__ time_w, const float* __restrict__ time_b,
                  float* __restrict__ out_task, float* __restrict__ out_time)
{
  const int g = blockIdx.x;
  const int t = threadIdx.x;
  __shared__ float fusion[256];
  __shared__ float fh[128];
  __shared__ float dpart[256];
  __shared__ int seg[2];

  if (t < 2) {
    int f = flags[1];
    int target = g + t, lo = 0, hi = N_NODES;
    while (lo < hi) { int mid = (lo + hi) >> 1; if (geti(batch, mid, f) < target) lo = mid + 1; else hi = mid; }
    seg[t] = lo;
  }
  {
    int c = t & 127, kh = t >> 7;
    float s = 0.f;
    for (int k = kh * 384; k < kh * 384 + 384; ++k) s += doc[g * 768 + k] * doc_w[k * 128 + c];
    dpart[t] = s;
  }
  __syncthreads();

  if (t < 128) {
    float cnt = (float)(seg[1] - seg[0]);
    fusion[t] = sums[g * 128 + t] / fmaxf(cnt, 1.f);
  } else {
    int c = t - 128;
    fusion[t] = fmaxf(dpart[c] + dpart[c + 128] + doc_b[c], 0.f);
  }
  __syncthreads();

  float mu = 0.f;
  for (int i = 0; i < 256; ++i) mu += fusion[i];
  mu *= (1.f / 256.f);
  float var = 0.f;
  for (int i = 0; i < 256; ++i) { float d = fusion[i] - mu; var += d * d; }
  var *= (1.f / 256.f);
  float inv = rsqrtf(var + 1e-5f);
  float norm = (fusion[t] - mu) * inv * ln_g[t] + ln_b[t];
  __syncthreads();
  fusion[t] = norm;
  __syncthreads();

  if (t < 128) {
    float s = 0.f;
    for (int k = 0; k < 256; ++k) s += fusion[k] * fus_w[k * 128 + t];
    s += fus_b[t];
    fh[t] = fmaxf(s, 0.f);
  }
  __syncthreads();

  if (t < 32) {
    float s = 0.f;
    for (int k = 0; k < 128; ++k) s += fh[k] * task_w[k * 32 + t];
    s += task_b[t];
    out_task[g * 32 + t] = s;
  }
  if (t == 32) {
    float s = 0.f;
    for (int k = 0; k < 128; ++k) s += fh[k] * time_w[k];
    s += time_b[0];
    out_time[g] = s;
  }
}

// ---------------- launch ----------------
extern "C" void kernel_launch(void* const* d_in, const int* in_sizes, int n_in,
                              void* d_out, int out_size, void* d_ws, size_t ws_size,
                              hipStream_t stream)
{
  const float* x        = (const float*)d_in[0];
  const float* doc      = (const float*)d_in[1];
  const int*   ei       = (const int*)d_in[2];
  const int*   batch    = (const int*)d_in[3];
  const float* node_w   = (const float*)d_in[4];
  const float* node_b   = (const float*)d_in[5];
  const float* ggnn_w   = (const float*)d_in[6];
  const float* gru_w_ih = (const float*)d_in[7];
  const float* gru_b_ih = (const float*)d_in[8];
  const float* gru_w_hh = (const float*)d_in[9];
  const float* gru_b_hh = (const float*)d_in[10];
  const float* doc_w    = (const float*)d_in[11];
  const float* doc_b    = (const float*)d_in[12];
  const float* ln_g     = (const float*)d_in[13];
  const float* ln_b     = (const float*)d_in[14];
  const float* fus_w    = (const float*)d_in[15];
  const float* fus_b    = (const float*)d_in[16];
  const float* task_w   = (const float*)d_in[17];
  const float* task_b   = (const float*)d_in[18];
  const float* time_w   = (const float*)d_in[19];
  const float* time_b   = (const float*)d_in[20];

  char* ws = (char*)d_ws;
  size_t off = 0;
  auto alloc = [&](size_t bytes) -> void* {
    void* p = ws + off;
    off = (off + bytes + 255) & ~(size_t)255;
    return p;
  };
  u16* aggb   = (u16*)alloc((size_t)N_NODES * 128 * 2);
  u16* hA     = (u16*)alloc((size_t)N_NODES * 128 * 2);
  u16* hB     = (u16*)alloc((size_t)N_NODES * 128 * 2);
  u16* nwT    = (u16*)alloc(64 * 128 * 2);
  u16* b2p    = (u16*)alloc(3 * 8 * 1536 * 8 * 2);
  float* wp   = (float*)alloc(3 * 128 * 384 * 4);
  float* sums = (float*)alloc(N_GRAPHS * 128 * 4);
  int* counts = (int*)alloc((size_t)N_NODES * 4);
  int* cursor = (int*)alloc((size_t)N_NODES * 4);
  int* offs   = (int*)alloc((size_t)(N_NODES + 1) * 4);
  int* ssrc   = (int*)alloc((size_t)N_EDGES * 4);
  int* bsum   = (int*)alloc(SCAN_BLOCKS * 4);
  int* bbase  = (int*)alloc(SCAN_BLOCKS * 4);
  int* flags  = (int*)alloc(2 * 4);

  hipMemsetAsync(counts, 0, (size_t)N_NODES * 4, stream);
  hipMemsetAsync(cursor, 0, (size_t)N_NODES * 4, stream);
  hipMemsetAsync(sums, 0, (size_t)N_GRAPHS * 128 * 4, stream);

  detect_i64_kernel<<<1, 64, 0, stream>>>(ei, batch, flags);
  hist_kernel<<<(N_EDGES + 255) / 256, 256, 0, stream>>>(ei, flags, counts);
  scanA_kernel<<<SCAN_BLOCKS, 1024, 0, stream>>>(counts, bsum);
  scanB_kernel<<<1, 64, 0, stream>>>(bsum, bbase, offs);
  scanC_kernel<<<SCAN_BLOCKS, 1024, 0, stream>>>(counts, bbase, offs);
  scatter_kernel<<<(N_EDGES + 255) / 256, 256, 0, stream>>>(ei, flags, offs, cursor, ssrc);

  transpose_kernel<<<(64 * 128 + 255) / 256, 256, 0, stream>>>(node_w, nwT, 64, 128);
  wprime_kernel<<<(3 * 128 * 384 + 255) / 256, 256, 0, stream>>>(ggnn_w, gru_w_ih, wp);
  for (int l = 0; l < 3; ++l)
    build_b2p_kernel<<<(8 * 1536 * 8 + 255) / 256, 256, 0, stream>>>(
        wp + l * 128 * 384, gru_w_hh, b2p + (size_t)l * 8 * 1536 * 8);

  const int GB = (N_NODES + 63) / 64;  // 1563
  nodeproj_gemm<<<GB, 256, 0, stream>>>(x, nwT, node_b, hA, N_NODES);

  u16* hcur = hA;
  u16* hnext = hB;
  for (int l = 0; l < 3; ++l) {
    agg_kernel<<<(N_NODES + 3) / 4, 256, 0, stream>>>(hcur, ssrc, offs, aggb);
    gru_gemm<<<GB, 256, 0, stream>>>(aggb, hcur, b2p + (size_t)l * 8 * 1536 * 8,
                                     gru_b_ih, gru_b_hh, hnext, N_NODES);
    u16* tmp = hcur; hcur = hnext; hnext = tmp;
  }

  pool_kernel<<<(N_NODES + 127) / 128, 256, 0, stream>>>(hcur, batch, flags, sums);

  float* out_task = (float*)d_out;
  float* out_time = out_task + N_GRAPHS * 32;
  head2_kernel<<<N_GRAPHS, 256, 0, stream>>>(sums, batch, flags, doc, doc_w, doc_b, ln_g, ln_b,
                                             fus_w, fus_b, task_w, task_b, time_w, time_b,
                                             out_task, out_time);
}

// Round 7
// 828.533 us; speedup vs baseline: 1.9798x; 1.0065x over previous
//
#include <hip/hip_runtime.h>

#define N_NODES  100000
#define N_EDGES  1600000
#define N_GRAPHS 128
#define SCAN_BLOCKS 98   // ceil(100000/1024)

typedef unsigned short u16;
typedef unsigned int   u32;
typedef __attribute__((ext_vector_type(8))) short short8;
typedef __attribute__((ext_vector_type(4))) float f32x4;

__device__ __forceinline__ float bf2f(u16 v) {
  union { u32 i; float f; } u; u.i = ((u32)v) << 16; return u.f;
}
__device__ __forceinline__ u16 f2bf(float f) {
  union { float f; u32 i; } u; u.f = f;
  u32 r = (u.i + 0x7fffu + ((u.i >> 16) & 1u)) >> 16;
  return (u16)r;
}
__device__ __forceinline__ float sigmoid_f(float x) { return 1.f / (1.f + __expf(-x)); }
__device__ __forceinline__ float tanh_f(float x) {
  x = fminf(15.f, fmaxf(-15.f, x));
  float e = __expf(2.f * x);
  return (e - 1.f) / (e + 1.f);
}
__device__ __forceinline__ int geti(const int* __restrict__ p, int i, int is64) {
  return p[is64 ? (2 * i) : i];
}

// Detect whether edge_index / batch are int64 (all sampled odd words == 0) or int32.
__global__ void detect_i64_kernel(const int* __restrict__ ei, const int* __restrict__ batch,
                                  int* __restrict__ flags) {
  int lane = threadIdx.x;  // 64
  {
    long long q = (long long)lane * (3200000 / 2 - 1) / 63;
    int pos = (int)(2 * q + 1);
    unsigned long long m = __ballot(ei[pos] != 0);
    if (lane == 0) flags[0] = (m == 0ull) ? 1 : 0;
  }
  {
    long long q = (long long)lane * (100000 / 2 - 1) / 63;
    int pos = (int)(2 * q + 1);
    unsigned long long m = __ballot(batch[pos] != 0);
    if (lane == 0) flags[1] = (m == 0ull) ? 1 : 0;
  }
}

// ---------------- CSR build ----------------
// hist also records each edge's rank among its dst's edges -> scatter needs no atomics.
__global__ void hist_kernel(const int* __restrict__ ei, const int* __restrict__ flags,
                            int* __restrict__ counts, u16* __restrict__ rankb) {
  int e = blockIdx.x * 256 + threadIdx.x;
  if (e < N_EDGES) {
    int f = flags[0];
    int d = geti(ei, N_EDGES + e, f);
    int r = atomicAdd(&counts[d], 1);
    rankb[e] = (u16)r;   // max degree ~60 for this data; u16 safe
  }
}

__global__ __launch_bounds__(1024)
void scanA_kernel(const int* __restrict__ counts, int* __restrict__ blocksums) {
  __shared__ int red[16];
  int i = blockIdx.x * 1024 + threadIdx.x;
  int v = (i < N_NODES) ? counts[i] : 0;
  for (int o = 32; o > 0; o >>= 1) v += __shfl_down(v, o, 64);
  int wv = threadIdx.x >> 6, lane = threadIdx.x & 63;
  if (lane == 0) red[wv] = v;
  __syncthreads();
  if (threadIdx.x < 16) {
    int s = red[threadIdx.x];
    for (int o = 8; o > 0; o >>= 1) s += __shfl_down(s, o, 64);
    if (threadIdx.x == 0) blocksums[blockIdx.x] = s;
  }
}

__global__ void scanB_kernel(const int* __restrict__ blocksums, int* __restrict__ blockbase,
                             int* __restrict__ offsets) {
  if (threadIdx.x == 0) {
    int run = 0;
    for (int b = 0; b < SCAN_BLOCKS; ++b) { blockbase[b] = run; run += blocksums[b]; }
    offsets[N_NODES] = run;
  }
}

__global__ __launch_bounds__(1024)
void scanC_kernel(const int* __restrict__ counts, const int* __restrict__ blockbase,
                  int* __restrict__ offsets) {
  __shared__ int buf[1024];
  int t = threadIdx.x;
  int i = blockIdx.x * 1024 + t;
  int v = (i < N_NODES) ? counts[i] : 0;
  buf[t] = v;
  __syncthreads();
  for (int o = 1; o < 1024; o <<= 1) {
    int add = (t >= o) ? buf[t - o] : 0;
    __syncthreads();
    buf[t] += add;
    __syncthreads();
  }
  if (i < N_NODES) offsets[i] = buf[t] - v + blockbase[blockIdx.x];
}

// atomic-free scatter using precomputed ranks
__global__ void scatter_kernel(const int* __restrict__ ei, const int* __restrict__ flags,
                               const int* __restrict__ offsets, const u16* __restrict__ rankb,
                               int* __restrict__ ssrc) {
  int e = blockIdx.x * 256 + threadIdx.x;
  if (e < N_EDGES) {
    int f = flags[0];
    int d = geti(ei, N_EDGES + e, f);
    ssrc[offsets[d] + (int)rankb[e]] = geti(ei, e, f);
  }
}

// ---------------- weight prep ----------------
// f32 [K][N] row-major -> bf16 [N][K]
__global__ void transpose_kernel(const float* __restrict__ in, u16* __restrict__ out, int K, int N) {
  int i = blockIdx.x * 256 + threadIdx.x;
  if (i < K * N) {
    int k = i / N, n = i % N;
    out[n * K + k] = f2bf(in[i]);
  }
}

// W'_l[k][c] = sum_j ggnn_w[l][k][j] * w_ih[j][c]   (f32, [3][128][384])
__global__ void wprime_kernel(const float* __restrict__ ggnn_w, const float* __restrict__ w_ih,
                              float* __restrict__ wp) {
  int i = blockIdx.x * 256 + threadIdx.x;
  if (i >= 3 * 128 * 384) return;
  int l = i / (128 * 384), r = i % (128 * 384), k = r / 384, c = r % 384;
  const float* W = ggnn_w + l * 128 * 128;
  float s = 0.f;
  for (int j = 0; j < 128; ++j) s += W[k * 128 + j] * w_ih[j * 384 + c];
  wp[i] = s;
}

// Packed GRU weight: b2p[ci][idx][e] u16, ci=0..7 (k-chunk), idx = ko*384 + n_lin,
// e=0..7. Zero quadrants excluded (ci<4: W' cols r|z|in; ci>=4: w_hh cols r|z|hn).
__global__ void build_b2p_kernel(const float* __restrict__ wp, const float* __restrict__ w_hh,
                                 u16* __restrict__ b2p) {
  int g = blockIdx.x * 256 + threadIdx.x;
  if (g >= 8 * 1536 * 8) return;
  int e = g & 7;
  int grp = g >> 3;
  int ci = grp / 1536;
  int idx = grp % 1536;
  int n_lin = idx % 384;
  int ko = idx / 384;
  int k = ci * 32 + ko * 8 + e;
  float v = (k < 128) ? wp[k * 384 + n_lin] : w_hh[(k - 128) * 384 + n_lin];
  b2p[g] = f2bf(v);
}

// ---------------- node projection GEMM (f32 A -> bf16 frags) ----------------
__global__ __launch_bounds__(256)
void nodeproj_gemm(const float* __restrict__ A, const u16* __restrict__ BT,
                   const float* __restrict__ bias, u16* __restrict__ out, int M)
{
  constexpr int K_DIM = 64, N_DIM = 128, NT = 8, NCHUNK = 2;
  __shared__ u16 B_lds[N_DIM * 40];
  const int tid = threadIdx.x, lane = tid & 63, w = tid >> 6;
  const int strip = blockIdx.x * 64;
  const int ksub = (lane >> 4) * 8;
  union Frag { uint4 u; short8 s; };
  Frag af[NCHUNK];
  const int m_node = strip + w * 16 + (lane & 15);
  const bool avalid = (m_node < M);
#pragma unroll
  for (int ci = 0; ci < NCHUNK; ++ci) {
    int k0 = ci * 32 + ksub;
    short8 sv = {0,0,0,0,0,0,0,0};
    if (avalid) {
      const float* p = A + (size_t)m_node * K_DIM + k0;
      float4 f0 = *(const float4*)p;
      float4 f1 = *(const float4*)(p + 4);
      sv[0]=(short)f2bf(f0.x); sv[1]=(short)f2bf(f0.y); sv[2]=(short)f2bf(f0.z); sv[3]=(short)f2bf(f0.w);
      sv[4]=(short)f2bf(f1.x); sv[5]=(short)f2bf(f1.y); sv[6]=(short)f2bf(f1.z); sv[7]=(short)f2bf(f1.w);
    }
    af[ci].s = sv;
  }
  f32x4 acc[NT];
#pragma unroll
  for (int t = 0; t < NT; ++t) acc[t] = {0.f, 0.f, 0.f, 0.f};
  const int boff = (lane & 15) * 40 + ksub;
#pragma unroll
  for (int ci = 0; ci < NCHUNK; ++ci) {
    if (ci) __syncthreads();
    for (int g = tid; g < N_DIM * 4; g += 256) {
      int n = g >> 2, ko = g & 3;
      uint4 bv = *(const uint4*)(BT + (size_t)n * K_DIM + ci * 32 + ko * 8);
      *(uint4*)(&B_lds[n * 40 + ko * 8]) = bv;
    }
    __syncthreads();
    short8 a = af[ci].s;
#pragma unroll
    for (int t = 0; t < NT; ++t) {
      const short8 b = *(const short8*)(&B_lds[t * 16 * 40 + boff]);
      acc[t] = __builtin_amdgcn_mfma_f32_16x16x32_bf16(a, b, acc[t], 0, 0, 0);
    }
  }
  const int mrow = (lane >> 4) * 4;
#pragma unroll
  for (int t = 0; t < NT; ++t) {
    int col = t * 16 + (lane & 15);
    float bv = bias[col];
#pragma unroll
    for (int r = 0; r < 4; ++r) {
      int node = strip + w * 16 + mrow + r;
      if (node < M) out[(size_t)node * N_DIM + col] = f2bf(fmaxf(acc[t][r] + bv, 0.f));
    }
  }
}

// ---------------- GRU GEMM: [agg|h] @ B2 -> GRU epilogue ----------------
// 512 thr = 8 waves; 128 rows/block. Wave w owns col-tiles t=w+8j, j=0..2; with the
// zero-free packed B, every j is active every chunk (j=2 is `in` for k<128, `hn` for
// k>=128 -> separate acc slots 2/3). A-fragments double-buffered across chunks.
// Plain __launch_bounds__ — min-waves arg caused acc spill in round 5.
__global__ __launch_bounds__(512)
void gru_gemm(const u16* __restrict__ agg, const u16* __restrict__ h,
              const u16* __restrict__ b2p, const float* __restrict__ b_ih,
              const float* __restrict__ b_hh, u16* __restrict__ hout, int M)
{
  __shared__ u16 B_lds[1536 * 8];   // 24 KB, idx-order: [ko*384+n_lin][8]
  const int tid  = threadIdx.x;
  const int lane = tid & 63;
  const int w    = tid >> 6;        // 0..7
  const int strip0 = blockIdx.x * 128;
  const int lrow = lane & 15;
  const int quad = lane >> 4;
  const int ksub = quad * 8;

  f32x4 acc[8][4];
#pragma unroll
  for (int s = 0; s < 8; ++s)
#pragma unroll
    for (int j = 0; j < 4; ++j) acc[s][j] = {0.f, 0.f, 0.f, 0.f};

  union Frag { uint4 u; short8 s8; };
  int rowoff[8]; bool aval[8];
#pragma unroll
  for (int s = 0; s < 8; ++s) { rowoff[s] = strip0 + s * 16 + lrow; aval[s] = rowoff[s] < M; }

  Frag a_cur[8], a_nxt[8];
  {
    const u16* abase = agg + ksub;  // chunk 0
#pragma unroll
    for (int s = 0; s < 8; ++s) {
      uint4 v = {0u,0u,0u,0u};
      if (aval[s]) v = *(const uint4*)(abase + (size_t)rowoff[s] * 128);
      a_cur[s].u = v;
    }
  }

#pragma unroll
  for (int ci = 0; ci < 8; ++ci) {
    if (ci) __syncthreads();   // prev chunk's MFMA reads done before overwrite
    // stage packed B chunk: 1536 x 16B in idx order (lane-contiguous, conflict-free)
    const u16* gsrc = b2p + (size_t)ci * (1536 * 8);
#pragma unroll
    for (int it = 0; it < 3; ++it) {
      int idx = tid + it * 512;
      *(uint4*)(&B_lds[idx * 8]) = *(const uint4*)(gsrc + (size_t)idx * 8);
    }
    // prefetch next chunk's A while staging/barrier/MFMA are in flight
    if (ci < 7) {
      const int cn = ci + 1;
      const u16* abase = (cn < 4) ? (agg + cn * 32 + ksub) : (h + (cn - 4) * 32 + ksub);
#pragma unroll
      for (int s = 0; s < 8; ++s) {
        uint4 v = {0u,0u,0u,0u};
        if (aval[s]) v = *(const uint4*)(abase + (size_t)rowoff[s] * 128);
        a_nxt[s].u = v;
      }
    }
    __syncthreads();
#pragma unroll
    for (int j = 0; j < 3; ++j) {
      const int t = w + 8 * j;
      const short8 b = *(const short8*)(&B_lds[((size_t)(quad * 384 + t * 16 + lrow)) * 8]);
      if (j == 2 && ci >= 4) {
#pragma unroll
        for (int s = 0; s < 8; ++s)
          acc[s][3] = __builtin_amdgcn_mfma_f32_16x16x32_bf16(a_cur[s].s8, b, acc[s][3], 0, 0, 0);
      } else {
#pragma unroll
        for (int s = 0; s < 8; ++s)
          acc[s][j] = __builtin_amdgcn_mfma_f32_16x16x32_bf16(a_cur[s].s8, b, acc[s][j], 0, 0, 0);
      }
    }
    if (ci < 7) {
#pragma unroll
      for (int s = 0; s < 8; ++s) a_cur[s] = a_nxt[s];
    }
  }

  // GRU epilogue: this wave covers h-cols c = w*16 + lrow
  {
    const int c = w * 16 + lrow;
    const float br  = b_ih[c] + b_hh[c];
    const float bz  = b_ih[128 + c] + b_hh[128 + c];
    const float bin = b_ih[256 + c];
    const float bhn = b_hh[256 + c];
#pragma unroll
    for (int s = 0; s < 8; ++s) {
#pragma unroll
      for (int r = 0; r < 4; ++r) {
        const int node = strip0 + s * 16 + quad * 4 + r;
        if (node < M) {
          float rg = sigmoid_f(acc[s][0][r] + br);
          float zg = sigmoid_f(acc[s][1][r] + bz);
          float hn = acc[s][3][r] + bhn;
          float ng = tanh_f(acc[s][2][r] + bin + rg * hn);
          float hp = bf2f(h[(size_t)node * 128 + c]);
          hout[(size_t)node * 128 + c] = f2bf((1.f - zg) * ng + zg * hp);
        }
      }
    }
  }
}

// ---------------- CSR aggregation: agg[n] = sum over in-edges of h[src], 8x MLP ----------------
__global__ __launch_bounds__(256)
void agg_kernel(const u16* __restrict__ m, const int* __restrict__ ssrc,
                const int* __restrict__ offsets, u16* __restrict__ agg)
{
  int node = blockIdx.x * 4 + (threadIdx.x >> 6);
  int lane = threadIdx.x & 63;
  if (node >= N_NODES) return;
  int beg = offsets[node], end = offsets[node + 1];
  float s0 = 0.f, s1 = 0.f;
  int e = beg;
  for (; e + 8 <= end; e += 8) {
    u32 v[8];
#pragma unroll
    for (int q = 0; q < 8; ++q) {
      int src = ssrc[e + q];
      v[q] = *(const u32*)(m + (size_t)src * 128 + lane * 2);
    }
#pragma unroll
    for (int q = 0; q < 8; ++q) {
      s0 += bf2f((u16)(v[q] & 0xffffu));
      s1 += bf2f((u16)(v[q] >> 16));
    }
  }
  for (; e < end; ++e) {
    int src = ssrc[e];
    u32 v = *(const u32*)(m + (size_t)src * 128 + lane * 2);
    s0 += bf2f((u16)(v & 0xffffu));
    s1 += bf2f((u16)(v >> 16));
  }
  u32 packed = (u32)f2bf(s0) | ((u32)f2bf(s1) << 16);
  *(u32*)(agg + (size_t)node * 128 + lane * 2) = packed;
}

// ---------------- parallel segmented mean-pool (batch is sorted) ----------------
__global__ __launch_bounds__(256)
void pool_kernel(const u16* __restrict__ h, const int* __restrict__ batch,
                 const int* __restrict__ flags, float* __restrict__ sums)
{
  const int c = threadIdx.x & 127;
  const int half = threadIdx.x >> 7;
  const int base = blockIdx.x * 128;
  const int f = flags[1];
  int gcur = -1; float s = 0.f;
  for (int i = half; i < 128; i += 2) {
    int n = base + i;
    if (n >= N_NODES) break;
    int g = geti(batch, n, f);
    if (g != gcur) {
      if (gcur >= 0) atomicAdd(&sums[gcur * 128 + c], s);
      s = 0.f; gcur = g;
    }
    s += bf2f(h[(size_t)n * 128 + c]);
  }
  if (gcur >= 0) atomicAdd(&sums[gcur * 128 + c], s);
}

// ---------------- doc proj + LN + fusion + heads, f32 (one block per graph) ----------------
__global__ __launch_bounds__(256)
void head2_kernel(const float* __restrict__ sums, const int* __restrict__ batch,
                  const int* __restrict__ flags,
                  const float* __restrict__ doc, const float* __restrict__ doc_w, const float* __restrict__ doc_b,
                  const float* __restrict__ ln_g, const float* __restrict__ ln_b,
                  const float* __restrict__ fus_w, const float* __restrict__ fus_b,
                  const float* __restrict__ task_w, const float* __restrict__ task_b,
                  const float* __restrict__ time_w, const float* __restrict__ time_b,
                  float* __restrict__ out_task, float* __restrict__ out_time)
{
  const int g = blockIdx.x;
  const int t = threadIdx.x;
  __shared__ float fusion[256];
  __shared__ float fh[128];
  __shared__ float dpart[256];
  __shared__ int seg[2];

  if (t < 2) {
    int f = flags[1];
    int target = g + t, lo = 0, hi = N_NODES;
    while (lo < hi) { int mid = (lo + hi) >> 1; if (geti(batch, mid, f) < target) lo = mid + 1; else hi = mid; }
    seg[t] = lo;
  }
  {
    int c = t & 127, kh = t >> 7;
    float s = 0.f;
    for (int k = kh * 384; k < kh * 384 + 384; ++k) s += doc[g * 768 + k] * doc_w[k * 128 + c];
    dpart[t] = s;
  }
  __syncthreads();

  if (t < 128) {
    float cnt = (float)(seg[1] - seg[0]);
    fusion[t] = sums[g * 128 + t] / fmaxf(cnt, 1.f);
  } else {
    int c = t - 128;
    fusion[t] = fmaxf(dpart[c] + dpart[c + 128] + doc_b[c], 0.f);
  }
  __syncthreads();

  float mu = 0.f;
  for (int i = 0; i < 256; ++i) mu += fusion[i];
  mu *= (1.f / 256.f);
  float var = 0.f;
  for (int i = 0; i < 256; ++i) { float d = fusion[i] - mu; var += d * d; }
  var *= (1.f / 256.f);
  float inv = rsqrtf(var + 1e-5f);
  float norm = (fusion[t] - mu) * inv * ln_g[t] + ln_b[t];
  __syncthreads();
  fusion[t] = norm;
  __syncthreads();

  if (t < 128) {
    float s = 0.f;
    for (int k = 0; k < 256; ++k) s += fusion[k] * fus_w[k * 128 + t];
    s += fus_b[t];
    fh[t] = fmaxf(s, 0.f);
  }
  __syncthreads();

  if (t < 32) {
    float s = 0.f;
    for (int k = 0; k < 128; ++k) s += fh[k] * task_w[k * 32 + t];
    s += task_b[t];
    out_task[g * 32 + t] = s;
  }
  if (t == 32) {
    float s = 0.f;
    for (int k = 0; k < 128; ++k) s += fh[k] * time_w[k];
    s += time_b[0];
    out_time[g] = s;
  }
}

// ---------------- launch ----------------
extern "C" void kernel_launch(void* const* d_in, const int* in_sizes, int n_in,
                              void* d_out, int out_size, void* d_ws, size_t ws_size,
                              hipStream_t stream)
{
  const float* x        = (const float*)d_in[0];
  const float* doc      = (const float*)d_in[1];
  const int*   ei       = (const int*)d_in[2];
  const int*   batch    = (const int*)d_in[3];
  const float* node_w   = (const float*)d_in[4];
  const float* node_b   = (const float*)d_in[5];
  const float* ggnn_w   = (const float*)d_in[6];
  const float* gru_w_ih = (const float*)d_in[7];
  const float* gru_b_ih = (const float*)d_in[8];
  const float* gru_w_hh = (const float*)d_in[9];
  const float* gru_b_hh = (const float*)d_in[10];
  const float* doc_w    = (const float*)d_in[11];
  const float* doc_b    = (const float*)d_in[12];
  const float* ln_g     = (const float*)d_in[13];
  const float* ln_b     = (const float*)d_in[14];
  const float* fus_w    = (const float*)d_in[15];
  const float* fus_b    = (const float*)d_in[16];
  const float* task_w   = (const float*)d_in[17];
  const float* task_b   = (const float*)d_in[18];
  const float* time_w   = (const float*)d_in[19];
  const float* time_b   = (const float*)d_in[20];

  char* ws = (char*)d_ws;
  size_t off = 0;
  auto alloc = [&](size_t bytes) -> void* {
    void* p = ws + off;
    off = (off + bytes + 255) & ~(size_t)255;
    return p;
  };
  u16* aggb   = (u16*)alloc((size_t)N_NODES * 128 * 2);
  u16* hA     = (u16*)alloc((size_t)N_NODES * 128 * 2);
  u16* hB     = (u16*)alloc((size_t)N_NODES * 128 * 2);
  u16* nwT    = (u16*)alloc(64 * 128 * 2);
  u16* b2p    = (u16*)alloc(3 * 8 * 1536 * 8 * 2);
  float* wp   = (float*)alloc(3 * 128 * 384 * 4);
  float* sums = (float*)alloc(N_GRAPHS * 128 * 4);
  int* counts = (int*)alloc((size_t)N_NODES * 4);
  int* offs   = (int*)alloc((size_t)(N_NODES + 1) * 4);
  int* ssrc   = (int*)alloc((size_t)N_EDGES * 4);
  u16* rankb  = (u16*)alloc((size_t)N_EDGES * 2);
  int* bsum   = (int*)alloc(SCAN_BLOCKS * 4);
  int* bbase  = (int*)alloc(SCAN_BLOCKS * 4);
  int* flags  = (int*)alloc(2 * 4);

  hipMemsetAsync(counts, 0, (size_t)N_NODES * 4, stream);
  hipMemsetAsync(sums, 0, (size_t)N_GRAPHS * 128 * 4, stream);

  detect_i64_kernel<<<1, 64, 0, stream>>>(ei, batch, flags);
  hist_kernel<<<(N_EDGES + 255) / 256, 256, 0, stream>>>(ei, flags, counts, rankb);
  scanA_kernel<<<SCAN_BLOCKS, 1024, 0, stream>>>(counts, bsum);
  scanB_kernel<<<1, 64, 0, stream>>>(bsum, bbase, offs);
  scanC_kernel<<<SCAN_BLOCKS, 1024, 0, stream>>>(counts, bbase, offs);
  scatter_kernel<<<(N_EDGES + 255) / 256, 256, 0, stream>>>(ei, flags, offs, rankb, ssrc);

  transpose_kernel<<<(64 * 128 + 255) / 256, 256, 0, stream>>>(node_w, nwT, 64, 128);
  wprime_kernel<<<(3 * 128 * 384 + 255) / 256, 256, 0, stream>>>(ggnn_w, gru_w_ih, wp);
  for (int l = 0; l < 3; ++l)
    build_b2p_kernel<<<(8 * 1536 * 8 + 255) / 256, 256, 0, stream>>>(
        wp + l * 128 * 384, gru_w_hh, b2p + (size_t)l * 8 * 1536 * 8);

  const int GB = (N_NODES + 63) / 64;    // 1563
  const int GB2 = (N_NODES + 127) / 128; // 782
  nodeproj_gemm<<<GB, 256, 0, stream>>>(x, nwT, node_b, hA, N_NODES);

  u16* hcur = hA;
  u16* hnext = hB;
  for (int l = 0; l < 3; ++l) {
    agg_kernel<<<(N_NODES + 3) / 4, 256, 0, stream>>>(hcur, ssrc, offs, aggb);
    gru_gemm<<<GB2, 512, 0, stream>>>(aggb, hcur, b2p + (size_t)l * 8 * 1536 * 8,
                                      gru_b_ih, gru_b_hh, hnext, N_NODES);
    u16* tmp = hcur; hcur = hnext; hnext = tmp;
  }

  pool_kernel<<<(N_NODES + 127) / 128, 256, 0, stream>>>(hcur, batch, flags, sums);

  float* out_task = (float*)d_out;
  float* out_time = out_task + N_GRAPHS * 32;
  head2_kernel<<<N_GRAPHS, 256, 0, stream>>>(sums, batch, flags, doc, doc_w, doc_b, ln_g, ln_b,
                                             fus_w, fus_b, task_w, task_b, time_w, time_b,
                                             out_task, out_time);
}

// Round 8
// 740.386 us; speedup vs baseline: 2.2155x; 1.1191x over previous
//
#include <hip/hip_runtime.h>

#define N_NODES  100000
#define N_EDGES  1600000
#define N_GRAPHS 128
#define SCAN_BLOCKS 98   // ceil(100000/1024)

typedef unsigned short u16;
typedef unsigned int   u32;
typedef __attribute__((ext_vector_type(8))) short short8;
typedef __attribute__((ext_vector_type(4))) float f32x4;

__device__ __forceinline__ float bf2f(u16 v) {
  union { u32 i; float f; } u; u.i = ((u32)v) << 16; return u.f;
}
__device__ __forceinline__ u16 f2bf(float f) {
  union { float f; u32 i; } u; u.f = f;
  u32 r = (u.i + 0x7fffu + ((u.i >> 16) & 1u)) >> 16;
  return (u16)r;
}
__device__ __forceinline__ float sigmoid_f(float x) { return 1.f / (1.f + __expf(-x)); }
__device__ __forceinline__ float tanh_f(float x) {
  x = fminf(15.f, fmaxf(-15.f, x));
  float e = __expf(2.f * x);
  return (e - 1.f) / (e + 1.f);
}
__device__ __forceinline__ int geti(const int* __restrict__ p, int i, int is64) {
  return p[is64 ? (2 * i) : i];
}

// Detect whether edge_index / batch are int64 (all sampled odd words == 0) or int32.
__global__ void detect_i64_kernel(const int* __restrict__ ei, const int* __restrict__ batch,
                                  int* __restrict__ flags) {
  int lane = threadIdx.x;  // 64
  {
    long long q = (long long)lane * (3200000 / 2 - 1) / 63;
    int pos = (int)(2 * q + 1);
    unsigned long long m = __ballot(ei[pos] != 0);
    if (lane == 0) flags[0] = (m == 0ull) ? 1 : 0;
  }
  {
    long long q = (long long)lane * (100000 / 2 - 1) / 63;
    int pos = (int)(2 * q + 1);
    unsigned long long m = __ballot(batch[pos] != 0);
    if (lane == 0) flags[1] = (m == 0ull) ? 1 : 0;
  }
}

// ---------------- CSR build ----------------
// hist also records each edge's rank among its dst's edges -> scatter needs no atomics.
__global__ void hist_kernel(const int* __restrict__ ei, const int* __restrict__ flags,
                            int* __restrict__ counts, u16* __restrict__ rankb) {
  int e = blockIdx.x * 256 + threadIdx.x;
  if (e < N_EDGES) {
    int f = flags[0];
    int d = geti(ei, N_EDGES + e, f);
    int r = atomicAdd(&counts[d], 1);
    rankb[e] = (u16)r;
  }
}

__global__ __launch_bounds__(1024)
void scanA_kernel(const int* __restrict__ counts, int* __restrict__ blocksums) {
  __shared__ int red[16];
  int i = blockIdx.x * 1024 + threadIdx.x;
  int v = (i < N_NODES) ? counts[i] : 0;
  for (int o = 32; o > 0; o >>= 1) v += __shfl_down(v, o, 64);
  int wv = threadIdx.x >> 6, lane = threadIdx.x & 63;
  if (lane == 0) red[wv] = v;
  __syncthreads();
  if (threadIdx.x < 16) {
    int s = red[threadIdx.x];
    for (int o = 8; o > 0; o >>= 1) s += __shfl_down(s, o, 64);
    if (threadIdx.x == 0) blocksums[blockIdx.x] = s;
  }
}

__global__ void scanB_kernel(const int* __restrict__ blocksums, int* __restrict__ blockbase,
                             int* __restrict__ offsets) {
  if (threadIdx.x == 0) {
    int run = 0;
    for (int b = 0; b < SCAN_BLOCKS; ++b) { blockbase[b] = run; run += blocksums[b]; }
    offsets[N_NODES] = run;
  }
}

__global__ __launch_bounds__(1024)
void scanC_kernel(const int* __restrict__ counts, const int* __restrict__ blockbase,
                  int* __restrict__ offsets) {
  __shared__ int buf[1024];
  int t = threadIdx.x;
  int i = blockIdx.x * 1024 + t;
  int v = (i < N_NODES) ? counts[i] : 0;
  buf[t] = v;
  __syncthreads();
  for (int o = 1; o < 1024; o <<= 1) {
    int add = (t >= o) ? buf[t - o] : 0;
    __syncthreads();
    buf[t] += add;
    __syncthreads();
  }
  if (i < N_NODES) offsets[i] = buf[t] - v + blockbase[blockIdx.x];
}

// atomic-free scatter using precomputed ranks
__global__ void scatter_kernel(const int* __restrict__ ei, const int* __restrict__ flags,
                               const int* __restrict__ offsets, const u16* __restrict__ rankb,
                               int* __restrict__ ssrc) {
  int e = blockIdx.x * 256 + threadIdx.x;
  if (e < N_EDGES) {
    int f = flags[0];
    int d = geti(ei, N_EDGES + e, f);
    ssrc[offsets[d] + (int)rankb[e]] = geti(ei, e, f);
  }
}

// ---------------- weight prep ----------------
// f32 [K][N] row-major -> bf16 [N][K]
__global__ void transpose_kernel(const float* __restrict__ in, u16* __restrict__ out, int K, int N) {
  int i = blockIdx.x * 256 + threadIdx.x;
  if (i < K * N) {
    int k = i / N, n = i % N;
    out[n * K + k] = f2bf(in[i]);
  }
}

// W'_l[k][c] = sum_j ggnn_w[l][k][j] * w_ih[j][c]   (f32, [3][128][384])
__global__ void wprime_kernel(const float* __restrict__ ggnn_w, const float* __restrict__ w_ih,
                              float* __restrict__ wp) {
  int i = blockIdx.x * 256 + threadIdx.x;
  if (i >= 3 * 128 * 384) return;
  int l = i / (128 * 384), r = i % (128 * 384), k = r / 384, c = r % 384;
  const float* W = ggnn_w + l * 128 * 128;
  float s = 0.f;
  for (int j = 0; j < 128; ++j) s += W[k * 128 + j] * w_ih[j * 384 + c];
  wp[i] = s;
}

// Packed GRU weight: b2p[ci][idx][e] u16, ci=0..7 (k-chunk), idx = ko*384 + n_lin,
// e=0..7. Zero quadrants excluded (ci<4: W' cols r|z|in; ci>=4: w_hh cols r|z|hn).
__global__ void build_b2p_kernel(const float* __restrict__ wp, const float* __restrict__ w_hh,
                                 u16* __restrict__ b2p) {
  int g = blockIdx.x * 256 + threadIdx.x;
  if (g >= 8 * 1536 * 8) return;
  int e = g & 7;
  int grp = g >> 3;
  int ci = grp / 1536;
  int idx = grp % 1536;
  int n_lin = idx % 384;
  int ko = idx / 384;
  int k = ci * 32 + ko * 8 + e;
  float v = (k < 128) ? wp[k * 384 + n_lin] : w_hh[(k - 128) * 384 + n_lin];
  b2p[g] = f2bf(v);
}

// ---------------- node projection GEMM (f32 A -> bf16 frags) ----------------
__global__ __launch_bounds__(256)
void nodeproj_gemm(const float* __restrict__ A, const u16* __restrict__ BT,
                   const float* __restrict__ bias, u16* __restrict__ out, int M)
{
  constexpr int K_DIM = 64, N_DIM = 128, NT = 8, NCHUNK = 2;
  __shared__ u16 B_lds[N_DIM * 40];
  const int tid = threadIdx.x, lane = tid & 63, w = tid >> 6;
  const int strip = blockIdx.x * 64;
  const int ksub = (lane >> 4) * 8;
  union Frag { uint4 u; short8 s; };
  Frag af[NCHUNK];
  const int m_node = strip + w * 16 + (lane & 15);
  const bool avalid = (m_node < M);
#pragma unroll
  for (int ci = 0; ci < NCHUNK; ++ci) {
    int k0 = ci * 32 + ksub;
    short8 sv = {0,0,0,0,0,0,0,0};
    if (avalid) {
      const float* p = A + (size_t)m_node * K_DIM + k0;
      float4 f0 = *(const float4*)p;
      float4 f1 = *(const float4*)(p + 4);
      sv[0]=(short)f2bf(f0.x); sv[1]=(short)f2bf(f0.y); sv[2]=(short)f2bf(f0.z); sv[3]=(short)f2bf(f0.w);
      sv[4]=(short)f2bf(f1.x); sv[5]=(short)f2bf(f1.y); sv[6]=(short)f2bf(f1.z); sv[7]=(short)f2bf(f1.w);
    }
    af[ci].s = sv;
  }
  f32x4 acc[NT];
#pragma unroll
  for (int t = 0; t < NT; ++t) acc[t] = {0.f, 0.f, 0.f, 0.f};
  const int boff = (lane & 15) * 40 + ksub;
#pragma unroll
  for (int ci = 0; ci < NCHUNK; ++ci) {
    if (ci) __syncthreads();
    for (int g = tid; g < N_DIM * 4; g += 256) {
      int n = g >> 2, ko = g & 3;
      uint4 bv = *(const uint4*)(BT + (size_t)n * K_DIM + ci * 32 + ko * 8);
      *(uint4*)(&B_lds[n * 40 + ko * 8]) = bv;
    }
    __syncthreads();
    short8 a = af[ci].s;
#pragma unroll
    for (int t = 0; t < NT; ++t) {
      const short8 b = *(const short8*)(&B_lds[t * 16 * 40 + boff]);
      acc[t] = __builtin_amdgcn_mfma_f32_16x16x32_bf16(a, b, acc[t], 0, 0, 0);
    }
  }
  const int mrow = (lane >> 4) * 4;
#pragma unroll
  for (int t = 0; t < NT; ++t) {
    int col = t * 16 + (lane & 15);
    float bv = bias[col];
#pragma unroll
    for (int r = 0; r < 4; ++r) {
      int node = strip + w * 16 + mrow + r;
      if (node < M) out[(size_t)node * N_DIM + col] = f2bf(fmaxf(acc[t][r] + bv, 0.f));
    }
  }
}

// ---------------- GRU GEMM: barrier-free, LDS-free ----------------
// Each wave is fully independent: 16 rows x 64 cols. acc = 16 tiles (r/z/in/hn x 4).
// B fragments load directly from the packed b2p (192 KB/layer, L2/L1-hot; every wave
// reads the same lines). 12 B-loads + 1 A-load per 12 MFMA, no __syncthreads at all —
// latency hidden by ILP (independent loads) + ~3 waves/SIMD.
__global__ __launch_bounds__(256)
void gru_gemm(const u16* __restrict__ agg, const u16* __restrict__ h,
              const u16* __restrict__ b2p, const float* __restrict__ b_ih,
              const float* __restrict__ b_hh, u16* __restrict__ hout, int M)
{
  const int tid  = threadIdx.x;
  const int lane = tid & 63;
  const int gw   = blockIdx.x * 4 + (tid >> 6);   // global wave id
  const int strip = (gw >> 1) * 16;               // 16-row strip
  const int hc    = gw & 1;                       // column half (64 cols)
  const int lrow  = lane & 15;
  const int quad  = lane >> 4;
  const int ksub  = quad * 8;
  if (strip >= M) return;

  f32x4 ar[4], az[4], ain[4], ahn[4];
#pragma unroll
  for (int t = 0; t < 4; ++t) {
    ar[t] = {0.f,0.f,0.f,0.f}; az[t] = {0.f,0.f,0.f,0.f};
    ain[t] = {0.f,0.f,0.f,0.f}; ahn[t] = {0.f,0.f,0.f,0.f};
  }

  union Frag { uint4 u; short8 s8; };
  const int node = strip + lrow;                  // A row for this lane
  // b2p base (u16 units): [ci]*12288 + (quad*384 + n_lin)*8, n_lin = gate*128 + hc*64 + t*16 + lrow
  const u16* bb = b2p + ((size_t)quad * 384 + hc * 64 + lrow) * 8;

#pragma unroll
  for (int ci = 0; ci < 8; ++ci) {
    Frag a;
    {
      const u16* ap = (ci < 4) ? (agg + ci * 32 + ksub) : (h + (ci - 4) * 32 + ksub);
      a.u = *(const uint4*)(ap + (size_t)node * 128);
    }
    const u16* cb = bb + ci * 12288;
    Frag br[4], bz[4], bg[4];
#pragma unroll
    for (int t = 0; t < 4; ++t) {
      br[t].u = *(const uint4*)(cb + t * 128);           // r: n_lin 0..127
      bz[t].u = *(const uint4*)(cb + 1024 + t * 128);    // z: n_lin 128..255
      bg[t].u = *(const uint4*)(cb + 2048 + t * 128);    // in (ci<4) / hn (ci>=4)
    }
#pragma unroll
    for (int t = 0; t < 4; ++t) {
      ar[t] = __builtin_amdgcn_mfma_f32_16x16x32_bf16(a.s8, br[t].s8, ar[t], 0, 0, 0);
      az[t] = __builtin_amdgcn_mfma_f32_16x16x32_bf16(a.s8, bz[t].s8, az[t], 0, 0, 0);
      if (ci < 4) ain[t] = __builtin_amdgcn_mfma_f32_16x16x32_bf16(a.s8, bg[t].s8, ain[t], 0, 0, 0);
      else        ahn[t] = __builtin_amdgcn_mfma_f32_16x16x32_bf16(a.s8, bg[t].s8, ahn[t], 0, 0, 0);
    }
  }

  // GRU epilogue. D layout: row = quad*4 + r, col = lrow (within each 16-col tile).
#pragma unroll
  for (int t = 0; t < 4; ++t) {
    const int c = hc * 64 + t * 16 + lrow;
    const float brr = b_ih[c] + b_hh[c];
    const float bzz = b_ih[128 + c] + b_hh[128 + c];
    const float bin = b_ih[256 + c];
    const float bhn = b_hh[256 + c];
#pragma unroll
    for (int r = 0; r < 4; ++r) {
      const int nrow = strip + quad * 4 + r;
      if (nrow < M) {
        float rg = sigmoid_f(ar[t][r] + brr);
        float zg = sigmoid_f(az[t][r] + bzz);
        float hv = ahn[t][r] + bhn;
        float ng = tanh_f(ain[t][r] + bin + rg * hv);
        float hp = bf2f(h[(size_t)nrow * 128 + c]);
        hout[(size_t)nrow * 128 + c] = f2bf((1.f - zg) * ng + zg * hp);
      }
    }
  }
}

// ---------------- CSR aggregation: agg[n] = sum over in-edges of h[src], 8x MLP ----------------
__global__ __launch_bounds__(256)
void agg_kernel(const u16* __restrict__ m, const int* __restrict__ ssrc,
                const int* __restrict__ offsets, u16* __restrict__ agg)
{
  int node = blockIdx.x * 4 + (threadIdx.x >> 6);
  int lane = threadIdx.x & 63;
  if (node >= N_NODES) return;
  int beg = offsets[node], end = offsets[node + 1];
  float s0 = 0.f, s1 = 0.f;
  int e = beg;
  for (; e + 8 <= end; e += 8) {
    u32 v[8];
#pragma unroll
    for (int q = 0; q < 8; ++q) {
      int src = ssrc[e + q];
      v[q] = *(const u32*)(m + (size_t)src * 128 + lane * 2);
    }
#pragma unroll
    for (int q = 0; q < 8; ++q) {
      s0 += bf2f((u16)(v[q] & 0xffffu));
      s1 += bf2f((u16)(v[q] >> 16));
    }
  }
  for (; e < end; ++e) {
    int src = ssrc[e];
    u32 v = *(const u32*)(m + (size_t)src * 128 + lane * 2);
    s0 += bf2f((u16)(v & 0xffffu));
    s1 += bf2f((u16)(v >> 16));
  }
  u32 packed = (u32)f2bf(s0) | ((u32)f2bf(s1) << 16);
  *(u32*)(agg + (size_t)node * 128 + lane * 2) = packed;
}

// ---------------- parallel segmented mean-pool (batch is sorted) ----------------
__global__ __launch_bounds__(256)
void pool_kernel(const u16* __restrict__ h, const int* __restrict__ batch,
                 const int* __restrict__ flags, float* __restrict__ sums)
{
  const int c = threadIdx.x & 127;
  const int half = threadIdx.x >> 7;
  const int base = blockIdx.x * 128;
  const int f = flags[1];
  int gcur = -1; float s = 0.f;
  for (int i = half; i < 128; i += 2) {
    int n = base + i;
    if (n >= N_NODES) break;
    int g = geti(batch, n, f);
    if (g != gcur) {
      if (gcur >= 0) atomicAdd(&sums[gcur * 128 + c], s);
      s = 0.f; gcur = g;
    }
    s += bf2f(h[(size_t)n * 128 + c]);
  }
  if (gcur >= 0) atomicAdd(&sums[gcur * 128 + c], s);
}

// ---------------- doc proj + LN + fusion + heads, f32 (one block per graph) ----------------
__global__ __launch_bounds__(256)
void head2_kernel(const float* __restrict__ sums, const int* __restrict__ batch,
                  const int* __restrict__ flags,
                  const float* __restrict__ doc, const float* __restrict__ doc_w, const float* __restrict__ doc_b,
                  const float* __restrict__ ln_g, const float* __restrict__ ln_b,
                  const float* __restrict__ fus_w, const float* __restrict__ fus_b,
                  const float* __restrict__ task_w, const float* __restrict__ task_b,
                  const float* __restrict__ time_w, const float* __restrict__ time_b,
                  float* __restrict__ out_task, float* __restrict__ out_time)
{
  const int g = blockIdx.x;
  const int t = threadIdx.x;
  __shared__ float fusion[256];
  __shared__ float fh[128];
  __shared__ float dpart[256];
  __shared__ int seg[2];

  if (t < 2) {
    int f = flags[1];
    int target = g + t, lo = 0, hi = N_NODES;
    while (lo < hi) { int mid = (lo + hi) >> 1; if (geti(batch, mid, f) < target) lo = mid + 1; else hi = mid; }
    seg[t] = lo;
  }
  {
    int c = t & 127, kh = t >> 7;
    float s = 0.f;
    for (int k = kh * 384; k < kh * 384 + 384; ++k) s += doc[g * 768 + k] * doc_w[k * 128 + c];
    dpart[t] = s;
  }
  __syncthreads();

  if (t < 128) {
    float cnt = (float)(seg[1] - seg[0]);
    fusion[t] = sums[g * 128 + t] / fmaxf(cnt, 1.f);
  } else {
    int c = t - 128;
    fusion[t] = fmaxf(dpart[c] + dpart[c + 128] + doc_b[c], 0.f);
  }
  __syncthreads();

  float mu = 0.f;
  for (int i = 0; i < 256; ++i) mu += fusion[i];
  mu *= (1.f / 256.f);
  float var = 0.f;
  for (int i = 0; i < 256; ++i) { float d = fusion[i] - mu; var += d * d; }
  var *= (1.f / 256.f);
  float inv = rsqrtf(var + 1e-5f);
  float norm = (fusion[t] - mu) * inv * ln_g[t] + ln_b[t];
  __syncthreads();
  fusion[t] = norm;
  __syncthreads();

  if (t < 128) {
    float s = 0.f;
    for (int k = 0; k < 256; ++k) s += fusion[k] * fus_w[k * 128 + t];
    s += fus_b[t];
    fh[t] = fmaxf(s, 0.f);
  }
  __syncthreads();

  if (t < 32) {
    float s = 0.f;
    for (int k = 0; k < 128; ++k) s += fh[k] * task_w[k * 32 + t];
    s += task_b[t];
    out_task[g * 32 + t] = s;
  }
  if (t == 32) {
    float s = 0.f;
    for (int k = 0; k < 128; ++k) s += fh[k] * time_w[k];
    s += time_b[0];
    out_time[g] = s;
  }
}

// ---------------- launch ----------------
extern "C" void kernel_launch(void* const* d_in, const int* in_sizes, int n_in,
                              void* d_out, int out_size, void* d_ws, size_t ws_size,
                              hipStream_t stream)
{
  const float* x        = (const float*)d_in[0];
  const float* doc      = (const float*)d_in[1];
  const int*   ei       = (const int*)d_in[2];
  const int*   batch    = (const int*)d_in[3];
  const float* node_w   = (const float*)d_in[4];
  const float* node_b   = (const float*)d_in[5];
  const float* ggnn_w   = (const float*)d_in[6];
  const float* gru_w_ih = (const float*)d_in[7];
  const float* gru_b_ih = (const float*)d_in[8];
  const float* gru_w_hh = (const float*)d_in[9];
  const float* gru_b_hh = (const float*)d_in[10];
  const float* doc_w    = (const float*)d_in[11];
  const float* doc_b    = (const float*)d_in[12];
  const float* ln_g     = (const float*)d_in[13];
  const float* ln_b     = (const float*)d_in[14];
  const float* fus_w    = (const float*)d_in[15];
  const float* fus_b    = (const float*)d_in[16];
  const float* task_w   = (const float*)d_in[17];
  const float* task_b   = (const float*)d_in[18];
  const float* time_w   = (const float*)d_in[19];
  const float* time_b   = (const float*)d_in[20];

  char* ws = (char*)d_ws;
  size_t off = 0;
  auto alloc = [&](size_t bytes) -> void* {
    void* p = ws + off;
    off = (off + bytes + 255) & ~(size_t)255;
    return p;
  };
  u16* aggb   = (u16*)alloc((size_t)N_NODES * 128 * 2);
  u16* hA     = (u16*)alloc((size_t)N_NODES * 128 * 2);
  u16* hB     = (u16*)alloc((size_t)N_NODES * 128 * 2);
  u16* nwT    = (u16*)alloc(64 * 128 * 2);
  u16* b2p    = (u16*)alloc(3 * 8 * 1536 * 8 * 2);
  float* wp   = (float*)alloc(3 * 128 * 384 * 4);
  float* sums = (float*)alloc(N_GRAPHS * 128 * 4);
  int* counts = (int*)alloc((size_t)N_NODES * 4);
  int* offs   = (int*)alloc((size_t)(N_NODES + 1) * 4);
  int* ssrc   = (int*)alloc((size_t)N_EDGES * 4);
  u16* rankb  = (u16*)alloc((size_t)N_EDGES * 2);
  int* bsum   = (int*)alloc(SCAN_BLOCKS * 4);
  int* bbase  = (int*)alloc(SCAN_BLOCKS * 4);
  int* flags  = (int*)alloc(2 * 4);

  hipMemsetAsync(counts, 0, (size_t)N_NODES * 4, stream);
  hipMemsetAsync(sums, 0, (size_t)N_GRAPHS * 128 * 4, stream);

  detect_i64_kernel<<<1, 64, 0, stream>>>(ei, batch, flags);
  hist_kernel<<<(N_EDGES + 255) / 256, 256, 0, stream>>>(ei, flags, counts, rankb);
  scanA_kernel<<<SCAN_BLOCKS, 1024, 0, stream>>>(counts, bsum);
  scanB_kernel<<<1, 64, 0, stream>>>(bsum, bbase, offs);
  scanC_kernel<<<SCAN_BLOCKS, 1024, 0, stream>>>(counts, bbase, offs);
  scatter_kernel<<<(N_EDGES + 255) / 256, 256, 0, stream>>>(ei, flags, offs, rankb, ssrc);

  transpose_kernel<<<(64 * 128 + 255) / 256, 256, 0, stream>>>(node_w, nwT, 64, 128);
  wprime_kernel<<<(3 * 128 * 384 + 255) / 256, 256, 0, stream>>>(ggnn_w, gru_w_ih, wp);
  for (int l = 0; l < 3; ++l)
    build_b2p_kernel<<<(8 * 1536 * 8 + 255) / 256, 256, 0, stream>>>(
        wp + l * 128 * 384, gru_w_hh, b2p + (size_t)l * 8 * 1536 * 8);

  const int GB = (N_NODES + 63) / 64;        // 1563
  const int GW = (N_NODES + 15) / 16 * 2;    // 12500 waves
  const int GB4 = (GW + 3) / 4;              // 3125 blocks of 4 waves
  nodeproj_gemm<<<GB, 256, 0, stream>>>(x, nwT, node_b, hA, N_NODES);

  u16* hcur = hA;
  u16* hnext = hB;
  for (int l = 0; l < 3; ++l) {
    agg_kernel<<<(N_NODES + 3) / 4, 256, 0, stream>>>(hcur, ssrc, offs, aggb);
    gru_gemm<<<GB4, 256, 0, stream>>>(aggb, hcur, b2p + (size_t)l * 8 * 1536 * 8,
                                      gru_b_ih, gru_b_hh, hnext, N_NODES);
    u16* tmp = hcur; hcur = hnext; hnext = tmp;
  }

  pool_kernel<<<(N_NODES + 127) / 128, 256, 0, stream>>>(hcur, batch, flags, sums);

  float* out_task = (float*)d_out;
  float* out_time = out_task + N_GRAPHS * 32;
  head2_kernel<<<N_GRAPHS, 256, 0, stream>>>(sums, batch, flags, doc, doc_w, doc_b, ln_g, ln_b,
                                             fus_w, fus_b, task_w, task_b, time_w, time_b,
                                             out_task, out_time);
}

// Round 9
// 728.506 us; speedup vs baseline: 2.2516x; 1.0163x over previous
//
#include <hip/hip_runtime.h>

#define N_NODES  100000
#define N_EDGES  1600000
#define N_GRAPHS 128
#define SCAN_BLOCKS 98   // ceil(100000/1024)

typedef unsigned short u16;
typedef unsigned int   u32;
typedef __attribute__((ext_vector_type(8))) short short8;
typedef __attribute__((ext_vector_type(4))) float f32x4;

__device__ __forceinline__ float bf2f(u16 v) {
  union { u32 i; float f; } u; u.i = ((u32)v) << 16; return u.f;
}
__device__ __forceinline__ u16 f2bf(float f) {
  union { float f; u32 i; } u; u.f = f;
  u32 r = (u.i + 0x7fffu + ((u.i >> 16) & 1u)) >> 16;
  return (u16)r;
}
__device__ __forceinline__ float sigmoid_f(float x) { return 1.f / (1.f + __expf(-x)); }
__device__ __forceinline__ float tanh_f(float x) {
  x = fminf(15.f, fmaxf(-15.f, x));
  float e = __expf(2.f * x);
  return (e - 1.f) / (e + 1.f);
}
__device__ __forceinline__ int geti(const int* __restrict__ p, int i, int is64) {
  return p[is64 ? (2 * i) : i];
}

// Detect whether edge_index / batch are int64 (all sampled odd words == 0) or int32.
__global__ void detect_i64_kernel(const int* __restrict__ ei, const int* __restrict__ batch,
                                  int* __restrict__ flags) {
  int lane = threadIdx.x;  // 64
  {
    long long q = (long long)lane * (3200000 / 2 - 1) / 63;
    int pos = (int)(2 * q + 1);
    unsigned long long m = __ballot(ei[pos] != 0);
    if (lane == 0) flags[0] = (m == 0ull) ? 1 : 0;
  }
  {
    long long q = (long long)lane * (100000 / 2 - 1) / 63;
    int pos = (int)(2 * q + 1);
    unsigned long long m = __ballot(batch[pos] != 0);
    if (lane == 0) flags[1] = (m == 0ull) ? 1 : 0;
  }
}

// ---------------- CSR build ----------------
// hist also records each edge's rank among its dst's edges -> scatter needs no atomics.
__global__ void hist_kernel(const int* __restrict__ ei, const int* __restrict__ flags,
                            int* __restrict__ counts, u16* __restrict__ rankb) {
  int e = blockIdx.x * 256 + threadIdx.x;
  if (e < N_EDGES) {
    int f = flags[0];
    int d = geti(ei, N_EDGES + e, f);
    int r = atomicAdd(&counts[d], 1);
    rankb[e] = (u16)r;
  }
}

__global__ __launch_bounds__(1024)
void scanA_kernel(const int* __restrict__ counts, int* __restrict__ blocksums) {
  __shared__ int red[16];
  int i = blockIdx.x * 1024 + threadIdx.x;
  int v = (i < N_NODES) ? counts[i] : 0;
  for (int o = 32; o > 0; o >>= 1) v += __shfl_down(v, o, 64);
  int wv = threadIdx.x >> 6, lane = threadIdx.x & 63;
  if (lane == 0) red[wv] = v;
  __syncthreads();
  if (threadIdx.x < 16) {
    int s = red[threadIdx.x];
    for (int o = 8; o > 0; o >>= 1) s += __shfl_down(s, o, 64);
    if (threadIdx.x == 0) blocksums[blockIdx.x] = s;
  }
}

__global__ void scanB_kernel(const int* __restrict__ blocksums, int* __restrict__ blockbase,
                             int* __restrict__ offsets) {
  if (threadIdx.x == 0) {
    int run = 0;
    for (int b = 0; b < SCAN_BLOCKS; ++b) { blockbase[b] = run; run += blocksums[b]; }
    offsets[N_NODES] = run;
  }
}

__global__ __launch_bounds__(1024)
void scanC_kernel(const int* __restrict__ counts, const int* __restrict__ blockbase,
                  int* __restrict__ offsets) {
  __shared__ int buf[1024];
  int t = threadIdx.x;
  int i = blockIdx.x * 1024 + t;
  int v = (i < N_NODES) ? counts[i] : 0;
  buf[t] = v;
  __syncthreads();
  for (int o = 1; o < 1024; o <<= 1) {
    int add = (t >= o) ? buf[t - o] : 0;
    __syncthreads();
    buf[t] += add;
    __syncthreads();
  }
  if (i < N_NODES) offsets[i] = buf[t] - v + blockbase[blockIdx.x];
}

// atomic-free scatter using precomputed ranks
__global__ void scatter_kernel(const int* __restrict__ ei, const int* __restrict__ flags,
                               const int* __restrict__ offsets, const u16* __restrict__ rankb,
                               int* __restrict__ ssrc) {
  int e = blockIdx.x * 256 + threadIdx.x;
  if (e < N_EDGES) {
    int f = flags[0];
    int d = geti(ei, N_EDGES + e, f);
    ssrc[offsets[d] + (int)rankb[e]] = geti(ei, e, f);
  }
}

// ---------------- weight prep ----------------
// f32 [K][N] row-major -> bf16 [N][K]
__global__ void transpose_kernel(const float* __restrict__ in, u16* __restrict__ out, int K, int N) {
  int i = blockIdx.x * 256 + threadIdx.x;
  if (i < K * N) {
    int k = i / N, n = i % N;
    out[n * K + k] = f2bf(in[i]);
  }
}

// W'_l[k][c] = sum_j ggnn_w[l][k][j] * w_ih[j][c]   (f32, [3][128][384])
__global__ void wprime_kernel(const float* __restrict__ ggnn_w, const float* __restrict__ w_ih,
                              float* __restrict__ wp) {
  int i = blockIdx.x * 256 + threadIdx.x;
  if (i >= 3 * 128 * 384) return;
  int l = i / (128 * 384), r = i % (128 * 384), k = r / 384, c = r % 384;
  const float* W = ggnn_w + l * 128 * 128;
  float s = 0.f;
  for (int j = 0; j < 128; ++j) s += W[k * 128 + j] * w_ih[j * 384 + c];
  wp[i] = s;
}

// Packed GRU weight: b2p[ci][idx][e] u16, ci=0..7 (k-chunk), idx = ko*384 + n_lin,
// e=0..7. Zero quadrants excluded (ci<4: W' cols r|z|in; ci>=4: w_hh cols r|z|hn).
__global__ void build_b2p_kernel(const float* __restrict__ wp, const float* __restrict__ w_hh,
                                 u16* __restrict__ b2p) {
  int g = blockIdx.x * 256 + threadIdx.x;
  if (g >= 8 * 1536 * 8) return;
  int e = g & 7;
  int grp = g >> 3;
  int ci = grp / 1536;
  int idx = grp % 1536;
  int n_lin = idx % 384;
  int ko = idx / 384;
  int k = ci * 32 + ko * 8 + e;
  float v = (k < 128) ? wp[k * 384 + n_lin] : w_hh[(k - 128) * 384 + n_lin];
  b2p[g] = f2bf(v);
}

// ---------------- node projection GEMM (f32 A -> bf16 frags) ----------------
__global__ __launch_bounds__(256)
void nodeproj_gemm(const float* __restrict__ A, const u16* __restrict__ BT,
                   const float* __restrict__ bias, u16* __restrict__ out, int M)
{
  constexpr int K_DIM = 64, N_DIM = 128, NT = 8, NCHUNK = 2;
  __shared__ u16 B_lds[N_DIM * 40];
  const int tid = threadIdx.x, lane = tid & 63, w = tid >> 6;
  const int strip = blockIdx.x * 64;
  const int ksub = (lane >> 4) * 8;
  union Frag { uint4 u; short8 s; };
  Frag af[NCHUNK];
  const int m_node = strip + w * 16 + (lane & 15);
  const bool avalid = (m_node < M);
#pragma unroll
  for (int ci = 0; ci < NCHUNK; ++ci) {
    int k0 = ci * 32 + ksub;
    short8 sv = {0,0,0,0,0,0,0,0};
    if (avalid) {
      const float* p = A + (size_t)m_node * K_DIM + k0;
      float4 f0 = *(const float4*)p;
      float4 f1 = *(const float4*)(p + 4);
      sv[0]=(short)f2bf(f0.x); sv[1]=(short)f2bf(f0.y); sv[2]=(short)f2bf(f0.z); sv[3]=(short)f2bf(f0.w);
      sv[4]=(short)f2bf(f1.x); sv[5]=(short)f2bf(f1.y); sv[6]=(short)f2bf(f1.z); sv[7]=(short)f2bf(f1.w);
    }
    af[ci].s = sv;
  }
  f32x4 acc[NT];
#pragma unroll
  for (int t = 0; t < NT; ++t) acc[t] = {0.f, 0.f, 0.f, 0.f};
  const int boff = (lane & 15) * 40 + ksub;
#pragma unroll
  for (int ci = 0; ci < NCHUNK; ++ci) {
    if (ci) __syncthreads();
    for (int g = tid; g < N_DIM * 4; g += 256) {
      int n = g >> 2, ko = g & 3;
      uint4 bv = *(const uint4*)(BT + (size_t)n * K_DIM + ci * 32 + ko * 8);
      *(uint4*)(&B_lds[n * 40 + ko * 8]) = bv;
    }
    __syncthreads();
    short8 a = af[ci].s;
#pragma unroll
    for (int t = 0; t < NT; ++t) {
      const short8 b = *(const short8*)(&B_lds[t * 16 * 40 + boff]);
      acc[t] = __builtin_amdgcn_mfma_f32_16x16x32_bf16(a, b, acc[t], 0, 0, 0);
    }
  }
  const int mrow = (lane >> 4) * 4;
#pragma unroll
  for (int t = 0; t < NT; ++t) {
    int col = t * 16 + (lane & 15);
    float bv = bias[col];
#pragma unroll
    for (int r = 0; r < 4; ++r) {
      int node = strip + w * 16 + mrow + r;
      if (node < M) out[(size_t)node * N_DIM + col] = f2bf(fmaxf(acc[t][r] + bv, 0.f));
    }
  }
}

// ---------------- GRU GEMM: barrier-free, LDS-free, 32 rows x 64 cols per wave ----------------
// 2x B-reuse vs round 8 (each B-frag feeds 2 row-substrips): per chunk 12 B-loads +
// 2 A-loads -> 24 MFMA. acc = 32 f32x4 tiles (128 regs, unified VGPR/AGPR file);
// per-gate load->MFMA grouping keeps <=4 B-frags live. No __syncthreads, no LDS.
// Plain __launch_bounds__ — a min-waves arg would cap regs below acc and spill (round 5).
__global__ __launch_bounds__(256)
void gru_gemm(const u16* __restrict__ agg, const u16* __restrict__ h,
              const u16* __restrict__ b2p, const float* __restrict__ b_ih,
              const float* __restrict__ b_hh, u16* __restrict__ hout, int M)
{
  const int tid  = threadIdx.x;
  const int lane = tid & 63;
  const int gw   = blockIdx.x * 4 + (tid >> 6);   // global wave id
  const int strip = (gw >> 1) * 32;               // 32-row strip (100000 % 32 == 0)
  const int hc    = gw & 1;                       // column half (64 cols)
  const int lrow  = lane & 15;
  const int quad  = lane >> 4;
  const int ksub  = quad * 8;
  if (strip >= M) return;

  f32x4 ar[2][4], az[2][4], ain[2][4], ahn[2][4];
#pragma unroll
  for (int s = 0; s < 2; ++s)
#pragma unroll
    for (int t = 0; t < 4; ++t) {
      ar[s][t] = {0.f,0.f,0.f,0.f}; az[s][t] = {0.f,0.f,0.f,0.f};
      ain[s][t] = {0.f,0.f,0.f,0.f}; ahn[s][t] = {0.f,0.f,0.f,0.f};
    }

  union Frag { uint4 u; short8 s8; };
  const int node0 = strip + lrow;
  const int node1 = strip + 16 + lrow;
  const u16* bb = b2p + ((size_t)quad * 384 + hc * 64 + lrow) * 8;

#pragma unroll
  for (int ci = 0; ci < 8; ++ci) {
    Frag a0, a1;
    {
      const u16* ap = (ci < 4) ? (agg + ci * 32 + ksub) : (h + (ci - 4) * 32 + ksub);
      a0.u = *(const uint4*)(ap + (size_t)node0 * 128);
      a1.u = *(const uint4*)(ap + (size_t)node1 * 128);
    }
    const u16* cb = bb + ci * 12288;
    {  // r gate: n_lin 0..127
      Frag b[4];
#pragma unroll
      for (int t = 0; t < 4; ++t) b[t].u = *(const uint4*)(cb + t * 128);
#pragma unroll
      for (int t = 0; t < 4; ++t) {
        ar[0][t] = __builtin_amdgcn_mfma_f32_16x16x32_bf16(a0.s8, b[t].s8, ar[0][t], 0, 0, 0);
        ar[1][t] = __builtin_amdgcn_mfma_f32_16x16x32_bf16(a1.s8, b[t].s8, ar[1][t], 0, 0, 0);
      }
    }
    {  // z gate: n_lin 128..255
      Frag b[4];
#pragma unroll
      for (int t = 0; t < 4; ++t) b[t].u = *(const uint4*)(cb + 1024 + t * 128);
#pragma unroll
      for (int t = 0; t < 4; ++t) {
        az[0][t] = __builtin_amdgcn_mfma_f32_16x16x32_bf16(a0.s8, b[t].s8, az[0][t], 0, 0, 0);
        az[1][t] = __builtin_amdgcn_mfma_f32_16x16x32_bf16(a1.s8, b[t].s8, az[1][t], 0, 0, 0);
      }
    }
    {  // in (ci<4) / hn (ci>=4): n_lin 256..383
      Frag b[4];
#pragma unroll
      for (int t = 0; t < 4; ++t) b[t].u = *(const uint4*)(cb + 2048 + t * 128);
      if (ci < 4) {
#pragma unroll
        for (int t = 0; t < 4; ++t) {
          ain[0][t] = __builtin_amdgcn_mfma_f32_16x16x32_bf16(a0.s8, b[t].s8, ain[0][t], 0, 0, 0);
          ain[1][t] = __builtin_amdgcn_mfma_f32_16x16x32_bf16(a1.s8, b[t].s8, ain[1][t], 0, 0, 0);
        }
      } else {
#pragma unroll
        for (int t = 0; t < 4; ++t) {
          ahn[0][t] = __builtin_amdgcn_mfma_f32_16x16x32_bf16(a0.s8, b[t].s8, ahn[0][t], 0, 0, 0);
          ahn[1][t] = __builtin_amdgcn_mfma_f32_16x16x32_bf16(a1.s8, b[t].s8, ahn[1][t], 0, 0, 0);
        }
      }
    }
  }

  // GRU epilogue. D layout per tile: row = quad*4 + r, col = lrow.
#pragma unroll
  for (int t = 0; t < 4; ++t) {
    const int c = hc * 64 + t * 16 + lrow;
    const float brr = b_ih[c] + b_hh[c];
    const float bzz = b_ih[128 + c] + b_hh[128 + c];
    const float bin = b_ih[256 + c];
    const float bhn = b_hh[256 + c];
#pragma unroll
    for (int s = 0; s < 2; ++s) {
#pragma unroll
      for (int r = 0; r < 4; ++r) {
        const int nrow = strip + s * 16 + quad * 4 + r;
        float rg = sigmoid_f(ar[s][t][r] + brr);
        float zg = sigmoid_f(az[s][t][r] + bzz);
        float hv = ahn[s][t][r] + bhn;
        float ng = tanh_f(ain[s][t][r] + bin + rg * hv);
        float hp = bf2f(h[(size_t)nrow * 128 + c]);
        hout[(size_t)nrow * 128 + c] = f2bf((1.f - zg) * ng + zg * hp);
      }
    }
  }
}

// ---------------- CSR aggregation: agg[n] = sum over in-edges of h[src], 8x MLP ----------------
__global__ __launch_bounds__(256)
void agg_kernel(const u16* __restrict__ m, const int* __restrict__ ssrc,
                const int* __restrict__ offsets, u16* __restrict__ agg)
{
  int node = blockIdx.x * 4 + (threadIdx.x >> 6);
  int lane = threadIdx.x & 63;
  if (node >= N_NODES) return;
  int beg = offsets[node], end = offsets[node + 1];
  float s0 = 0.f, s1 = 0.f;
  int e = beg;
  for (; e + 8 <= end; e += 8) {
    u32 v[8];
#pragma unroll
    for (int q = 0; q < 8; ++q) {
      int src = ssrc[e + q];
      v[q] = *(const u32*)(m + (size_t)src * 128 + lane * 2);
    }
#pragma unroll
    for (int q = 0; q < 8; ++q) {
      s0 += bf2f((u16)(v[q] & 0xffffu));
      s1 += bf2f((u16)(v[q] >> 16));
    }
  }
  for (; e < end; ++e) {
    int src = ssrc[e];
    u32 v = *(const u32*)(m + (size_t)src * 128 + lane * 2);
    s0 += bf2f((u16)(v & 0xffffu));
    s1 += bf2f((u16)(v >> 16));
  }
  u32 packed = (u32)f2bf(s0) | ((u32)f2bf(s1) << 16);
  *(u32*)(agg + (size_t)node * 128 + lane * 2) = packed;
}

// ---------------- parallel segmented mean-pool (batch is sorted) ----------------
__global__ __launch_bounds__(256)
void pool_kernel(const u16* __restrict__ h, const int* __restrict__ batch,
                 const int* __restrict__ flags, float* __restrict__ sums)
{
  const int c = threadIdx.x & 127;
  const int half = threadIdx.x >> 7;
  const int base = blockIdx.x * 128;
  const int f = flags[1];
  int gcur = -1; float s = 0.f;
  for (int i = half; i < 128; i += 2) {
    int n = base + i;
    if (n >= N_NODES) break;
    int g = geti(batch, n, f);
    if (g != gcur) {
      if (gcur >= 0) atomicAdd(&sums[gcur * 128 + c], s);
      s = 0.f; gcur = g;
    }
    s += bf2f(h[(size_t)n * 128 + c]);
  }
  if (gcur >= 0) atomicAdd(&sums[gcur * 128 + c], s);
}

// ---------------- doc proj + LN + fusion + heads, f32 (one block per graph) ----------------
__global__ __launch_bounds__(256)
void head2_kernel(const float* __restrict__ sums, const int* __restrict__ batch,
                  const int* __restrict__ flags,
                  const float* __restrict__ doc, const float* __restrict__ doc_w, const float* __restrict__ doc_b,
                  const float* __restrict__ ln_g, const float* __restrict__ ln_b,
                  const float* __restrict__ fus_w, const float* __restrict__ fus_b,
                  const float* __restrict__ task_w, const float* __restrict__ task_b,
                  const float* __restrict__ time_w, const float* __restrict__ time_b,
                  float* __restrict__ out_task, float* __restrict__ out_time)
{
  const int g = blockIdx.x;
  const int t = threadIdx.x;
  __shared__ float fusion[256];
  __shared__ float fh[128];
  __shared__ float dpart[256];
  __shared__ int seg[2];

  if (t < 2) {
    int f = flags[1];
    int target = g + t, lo = 0, hi = N_NODES;
    while (lo < hi) { int mid = (lo + hi) >> 1; if (geti(batch, mid, f) < target) lo = mid + 1; else hi = mid; }
    seg[t] = lo;
  }
  {
    int c = t & 127, kh = t >> 7;
    float s = 0.f;
    for (int k = kh * 384; k < kh * 384 + 384; ++k) s += doc[g * 768 + k] * doc_w[k * 128 + c];
    dpart[t] = s;
  }
  __syncthreads();

  if (t < 128) {
    float cnt = (float)(seg[1] - seg[0]);
    fusion[t] = sums[g * 128 + t] / fmaxf(cnt, 1.f);
  } else {
    int c = t - 128;
    fusion[t] = fmaxf(dpart[c] + dpart[c + 128] + doc_b[c], 0.f);
  }
  __syncthreads();

  float mu = 0.f;
  for (int i = 0; i < 256; ++i) mu += fusion[i];
  mu *= (1.f / 256.f);
  float var = 0.f;
  for (int i = 0; i < 256; ++i) { float d = fusion[i] - mu; var += d * d; }
  var *= (1.f / 256.f);
  float inv = rsqrtf(var + 1e-5f);
  float norm = (fusion[t] - mu) * inv * ln_g[t] + ln_b[t];
  __syncthreads();
  fusion[t] = norm;
  __syncthreads();

  if (t < 128) {
    float s = 0.f;
    for (int k = 0; k < 256; ++k) s += fusion[k] * fus_w[k * 128 + t];
    s += fus_b[t];
    fh[t] = fmaxf(s, 0.f);
  }
  __syncthreads();

  if (t < 32) {
    float s = 0.f;
    for (int k = 0; k < 128; ++k) s += fh[k] * task_w[k * 32 + t];
    s += task_b[t];
    out_task[g * 32 + t] = s;
  }
  if (t == 32) {
    float s = 0.f;
    for (int k = 0; k < 128; ++k) s += fh[k] * time_w[k];
    s += time_b[0];
    out_time[g] = s;
  }
}

// ---------------- launch ----------------
extern "C" void kernel_launch(void* const* d_in, const int* in_sizes, int n_in,
                              void* d_out, int out_size, void* d_ws, size_t ws_size,
                              hipStream_t stream)
{
  const float* x        = (const float*)d_in[0];
  const float* doc      = (const float*)d_in[1];
  const int*   ei       = (const int*)d_in[2];
  const int*   batch    = (const int*)d_in[3];
  const float* node_w   = (const float*)d_in[4];
  const float* node_b   = (const float*)d_in[5];
  const float* ggnn_w   = (const float*)d_in[6];
  const float* gru_w_ih = (const float*)d_in[7];
  const float* gru_b_ih = (const float*)d_in[8];
  const float* gru_w_hh = (const float*)d_in[9];
  const float* gru_b_hh = (const float*)d_in[10];
  const float* doc_w    = (const float*)d_in[11];
  const float* doc_b    = (const float*)d_in[12];
  const float* ln_g     = (const float*)d_in[13];
  const float* ln_b     = (const float*)d_in[14];
  const float* fus_w    = (const float*)d_in[15];
  const float* fus_b    = (const float*)d_in[16];
  const float* task_w   = (const float*)d_in[17];
  const float* task_b   = (const float*)d_in[18];
  const float* time_w   = (const float*)d_in[19];
  const float* time_b   = (const float*)d_in[20];

  char* ws = (char*)d_ws;
  size_t off = 0;
  auto alloc = [&](size_t bytes) -> void* {
    void* p = ws + off;
    off = (off + bytes + 255) & ~(size_t)255;
    return p;
  };
  u16* aggb   = (u16*)alloc((size_t)N_NODES * 128 * 2);
  u16* hA     = (u16*)alloc((size_t)N_NODES * 128 * 2);
  u16* hB     = (u16*)alloc((size_t)N_NODES * 128 * 2);
  u16* nwT    = (u16*)alloc(64 * 128 * 2);
  u16* b2p    = (u16*)alloc(3 * 8 * 1536 * 8 * 2);
  float* wp   = (float*)alloc(3 * 128 * 384 * 4);
  float* sums = (float*)alloc(N_GRAPHS * 128 * 4);
  int* counts = (int*)alloc((size_t)N_NODES * 4);
  int* offs   = (int*)alloc((size_t)(N_NODES + 1) * 4);
  int* ssrc   = (int*)alloc((size_t)N_EDGES * 4);
  u16* rankb  = (u16*)alloc((size_t)N_EDGES * 2);
  int* bsum   = (int*)alloc(SCAN_BLOCKS * 4);
  int* bbase  = (int*)alloc(SCAN_BLOCKS * 4);
  int* flags  = (int*)alloc(2 * 4);

  hipMemsetAsync(counts, 0, (size_t)N_NODES * 4, stream);
  hipMemsetAsync(sums, 0, (size_t)N_GRAPHS * 128 * 4, stream);

  detect_i64_kernel<<<1, 64, 0, stream>>>(ei, batch, flags);
  hist_kernel<<<(N_EDGES + 255) / 256, 256, 0, stream>>>(ei, flags, counts, rankb);
  scanA_kernel<<<SCAN_BLOCKS, 1024, 0, stream>>>(counts, bsum);
  scanB_kernel<<<1, 64, 0, stream>>>(bsum, bbase, offs);
  scanC_kernel<<<SCAN_BLOCKS, 1024, 0, stream>>>(counts, bbase, offs);
  scatter_kernel<<<(N_EDGES + 255) / 256, 256, 0, stream>>>(ei, flags, offs, rankb, ssrc);

  transpose_kernel<<<(64 * 128 + 255) / 256, 256, 0, stream>>>(node_w, nwT, 64, 128);
  wprime_kernel<<<(3 * 128 * 384 + 255) / 256, 256, 0, stream>>>(ggnn_w, gru_w_ih, wp);
  for (int l = 0; l < 3; ++l)
    build_b2p_kernel<<<(8 * 1536 * 8 + 255) / 256, 256, 0, stream>>>(
        wp + l * 128 * 384, gru_w_hh, b2p + (size_t)l * 8 * 1536 * 8);

  const int GB = (N_NODES + 63) / 64;        // 1563
  const int GW = (N_NODES / 32) * 2;         // 6250 waves (100000 % 32 == 0)
  const int GB4 = (GW + 3) / 4;              // 1563 blocks of 4 waves
  nodeproj_gemm<<<GB, 256, 0, stream>>>(x, nwT, node_b, hA, N_NODES);

  u16* hcur = hA;
  u16* hnext = hB;
  for (int l = 0; l < 3; ++l) {
    agg_kernel<<<(N_NODES + 3) / 4, 256, 0, stream>>>(hcur, ssrc, offs, aggb);
    gru_gemm<<<GB4, 256, 0, stream>>>(aggb, hcur, b2p + (size_t)l * 8 * 1536 * 8,
                                      gru_b_ih, gru_b_hh, hnext, N_NODES);
    u16* tmp = hcur; hcur = hnext; hnext = tmp;
  }

  pool_kernel<<<(N_NODES + 127) / 128, 256, 0, stream>>>(hcur, batch, flags, sums);

  float* out_task = (float*)d_out;
  float* out_time = out_task + N_GRAPHS * 32;
  head2_kernel<<<N_GRAPHS, 256, 0, stream>>>(sums, batch, flags, doc, doc_w, doc_b, ln_g, ln_b,
                                             fus_w, fus_b, task_w, task_b, time_w, time_b,
                                             out_task, out_time);
}

// Round 10
// 717.539 us; speedup vs baseline: 2.2861x; 1.0153x over previous
//
#include <hip/hip_runtime.h>

#define N_NODES  100000
#define N_EDGES  1600000
#define N_GRAPHS 128
#define SCAN_BLOCKS 98   // ceil(100000/1024)

typedef unsigned short u16;
typedef unsigned int   u32;
typedef __attribute__((ext_vector_type(8))) short short8;
typedef __attribute__((ext_vector_type(4))) float f32x4;

__device__ __forceinline__ float bf2f(u16 v) {
  union { u32 i; float f; } u; u.i = ((u32)v) << 16; return u.f;
}
__device__ __forceinline__ u16 f2bf(float f) {
  union { float f; u32 i; } u; u.f = f;
  u32 r = (u.i + 0x7fffu + ((u.i >> 16) & 1u)) >> 16;
  return (u16)r;
}
__device__ __forceinline__ float sigmoid_f(float x) { return 1.f / (1.f + __expf(-x)); }
__device__ __forceinline__ float tanh_f(float x) {
  x = fminf(15.f, fmaxf(-15.f, x));
  float e = __expf(2.f * x);
  return (e - 1.f) / (e + 1.f);
}
__device__ __forceinline__ int geti(const int* __restrict__ p, int i, int is64) {
  return p[is64 ? (2 * i) : i];
}

// Detect whether edge_index / batch are int64 (all sampled odd words == 0) or int32.
__global__ void detect_i64_kernel(const int* __restrict__ ei, const int* __restrict__ batch,
                                  int* __restrict__ flags) {
  int lane = threadIdx.x;  // 64
  {
    long long q = (long long)lane * (3200000 / 2 - 1) / 63;
    int pos = (int)(2 * q + 1);
    unsigned long long m = __ballot(ei[pos] != 0);
    if (lane == 0) flags[0] = (m == 0ull) ? 1 : 0;
  }
  {
    long long q = (long long)lane * (100000 / 2 - 1) / 63;
    int pos = (int)(2 * q + 1);
    unsigned long long m = __ballot(batch[pos] != 0);
    if (lane == 0) flags[1] = (m == 0ull) ? 1 : 0;
  }
}

// ---------------- CSR build ----------------
// hist also records each edge's rank among its dst's edges -> scatter needs no atomics.
__global__ void hist_kernel(const int* __restrict__ ei, const int* __restrict__ flags,
                            int* __restrict__ counts, u16* __restrict__ rankb) {
  int e = blockIdx.x * 256 + threadIdx.x;
  if (e < N_EDGES) {
    int f = flags[0];
    int d = geti(ei, N_EDGES + e, f);
    int r = atomicAdd(&counts[d], 1);
    rankb[e] = (u16)r;
  }
}

__global__ __launch_bounds__(1024)
void scanA_kernel(const int* __restrict__ counts, int* __restrict__ blocksums) {
  __shared__ int red[16];
  int i = blockIdx.x * 1024 + threadIdx.x;
  int v = (i < N_NODES) ? counts[i] : 0;
  for (int o = 32; o > 0; o >>= 1) v += __shfl_down(v, o, 64);
  int wv = threadIdx.x >> 6, lane = threadIdx.x & 63;
  if (lane == 0) red[wv] = v;
  __syncthreads();
  if (threadIdx.x < 16) {
    int s = red[threadIdx.x];
    for (int o = 8; o > 0; o >>= 1) s += __shfl_down(s, o, 64);
    if (threadIdx.x == 0) blocksums[blockIdx.x] = s;
  }
}

__global__ void scanB_kernel(const int* __restrict__ blocksums, int* __restrict__ blockbase,
                             int* __restrict__ offsets) {
  if (threadIdx.x == 0) {
    int run = 0;
    for (int b = 0; b < SCAN_BLOCKS; ++b) { blockbase[b] = run; run += blocksums[b]; }
    offsets[N_NODES] = run;
  }
}

__global__ __launch_bounds__(1024)
void scanC_kernel(const int* __restrict__ counts, const int* __restrict__ blockbase,
                  int* __restrict__ offsets) {
  __shared__ int buf[1024];
  int t = threadIdx.x;
  int i = blockIdx.x * 1024 + t;
  int v = (i < N_NODES) ? counts[i] : 0;
  buf[t] = v;
  __syncthreads();
  for (int o = 1; o < 1024; o <<= 1) {
    int add = (t >= o) ? buf[t - o] : 0;
    __syncthreads();
    buf[t] += add;
    __syncthreads();
  }
  if (i < N_NODES) offsets[i] = buf[t] - v + blockbase[blockIdx.x];
}

// atomic-free scatter using precomputed ranks
__global__ void scatter_kernel(const int* __restrict__ ei, const int* __restrict__ flags,
                               const int* __restrict__ offsets, const u16* __restrict__ rankb,
                               int* __restrict__ ssrc) {
  int e = blockIdx.x * 256 + threadIdx.x;
  if (e < N_EDGES) {
    int f = flags[0];
    int d = geti(ei, N_EDGES + e, f);
    ssrc[offsets[d] + (int)rankb[e]] = geti(ei, e, f);
  }
}

// ---------------- weight prep ----------------
// f32 [K][N] row-major -> bf16 [N][K]
__global__ void transpose_kernel(const float* __restrict__ in, u16* __restrict__ out, int K, int N) {
  int i = blockIdx.x * 256 + threadIdx.x;
  if (i < K * N) {
    int k = i / N, n = i % N;
    out[n * K + k] = f2bf(in[i]);
  }
}

// W'_l[k][c] = sum_j ggnn_w[l][k][j] * w_ih[j][c]   (f32, [3][128][384])
__global__ void wprime_kernel(const float* __restrict__ ggnn_w, const float* __restrict__ w_ih,
                              float* __restrict__ wp) {
  int i = blockIdx.x * 256 + threadIdx.x;
  if (i >= 3 * 128 * 384) return;
  int l = i / (128 * 384), r = i % (128 * 384), k = r / 384, c = r % 384;
  const float* W = ggnn_w + l * 128 * 128;
  float s = 0.f;
  for (int j = 0; j < 128; ++j) s += W[k * 128 + j] * w_ih[j * 384 + c];
  wp[i] = s;
}

// Packed GRU weight: b2p[ci][idx][e] u16, ci=0..7 (k-chunk), idx = ko*384 + n_lin,
// e=0..7. Zero quadrants excluded (ci<4: W' cols r|z|in; ci>=4: w_hh cols r|z|hn).
__global__ void build_b2p_kernel(const float* __restrict__ wp, const float* __restrict__ w_hh,
                                 u16* __restrict__ b2p) {
  int g = blockIdx.x * 256 + threadIdx.x;
  if (g >= 8 * 1536 * 8) return;
  int e = g & 7;
  int grp = g >> 3;
  int ci = grp / 1536;
  int idx = grp % 1536;
  int n_lin = idx % 384;
  int ko = idx / 384;
  int k = ci * 32 + ko * 8 + e;
  float v = (k < 128) ? wp[k * 384 + n_lin] : w_hh[(k - 128) * 384 + n_lin];
  b2p[g] = f2bf(v);
}

// ---------------- node projection GEMM (f32 A -> bf16 frags) ----------------
__global__ __launch_bounds__(256)
void nodeproj_gemm(const float* __restrict__ A, const u16* __restrict__ BT,
                   const float* __restrict__ bias, u16* __restrict__ out, int M)
{
  constexpr int K_DIM = 64, N_DIM = 128, NT = 8, NCHUNK = 2;
  __shared__ u16 B_lds[N_DIM * 40];
  const int tid = threadIdx.x, lane = tid & 63, w = tid >> 6;
  const int strip = blockIdx.x * 64;
  const int ksub = (lane >> 4) * 8;
  union Frag { uint4 u; short8 s; };
  Frag af[NCHUNK];
  const int m_node = strip + w * 16 + (lane & 15);
  const bool avalid = (m_node < M);
#pragma unroll
  for (int ci = 0; ci < NCHUNK; ++ci) {
    int k0 = ci * 32 + ksub;
    short8 sv = {0,0,0,0,0,0,0,0};
    if (avalid) {
      const float* p = A + (size_t)m_node * K_DIM + k0;
      float4 f0 = *(const float4*)p;
      float4 f1 = *(const float4*)(p + 4);
      sv[0]=(short)f2bf(f0.x); sv[1]=(short)f2bf(f0.y); sv[2]=(short)f2bf(f0.z); sv[3]=(short)f2bf(f0.w);
      sv[4]=(short)f2bf(f1.x); sv[5]=(short)f2bf(f1.y); sv[6]=(short)f2bf(f1.z); sv[7]=(short)f2bf(f1.w);
    }
    af[ci].s = sv;
  }
  f32x4 acc[NT];
#pragma unroll
  for (int t = 0; t < NT; ++t) acc[t] = {0.f, 0.f, 0.f, 0.f};
  const int boff = (lane & 15) * 40 + ksub;
#pragma unroll
  for (int ci = 0; ci < NCHUNK; ++ci) {
    if (ci) __syncthreads();
    for (int g = tid; g < N_DIM * 4; g += 256) {
      int n = g >> 2, ko = g & 3;
      uint4 bv = *(const uint4*)(BT + (size_t)n * K_DIM + ci * 32 + ko * 8);
      *(uint4*)(&B_lds[n * 40 + ko * 8]) = bv;
    }
    __syncthreads();
    short8 a = af[ci].s;
#pragma unroll
    for (int t = 0; t < NT; ++t) {
      const short8 b = *(const short8*)(&B_lds[t * 16 * 40 + boff]);
      acc[t] = __builtin_amdgcn_mfma_f32_16x16x32_bf16(a, b, acc[t], 0, 0, 0);
    }
  }
  const int mrow = (lane >> 4) * 4;
#pragma unroll
  for (int t = 0; t < NT; ++t) {
    int col = t * 16 + (lane & 15);
    float bv = bias[col];
#pragma unroll
    for (int r = 0; r < 4; ++r) {
      int node = strip + w * 16 + mrow + r;
      if (node < M) out[(size_t)node * N_DIM + col] = f2bf(fmaxf(acc[t][r] + bv, 0.f));
    }
  }
}

// ---------------- GRU GEMM: barrier-free, LDS-free, 32 rows x 32 cols per wave ----------------
// acc = 16 f32x4 (64 regs) -> 3-4 waves/SIMD; B-reuse kept (each B-frag feeds 2 row-strips:
// 8 loads -> 12 MFMA per chunk); the block's 4 waves share one 32-row strip at 4 col-quarters,
// so A-loads (16 KB/block) hit L1 for 3 of 4 waves. No __syncthreads, no LDS.
// Plain __launch_bounds__ — a min-waves arg would cap regs below acc and spill (round 5).
__global__ __launch_bounds__(256)
void gru_gemm(const u16* __restrict__ agg, const u16* __restrict__ h,
              const u16* __restrict__ b2p, const float* __restrict__ b_ih,
              const float* __restrict__ b_hh, u16* __restrict__ hout, int M)
{
  const int tid  = threadIdx.x;
  const int lane = tid & 63;
  const int qc   = tid >> 6;              // col-quarter 0..3 (32 cols each)
  const int strip = blockIdx.x * 32;      // one 32-row strip per block (100000 % 32 == 0)
  const int lrow  = lane & 15;
  const int quad  = lane >> 4;
  const int ksub  = quad * 8;
  if (strip >= M) return;

  f32x4 ar[2][2], az[2][2], ain[2][2], ahn[2][2];
#pragma unroll
  for (int s = 0; s < 2; ++s)
#pragma unroll
    for (int t = 0; t < 2; ++t) {
      ar[s][t] = {0.f,0.f,0.f,0.f}; az[s][t] = {0.f,0.f,0.f,0.f};
      ain[s][t] = {0.f,0.f,0.f,0.f}; ahn[s][t] = {0.f,0.f,0.f,0.f};
    }

  union Frag { uint4 u; short8 s8; };
  const int node0 = strip + lrow;
  const int node1 = strip + 16 + lrow;
  const u16* bb = b2p + ((size_t)quad * 384 + qc * 32 + lrow) * 8;

#pragma unroll
  for (int ci = 0; ci < 8; ++ci) {
    Frag a0, a1;
    {
      const u16* ap = (ci < 4) ? (agg + ci * 32 + ksub) : (h + (ci - 4) * 32 + ksub);
      a0.u = *(const uint4*)(ap + (size_t)node0 * 128);
      a1.u = *(const uint4*)(ap + (size_t)node1 * 128);
    }
    const u16* cb = bb + ci * 12288;
    {  // r gate: n_lin qc*32 + t*16
      Frag b[2];
#pragma unroll
      for (int t = 0; t < 2; ++t) b[t].u = *(const uint4*)(cb + t * 128);
#pragma unroll
      for (int t = 0; t < 2; ++t) {
        ar[0][t] = __builtin_amdgcn_mfma_f32_16x16x32_bf16(a0.s8, b[t].s8, ar[0][t], 0, 0, 0);
        ar[1][t] = __builtin_amdgcn_mfma_f32_16x16x32_bf16(a1.s8, b[t].s8, ar[1][t], 0, 0, 0);
      }
    }
    {  // z gate: +128 n_lin
      Frag b[2];
#pragma unroll
      for (int t = 0; t < 2; ++t) b[t].u = *(const uint4*)(cb + 1024 + t * 128);
#pragma unroll
      for (int t = 0; t < 2; ++t) {
        az[0][t] = __builtin_amdgcn_mfma_f32_16x16x32_bf16(a0.s8, b[t].s8, az[0][t], 0, 0, 0);
        az[1][t] = __builtin_amdgcn_mfma_f32_16x16x32_bf16(a1.s8, b[t].s8, az[1][t], 0, 0, 0);
      }
    }
    {  // in (ci<4) / hn (ci>=4): +256 n_lin
      Frag b[2];
#pragma unroll
      for (int t = 0; t < 2; ++t) b[t].u = *(const uint4*)(cb + 2048 + t * 128);
      if (ci < 4) {
#pragma unroll
        for (int t = 0; t < 2; ++t) {
          ain[0][t] = __builtin_amdgcn_mfma_f32_16x16x32_bf16(a0.s8, b[t].s8, ain[0][t], 0, 0, 0);
          ain[1][t] = __builtin_amdgcn_mfma_f32_16x16x32_bf16(a1.s8, b[t].s8, ain[1][t], 0, 0, 0);
        }
      } else {
#pragma unroll
        for (int t = 0; t < 2; ++t) {
          ahn[0][t] = __builtin_amdgcn_mfma_f32_16x16x32_bf16(a0.s8, b[t].s8, ahn[0][t], 0, 0, 0);
          ahn[1][t] = __builtin_amdgcn_mfma_f32_16x16x32_bf16(a1.s8, b[t].s8, ahn[1][t], 0, 0, 0);
        }
      }
    }
  }

  // GRU epilogue. D layout per tile: row = quad*4 + r, col = lrow.
#pragma unroll
  for (int t = 0; t < 2; ++t) {
    const int c = qc * 32 + t * 16 + lrow;
    const float brr = b_ih[c] + b_hh[c];
    const float bzz = b_ih[128 + c] + b_hh[128 + c];
    const float bin = b_ih[256 + c];
    const float bhn = b_hh[256 + c];
#pragma unroll
    for (int s = 0; s < 2; ++s) {
#pragma unroll
      for (int r = 0; r < 4; ++r) {
        const int nrow = strip + s * 16 + quad * 4 + r;
        float rg = sigmoid_f(ar[s][t][r] + brr);
        float zg = sigmoid_f(az[s][t][r] + bzz);
        float hv = ahn[s][t][r] + bhn;
        float ng = tanh_f(ain[s][t][r] + bin + rg * hv);
        float hp = bf2f(h[(size_t)nrow * 128 + c]);
        hout[(size_t)nrow * 128 + c] = f2bf((1.f - zg) * ng + zg * hp);
      }
    }
  }
}

// ---------------- CSR aggregation: agg[n] = sum over in-edges of h[src], 8x MLP ----------------
__global__ __launch_bounds__(256)
void agg_kernel(const u16* __restrict__ m, const int* __restrict__ ssrc,
                const int* __restrict__ offsets, u16* __restrict__ agg)
{
  int node = blockIdx.x * 4 + (threadIdx.x >> 6);
  int lane = threadIdx.x & 63;
  if (node >= N_NODES) return;
  int beg = offsets[node], end = offsets[node + 1];
  float s0 = 0.f, s1 = 0.f;
  int e = beg;
  for (; e + 8 <= end; e += 8) {
    u32 v[8];
#pragma unroll
    for (int q = 0; q < 8; ++q) {
      int src = ssrc[e + q];
      v[q] = *(const u32*)(m + (size_t)src * 128 + lane * 2);
    }
#pragma unroll
    for (int q = 0; q < 8; ++q) {
      s0 += bf2f((u16)(v[q] & 0xffffu));
      s1 += bf2f((u16)(v[q] >> 16));
    }
  }
  for (; e < end; ++e) {
    int src = ssrc[e];
    u32 v = *(const u32*)(m + (size_t)src * 128 + lane * 2);
    s0 += bf2f((u16)(v & 0xffffu));
    s1 += bf2f((u16)(v >> 16));
  }
  u32 packed = (u32)f2bf(s0) | ((u32)f2bf(s1) << 16);
  *(u32*)(agg + (size_t)node * 128 + lane * 2) = packed;
}

// ---------------- parallel segmented mean-pool (batch is sorted) ----------------
__global__ __launch_bounds__(256)
void pool_kernel(const u16* __restrict__ h, const int* __restrict__ batch,
                 const int* __restrict__ flags, float* __restrict__ sums)
{
  const int c = threadIdx.x & 127;
  const int half = threadIdx.x >> 7;
  const int base = blockIdx.x * 128;
  const int f = flags[1];
  int gcur = -1; float s = 0.f;
  for (int i = half; i < 128; i += 2) {
    int n = base + i;
    if (n >= N_NODES) break;
    int g = geti(batch, n, f);
    if (g != gcur) {
      if (gcur >= 0) atomicAdd(&sums[gcur * 128 + c], s);
      s = 0.f; gcur = g;
    }
    s += bf2f(h[(size_t)n * 128 + c]);
  }
  if (gcur >= 0) atomicAdd(&sums[gcur * 128 + c], s);
}

// ---------------- doc proj + LN + fusion + heads, f32 (one block per graph) ----------------
__global__ __launch_bounds__(256)
void head2_kernel(const float* __restrict__ sums, const int* __restrict__ batch,
                  const int* __restrict__ flags,
                  const float* __restrict__ doc, const float* __restrict__ doc_w, const float* __restrict__ doc_b,
                  const float* __restrict__ ln_g, const float* __restrict__ ln_b,
                  const float* __restrict__ fus_w, const float* __restrict__ fus_b,
                  const float* __restrict__ task_w, const float* __restrict__ task_b,
                  const float* __restrict__ time_w, const float* __restrict__ time_b,
                  float* __restrict__ out_task, float* __restrict__ out_time)
{
  const int g = blockIdx.x;
  const int t = threadIdx.x;
  __shared__ float fusion[256];
  __shared__ float fh[128];
  __shared__ float dpart[256];
  __shared__ int seg[2];

  if (t < 2) {
    int f = flags[1];
    int target = g + t, lo = 0, hi = N_NODES;
    while (lo < hi) { int mid = (lo + hi) >> 1; if (geti(batch, mid, f) < target) lo = mid + 1; else hi = mid; }
    seg[t] = lo;
  }
  {
    int c = t & 127, kh = t >> 7;
    float s = 0.f;
    for (int k = kh * 384; k < kh * 384 + 384; ++k) s += doc[g * 768 + k] * doc_w[k * 128 + c];
    dpart[t] = s;
  }
  __syncthreads();

  if (t < 128) {
    float cnt = (float)(seg[1] - seg[0]);
    fusion[t] = sums[g * 128 + t] / fmaxf(cnt, 1.f);
  } else {
    int c = t - 128;
    fusion[t] = fmaxf(dpart[c] + dpart[c + 128] + doc_b[c], 0.f);
  }
  __syncthreads();

  float mu = 0.f;
  for (int i = 0; i < 256; ++i) mu += fusion[i];
  mu *= (1.f / 256.f);
  float var = 0.f;
  for (int i = 0; i < 256; ++i) { float d = fusion[i] - mu; var += d * d; }
  var *= (1.f / 256.f);
  float inv = rsqrtf(var + 1e-5f);
  float norm = (fusion[t] - mu) * inv * ln_g[t] + ln_b[t];
  __syncthreads();
  fusion[t] = norm;
  __syncthreads();

  if (t < 128) {
    float s = 0.f;
    for (int k = 0; k < 256; ++k) s += fusion[k] * fus_w[k * 128 + t];
    s += fus_b[t];
    fh[t] = fmaxf(s, 0.f);
  }
  __syncthreads();

  if (t < 32) {
    float s = 0.f;
    for (int k = 0; k < 128; ++k) s += fh[k] * task_w[k * 32 + t];
    s += task_b[t];
    out_task[g * 32 + t] = s;
  }
  if (t == 32) {
    float s = 0.f;
    for (int k = 0; k < 128; ++k) s += fh[k] * time_w[k];
    s += time_b[0];
    out_time[g] = s;
  }
}

// ---------------- launch ----------------
extern "C" void kernel_launch(void* const* d_in, const int* in_sizes, int n_in,
                              void* d_out, int out_size, void* d_ws, size_t ws_size,
                              hipStream_t stream)
{
  const float* x        = (const float*)d_in[0];
  const float* doc      = (const float*)d_in[1];
  const int*   ei       = (const int*)d_in[2];
  const int*   batch    = (const int*)d_in[3];
  const float* node_w   = (const float*)d_in[4];
  const float* node_b   = (const float*)d_in[5];
  const float* ggnn_w   = (const float*)d_in[6];
  const float* gru_w_ih = (const float*)d_in[7];
  const float* gru_b_ih = (const float*)d_in[8];
  const float* gru_w_hh = (const float*)d_in[9];
  const float* gru_b_hh = (const float*)d_in[10];
  const float* doc_w    = (const float*)d_in[11];
  const float* doc_b    = (const float*)d_in[12];
  const float* ln_g     = (const float*)d_in[13];
  const float* ln_b     = (const float*)d_in[14];
  const float* fus_w    = (const float*)d_in[15];
  const float* fus_b    = (const float*)d_in[16];
  const float* task_w   = (const float*)d_in[17];
  const float* task_b   = (const float*)d_in[18];
  const float* time_w   = (const float*)d_in[19];
  const float* time_b   = (const float*)d_in[20];

  char* ws = (char*)d_ws;
  size_t off = 0;
  auto alloc = [&](size_t bytes) -> void* {
    void* p = ws + off;
    off = (off + bytes + 255) & ~(size_t)255;
    return p;
  };
  u16* aggb   = (u16*)alloc((size_t)N_NODES * 128 * 2);
  u16* hA     = (u16*)alloc((size_t)N_NODES * 128 * 2);
  u16* hB     = (u16*)alloc((size_t)N_NODES * 128 * 2);
  u16* nwT    = (u16*)alloc(64 * 128 * 2);
  u16* b2p    = (u16*)alloc(3 * 8 * 1536 * 8 * 2);
  float* wp   = (float*)alloc(3 * 128 * 384 * 4);
  float* sums = (float*)alloc(N_GRAPHS * 128 * 4);
  int* counts = (int*)alloc((size_t)N_NODES * 4);
  int* offs   = (int*)alloc((size_t)(N_NODES + 1) * 4);
  int* ssrc   = (int*)alloc((size_t)N_EDGES * 4);
  u16* rankb  = (u16*)alloc((size_t)N_EDGES * 2);
  int* bsum   = (int*)alloc(SCAN_BLOCKS * 4);
  int* bbase  = (int*)alloc(SCAN_BLOCKS * 4);
  int* flags  = (int*)alloc(2 * 4);

  hipMemsetAsync(counts, 0, (size_t)N_NODES * 4, stream);
  hipMemsetAsync(sums, 0, (size_t)N_GRAPHS * 128 * 4, stream);

  detect_i64_kernel<<<1, 64, 0, stream>>>(ei, batch, flags);
  hist_kernel<<<(N_EDGES + 255) / 256, 256, 0, stream>>>(ei, flags, counts, rankb);
  scanA_kernel<<<SCAN_BLOCKS, 1024, 0, stream>>>(counts, bsum);
  scanB_kernel<<<1, 64, 0, stream>>>(bsum, bbase, offs);
  scanC_kernel<<<SCAN_BLOCKS, 1024, 0, stream>>>(counts, bbase, offs);
  scatter_kernel<<<(N_EDGES + 255) / 256, 256, 0, stream>>>(ei, flags, offs, rankb, ssrc);

  transpose_kernel<<<(64 * 128 + 255) / 256, 256, 0, stream>>>(node_w, nwT, 64, 128);
  wprime_kernel<<<(3 * 128 * 384 + 255) / 256, 256, 0, stream>>>(ggnn_w, gru_w_ih, wp);
  for (int l = 0; l < 3; ++l)
    build_b2p_kernel<<<(8 * 1536 * 8 + 255) / 256, 256, 0, stream>>>(
        wp + l * 128 * 384, gru_w_hh, b2p + (size_t)l * 8 * 1536 * 8);

  const int GB = (N_NODES + 63) / 64;    // 1563
  const int GB32 = N_NODES / 32;         // 3125 blocks; 4 waves = 4 col-quarters of one strip
  nodeproj_gemm<<<GB, 256, 0, stream>>>(x, nwT, node_b, hA, N_NODES);

  u16* hcur = hA;
  u16* hnext = hB;
  for (int l = 0; l < 3; ++l) {
    agg_kernel<<<(N_NODES + 3) / 4, 256, 0, stream>>>(hcur, ssrc, offs, aggb);
    gru_gemm<<<GB32, 256, 0, stream>>>(aggb, hcur, b2p + (size_t)l * 8 * 1536 * 8,
                                       gru_b_ih, gru_b_hh, hnext, N_NODES);
    u16* tmp = hcur; hcur = hnext; hnext = tmp;
  }

  pool_kernel<<<(N_NODES + 127) / 128, 256, 0, stream>>>(hcur, batch, flags, sums);

  float* out_task = (float*)d_out;
  float* out_time = out_task + N_GRAPHS * 32;
  head2_kernel<<<N_GRAPHS, 256, 0, stream>>>(sums, batch, flags, doc, doc_w, doc_b, ln_g, ln_b,
                                             fus_w, fus_b, task_w, task_b, time_w, time_b,
                                             out_task, out_time);
}

// Round 11
// 667.363 us; speedup vs baseline: 2.4579x; 1.0752x over previous
//
#include <hip/hip_runtime.h>

#define N_NODES  100000
#define N_EDGES  1600000
#define N_GRAPHS 128
#define SCAN_BLOCKS 98   // ceil(100000/1024)

typedef unsigned short u16;
typedef unsigned int   u32;
typedef __attribute__((ext_vector_type(8))) short short8;
typedef __attribute__((ext_vector_type(4))) float f32x4;

__device__ __forceinline__ float bf2f(u16 v) {
  union { u32 i; float f; } u; u.i = ((u32)v) << 16; return u.f;
}
__device__ __forceinline__ u16 f2bf(float f) {
  union { float f; u32 i; } u; u.f = f;
  u32 r = (u.i + 0x7fffu + ((u.i >> 16) & 1u)) >> 16;
  return (u16)r;
}
__device__ __forceinline__ float sigmoid_f(float x) { return 1.f / (1.f + __expf(-x)); }
__device__ __forceinline__ float tanh_f(float x) {
  x = fminf(15.f, fmaxf(-15.f, x));
  float e = __expf(2.f * x);
  return (e - 1.f) / (e + 1.f);
}
__device__ __forceinline__ int geti(const int* __restrict__ p, int i, int is64) {
  return p[is64 ? (2 * i) : i];
}

// Detect whether edge_index / batch are int64 (all sampled odd words == 0) or int32.
__global__ void detect_i64_kernel(const int* __restrict__ ei, const int* __restrict__ batch,
                                  int* __restrict__ flags) {
  int lane = threadIdx.x;  // 64
  {
    long long q = (long long)lane * (3200000 / 2 - 1) / 63;
    int pos = (int)(2 * q + 1);
    unsigned long long m = __ballot(ei[pos] != 0);
    if (lane == 0) flags[0] = (m == 0ull) ? 1 : 0;
  }
  {
    long long q = (long long)lane * (100000 / 2 - 1) / 63;
    int pos = (int)(2 * q + 1);
    unsigned long long m = __ballot(batch[pos] != 0);
    if (lane == 0) flags[1] = (m == 0ull) ? 1 : 0;
  }
}

// ---------------- CSR build ----------------
// hist also records each edge's rank among its dst's edges -> scatter needs no atomics.
__global__ void hist_kernel(const int* __restrict__ ei, const int* __restrict__ flags,
                            int* __restrict__ counts, u16* __restrict__ rankb) {
  int e = blockIdx.x * 256 + threadIdx.x;
  if (e < N_EDGES) {
    int f = flags[0];
    int d = geti(ei, N_EDGES + e, f);
    int r = atomicAdd(&counts[d], 1);
    rankb[e] = (u16)r;
  }
}

__global__ __launch_bounds__(1024)
void scanA_kernel(const int* __restrict__ counts, int* __restrict__ blocksums) {
  __shared__ int red[16];
  int i = blockIdx.x * 1024 + threadIdx.x;
  int v = (i < N_NODES) ? counts[i] : 0;
  for (int o = 32; o > 0; o >>= 1) v += __shfl_down(v, o, 64);
  int wv = threadIdx.x >> 6, lane = threadIdx.x & 63;
  if (lane == 0) red[wv] = v;
  __syncthreads();
  if (threadIdx.x < 16) {
    int s = red[threadIdx.x];
    for (int o = 8; o > 0; o >>= 1) s += __shfl_down(s, o, 64);
    if (threadIdx.x == 0) blocksums[blockIdx.x] = s;
  }
}

__global__ void scanB_kernel(const int* __restrict__ blocksums, int* __restrict__ blockbase,
                             int* __restrict__ offsets) {
  if (threadIdx.x == 0) {
    int run = 0;
    for (int b = 0; b < SCAN_BLOCKS; ++b) { blockbase[b] = run; run += blocksums[b]; }
    offsets[N_NODES] = run;
  }
}

__global__ __launch_bounds__(1024)
void scanC_kernel(const int* __restrict__ counts, const int* __restrict__ blockbase,
                  int* __restrict__ offsets) {
  __shared__ int buf[1024];
  int t = threadIdx.x;
  int i = blockIdx.x * 1024 + t;
  int v = (i < N_NODES) ? counts[i] : 0;
  buf[t] = v;
  __syncthreads();
  for (int o = 1; o < 1024; o <<= 1) {
    int add = (t >= o) ? buf[t - o] : 0;
    __syncthreads();
    buf[t] += add;
    __syncthreads();
  }
  if (i < N_NODES) offsets[i] = buf[t] - v + blockbase[blockIdx.x];
}

// atomic-free scatter using precomputed ranks
__global__ void scatter_kernel(const int* __restrict__ ei, const int* __restrict__ flags,
                               const int* __restrict__ offsets, const u16* __restrict__ rankb,
                               int* __restrict__ ssrc) {
  int e = blockIdx.x * 256 + threadIdx.x;
  if (e < N_EDGES) {
    int f = flags[0];
    int d = geti(ei, N_EDGES + e, f);
    ssrc[offsets[d] + (int)rankb[e]] = geti(ei, e, f);
  }
}

// ---------------- weight prep ----------------
// f32 [K][N] row-major -> bf16 [N][K]
__global__ void transpose_kernel(const float* __restrict__ in, u16* __restrict__ out, int K, int N) {
  int i = blockIdx.x * 256 + threadIdx.x;
  if (i < K * N) {
    int k = i / N, n = i % N;
    out[n * K + k] = f2bf(in[i]);
  }
}

// W'_l[k][c] = sum_j ggnn_w[l][k][j] * w_ih[j][c]   (f32, [3][128][384])
__global__ void wprime_kernel(const float* __restrict__ ggnn_w, const float* __restrict__ w_ih,
                              float* __restrict__ wp) {
  int i = blockIdx.x * 256 + threadIdx.x;
  if (i >= 3 * 128 * 384) return;
  int l = i / (128 * 384), r = i % (128 * 384), k = r / 384, c = r % 384;
  const float* W = ggnn_w + l * 128 * 128;
  float s = 0.f;
  for (int j = 0; j < 128; ++j) s += W[k * 128 + j] * w_ih[j * 384 + c];
  wp[i] = s;
}

// Packed GRU weight: b2p[ci][idx][e] u16, ci=0..7 (k-chunk), idx = ko*384 + n_lin,
// e=0..7. Zero quadrants excluded (ci<4: W' cols r|z|in; ci>=4: w_hh cols r|z|hn).
__global__ void build_b2p_kernel(const float* __restrict__ wp, const float* __restrict__ w_hh,
                                 u16* __restrict__ b2p) {
  int g = blockIdx.x * 256 + threadIdx.x;
  if (g >= 8 * 1536 * 8) return;
  int e = g & 7;
  int grp = g >> 3;
  int ci = grp / 1536;
  int idx = grp % 1536;
  int n_lin = idx % 384;
  int ko = idx / 384;
  int k = ci * 32 + ko * 8 + e;
  float v = (k < 128) ? wp[k * 384 + n_lin] : w_hh[(k - 128) * 384 + n_lin];
  b2p[g] = f2bf(v);
}

// ---------------- node projection GEMM (f32 A -> bf16 frags) ----------------
__global__ __launch_bounds__(256)
void nodeproj_gemm(const float* __restrict__ A, const u16* __restrict__ BT,
                   const float* __restrict__ bias, u16* __restrict__ out, int M)
{
  constexpr int K_DIM = 64, N_DIM = 128, NT = 8, NCHUNK = 2;
  __shared__ u16 B_lds[N_DIM * 40];
  const int tid = threadIdx.x, lane = tid & 63, w = tid >> 6;
  const int strip = blockIdx.x * 64;
  const int ksub = (lane >> 4) * 8;
  union Frag { uint4 u; short8 s; };
  Frag af[NCHUNK];
  const int m_node = strip + w * 16 + (lane & 15);
  const bool avalid = (m_node < M);
#pragma unroll
  for (int ci = 0; ci < NCHUNK; ++ci) {
    int k0 = ci * 32 + ksub;
    short8 sv = {0,0,0,0,0,0,0,0};
    if (avalid) {
      const float* p = A + (size_t)m_node * K_DIM + k0;
      float4 f0 = *(const float4*)p;
      float4 f1 = *(const float4*)(p + 4);
      sv[0]=(short)f2bf(f0.x); sv[1]=(short)f2bf(f0.y); sv[2]=(short)f2bf(f0.z); sv[3]=(short)f2bf(f0.w);
      sv[4]=(short)f2bf(f1.x); sv[5]=(short)f2bf(f1.y); sv[6]=(short)f2bf(f1.z); sv[7]=(short)f2bf(f1.w);
    }
    af[ci].s = sv;
  }
  f32x4 acc[NT];
#pragma unroll
  for (int t = 0; t < NT; ++t) acc[t] = {0.f, 0.f, 0.f, 0.f};
  const int boff = (lane & 15) * 40 + ksub;
#pragma unroll
  for (int ci = 0; ci < NCHUNK; ++ci) {
    if (ci) __syncthreads();
    for (int g = tid; g < N_DIM * 4; g += 256) {
      int n = g >> 2, ko = g & 3;
      uint4 bv = *(const uint4*)(BT + (size_t)n * K_DIM + ci * 32 + ko * 8);
      *(uint4*)(&B_lds[n * 40 + ko * 8]) = bv;
    }
    __syncthreads();
    short8 a = af[ci].s;
#pragma unroll
    for (int t = 0; t < NT; ++t) {
      const short8 b = *(const short8*)(&B_lds[t * 16 * 40 + boff]);
      acc[t] = __builtin_amdgcn_mfma_f32_16x16x32_bf16(a, b, acc[t], 0, 0, 0);
    }
  }
  const int mrow = (lane >> 4) * 4;
#pragma unroll
  for (int t = 0; t < NT; ++t) {
    int col = t * 16 + (lane & 15);
    float bv = bias[col];
#pragma unroll
    for (int r = 0; r < 4; ++r) {
      int node = strip + w * 16 + mrow + r;
      if (node < M) out[(size_t)node * N_DIM + col] = f2bf(fmaxf(acc[t][r] + bv, 0.f));
    }
  }
}

// ---------------- GRU GEMM: barrier-free, LDS-free, 32x32/wave, 2-chunk software pipeline ----------------
// Round 10 showed the kernel dependency-latency-bound (loads issued right before their MFMAs,
// VGPR=68 -> compiler hoisted nothing). Ping-pong fragment buffers: chunk ci+1's 8 loads are
// issued BEFORE chunk ci's MFMAs, doubling memory-level parallelism per wave. ~150 regs, still
// ~3 waves/SIMD. Plain __launch_bounds__ — a min-waves arg would cap regs below acc and spill.
__global__ __launch_bounds__(256)
void gru_gemm(const u16* __restrict__ agg, const u16* __restrict__ h,
              const u16* __restrict__ b2p, const float* __restrict__ b_ih,
              const float* __restrict__ b_hh, u16* __restrict__ hout, int M)
{
  const int tid  = threadIdx.x;
  const int lane = tid & 63;
  const int qc   = tid >> 6;              // col-quarter 0..3 (32 cols each)
  const int strip = blockIdx.x * 32;      // one 32-row strip per block (100000 % 32 == 0)
  const int lrow  = lane & 15;
  const int quad  = lane >> 4;
  const int ksub  = quad * 8;
  if (strip >= M) return;

  f32x4 ar[2][2], az[2][2], ain[2][2], ahn[2][2];
#pragma unroll
  for (int s = 0; s < 2; ++s)
#pragma unroll
    for (int t = 0; t < 2; ++t) {
      ar[s][t] = {0.f,0.f,0.f,0.f}; az[s][t] = {0.f,0.f,0.f,0.f};
      ain[s][t] = {0.f,0.f,0.f,0.f}; ahn[s][t] = {0.f,0.f,0.f,0.f};
    }

  union Frag { uint4 u; short8 s8; };
  const int node0 = strip + lrow;
  const int node1 = strip + 16 + lrow;
  const u16* bb = b2p + ((size_t)quad * 384 + qc * 32 + lrow) * 8;

  Frag a0[2], a1[2], fbr[2][2], fbz[2][2], fbg[2][2];

  auto ldchunk = [&](int ci, int p) {
    const u16* ap = (ci < 4) ? (agg + ci * 32 + ksub) : (h + (ci - 4) * 32 + ksub);
    a0[p].u = *(const uint4*)(ap + (size_t)node0 * 128);
    a1[p].u = *(const uint4*)(ap + (size_t)node1 * 128);
    const u16* cb = bb + ci * 12288;
    fbr[p][0].u = *(const uint4*)(cb);
    fbr[p][1].u = *(const uint4*)(cb + 128);
    fbz[p][0].u = *(const uint4*)(cb + 1024);
    fbz[p][1].u = *(const uint4*)(cb + 1024 + 128);
    fbg[p][0].u = *(const uint4*)(cb + 2048);
    fbg[p][1].u = *(const uint4*)(cb + 2048 + 128);
  };

  ldchunk(0, 0);
#pragma unroll
  for (int ci = 0; ci < 8; ++ci) {
    const int p = ci & 1, q = p ^ 1;
    if (ci < 7) ldchunk(ci + 1, q);   // prefetch next chunk before consuming current
#pragma unroll
    for (int t = 0; t < 2; ++t) {
      ar[0][t] = __builtin_amdgcn_mfma_f32_16x16x32_bf16(a0[p].s8, fbr[p][t].s8, ar[0][t], 0, 0, 0);
      ar[1][t] = __builtin_amdgcn_mfma_f32_16x16x32_bf16(a1[p].s8, fbr[p][t].s8, ar[1][t], 0, 0, 0);
      az[0][t] = __builtin_amdgcn_mfma_f32_16x16x32_bf16(a0[p].s8, fbz[p][t].s8, az[0][t], 0, 0, 0);
      az[1][t] = __builtin_amdgcn_mfma_f32_16x16x32_bf16(a1[p].s8, fbz[p][t].s8, az[1][t], 0, 0, 0);
    }
    if (ci < 4) {
#pragma unroll
      for (int t = 0; t < 2; ++t) {
        ain[0][t] = __builtin_amdgcn_mfma_f32_16x16x32_bf16(a0[p].s8, fbg[p][t].s8, ain[0][t], 0, 0, 0);
        ain[1][t] = __builtin_amdgcn_mfma_f32_16x16x32_bf16(a1[p].s8, fbg[p][t].s8, ain[1][t], 0, 0, 0);
      }
    } else {
#pragma unroll
      for (int t = 0; t < 2; ++t) {
        ahn[0][t] = __builtin_amdgcn_mfma_f32_16x16x32_bf16(a0[p].s8, fbg[p][t].s8, ahn[0][t], 0, 0, 0);
        ahn[1][t] = __builtin_amdgcn_mfma_f32_16x16x32_bf16(a1[p].s8, fbg[p][t].s8, ahn[1][t], 0, 0, 0);
      }
    }
  }

  // GRU epilogue. D layout per tile: row = quad*4 + r, col = lrow.
#pragma unroll
  for (int t = 0; t < 2; ++t) {
    const int c = qc * 32 + t * 16 + lrow;
    const float brr = b_ih[c] + b_hh[c];
    const float bzz = b_ih[128 + c] + b_hh[128 + c];
    const float bin = b_ih[256 + c];
    const float bhn = b_hh[256 + c];
#pragma unroll
    for (int s = 0; s < 2; ++s) {
#pragma unroll
      for (int r = 0; r < 4; ++r) {
        const int nrow = strip + s * 16 + quad * 4 + r;
        float rg = sigmoid_f(ar[s][t][r] + brr);
        float zg = sigmoid_f(az[s][t][r] + bzz);
        float hv = ahn[s][t][r] + bhn;
        float ng = tanh_f(ain[s][t][r] + bin + rg * hv);
        float hp = bf2f(h[(size_t)nrow * 128 + c]);
        hout[(size_t)nrow * 128 + c] = f2bf((1.f - zg) * ng + zg * hp);
      }
    }
  }
}

// ---------------- CSR aggregation, row-vectorized ----------------
// 16 lanes cover one 256B row with uint4 loads -> 4 edge-rows per instruction (4x fewer
// VMEM instructions at identical traffic/coalescing). Cross-group shfl_xor(16/32) reduce,
// 16-lane packed uint4 writeback.
__global__ __launch_bounds__(256)
void agg_kernel(const u16* __restrict__ m, const int* __restrict__ ssrc,
                const int* __restrict__ offsets, u16* __restrict__ agg)
{
  int node = blockIdx.x * 4 + (threadIdx.x >> 6);
  int lane = threadIdx.x & 63;
  if (node >= N_NODES) return;
  const int g = lane >> 4, l = lane & 15;
  int beg = offsets[node], end = offsets[node + 1];
  float s[8] = {0.f,0.f,0.f,0.f,0.f,0.f,0.f,0.f};
  for (int e = beg; e < end; e += 8) {   // 2 groups of 4 edges in flight
    uint4 v0 = {0u,0u,0u,0u}, v1 = {0u,0u,0u,0u};
    int e0 = e + g, e1 = e + 4 + g;
    if (e0 < end) { int src = ssrc[e0]; v0 = *(const uint4*)(m + (size_t)src * 128 + l * 8); }
    if (e1 < end) { int src = ssrc[e1]; v1 = *(const uint4*)(m + (size_t)src * 128 + l * 8); }
    u32 w0[4] = {v0.x, v0.y, v0.z, v0.w};
    u32 w1[4] = {v1.x, v1.y, v1.z, v1.w};
#pragma unroll
    for (int i = 0; i < 4; ++i) {
      s[2*i]   += bf2f((u16)(w0[i] & 0xffffu)) + bf2f((u16)(w1[i] & 0xffffu));
      s[2*i+1] += bf2f((u16)(w0[i] >> 16))     + bf2f((u16)(w1[i] >> 16));
    }
  }
#pragma unroll
  for (int i = 0; i < 8; ++i) {
    s[i] += __shfl_xor(s[i], 16, 64);
    s[i] += __shfl_xor(s[i], 32, 64);
  }
  if (g == 0) {
    uint4 o;
    o.x = (u32)f2bf(s[0]) | ((u32)f2bf(s[1]) << 16);
    o.y = (u32)f2bf(s[2]) | ((u32)f2bf(s[3]) << 16);
    o.z = (u32)f2bf(s[4]) | ((u32)f2bf(s[5]) << 16);
    o.w = (u32)f2bf(s[6]) | ((u32)f2bf(s[7]) << 16);
    *(uint4*)(agg + (size_t)node * 128 + l * 8) = o;
  }
}

// ---------------- parallel segmented mean-pool (batch is sorted) ----------------
__global__ __launch_bounds__(256)
void pool_kernel(const u16* __restrict__ h, const int* __restrict__ batch,
                 const int* __restrict__ flags, float* __restrict__ sums)
{
  const int c = threadIdx.x & 127;
  const int half = threadIdx.x >> 7;
  const int base = blockIdx.x * 128;
  const int f = flags[1];
  int gcur = -1; float s = 0.f;
  for (int i = half; i < 128; i += 2) {
    int n = base + i;
    if (n >= N_NODES) break;
    int g = geti(batch, n, f);
    if (g != gcur) {
      if (gcur >= 0) atomicAdd(&sums[gcur * 128 + c], s);
      s = 0.f; gcur = g;
    }
    s += bf2f(h[(size_t)n * 128 + c]);
  }
  if (gcur >= 0) atomicAdd(&sums[gcur * 128 + c], s);
}

// ---------------- doc proj + LN + fusion + heads, f32 (one block per graph) ----------------
__global__ __launch_bounds__(256)
void head2_kernel(const float* __restrict__ sums, const int* __restrict__ batch,
                  const int* __restrict__ flags,
                  const float* __restrict__ doc, const float* __restrict__ doc_w, const float* __restrict__ doc_b,
                  const float* __restrict__ ln_g, const float* __restrict__ ln_b,
                  const float* __restrict__ fus_w, const float* __restrict__ fus_b,
                  const float* __restrict__ task_w, const float* __restrict__ task_b,
                  const float* __restrict__ time_w, const float* __restrict__ time_b,
                  float* __restrict__ out_task, float* __restrict__ out_time)
{
  const int g = blockIdx.x;
  const int t = threadIdx.x;
  __shared__ float fusion[256];
  __shared__ float fh[128];
  __shared__ float dpart[256];
  __shared__ int seg[2];

  if (t < 2) {
    int f = flags[1];
    int target = g + t, lo = 0, hi = N_NODES;
    while (lo < hi) { int mid = (lo + hi) >> 1; if (geti(batch, mid, f) < target) lo = mid + 1; else hi = mid; }
    seg[t] = lo;
  }
  {
    int c = t & 127, kh = t >> 7;
    float s = 0.f;
    for (int k = kh * 384; k < kh * 384 + 384; ++k) s += doc[g * 768 + k] * doc_w[k * 128 + c];
    dpart[t] = s;
  }
  __syncthreads();

  if (t < 128) {
    float cnt = (float)(seg[1] - seg[0]);
    fusion[t] = sums[g * 128 + t] / fmaxf(cnt, 1.f);
  } else {
    int c = t - 128;
    fusion[t] = fmaxf(dpart[c] + dpart[c + 128] + doc_b[c], 0.f);
  }
  __syncthreads();

  float mu = 0.f;
  for (int i = 0; i < 256; ++i) mu += fusion[i];
  mu *= (1.f / 256.f);
  float var = 0.f;
  for (int i = 0; i < 256; ++i) { float d = fusion[i] - mu; var += d * d; }
  var *= (1.f / 256.f);
  float inv = rsqrtf(var + 1e-5f);
  float norm = (fusion[t] - mu) * inv * ln_g[t] + ln_b[t];
  __syncthreads();
  fusion[t] = norm;
  __syncthreads();

  if (t < 128) {
    float s = 0.f;
    for (int k = 0; k < 256; ++k) s += fusion[k] * fus_w[k * 128 + t];
    s += fus_b[t];
    fh[t] = fmaxf(s, 0.f);
  }
  __syncthreads();

  if (t < 32) {
    float s = 0.f;
    for (int k = 0; k < 128; ++k) s += fh[k] * task_w[k * 32 + t];
    s += task_b[t];
    out_task[g * 32 + t] = s;
  }
  if (t == 32) {
    float s = 0.f;
    for (int k = 0; k < 128; ++k) s += fh[k] * time_w[k];
    s += time_b[0];
    out_time[g] = s;
  }
}

// ---------------- launch ----------------
extern "C" void kernel_launch(void* const* d_in, const int* in_sizes, int n_in,
                              void* d_out, int out_size, void* d_ws, size_t ws_size,
                              hipStream_t stream)
{
  const float* x        = (const float*)d_in[0];
  const float* doc      = (const float*)d_in[1];
  const int*   ei       = (const int*)d_in[2];
  const int*   batch    = (const int*)d_in[3];
  const float* node_w   = (const float*)d_in[4];
  const float* node_b   = (const float*)d_in[5];
  const float* ggnn_w   = (const float*)d_in[6];
  const float* gru_w_ih = (const float*)d_in[7];
  const float* gru_b_ih = (const float*)d_in[8];
  const float* gru_w_hh = (const float*)d_in[9];
  const float* gru_b_hh = (const float*)d_in[10];
  const float* doc_w    = (const float*)d_in[11];
  const float* doc_b    = (const float*)d_in[12];
  const float* ln_g     = (const float*)d_in[13];
  const float* ln_b     = (const float*)d_in[14];
  const float* fus_w    = (const float*)d_in[15];
  const float* fus_b    = (const float*)d_in[16];
  const float* task_w   = (const float*)d_in[17];
  const float* task_b   = (const float*)d_in[18];
  const float* time_w   = (const float*)d_in[19];
  const float* time_b   = (const float*)d_in[20];

  char* ws = (char*)d_ws;
  size_t off = 0;
  auto alloc = [&](size_t bytes) -> void* {
    void* p = ws + off;
    off = (off + bytes + 255) & ~(size_t)255;
    return p;
  };
  u16* aggb   = (u16*)alloc((size_t)N_NODES * 128 * 2);
  u16* hA     = (u16*)alloc((size_t)N_NODES * 128 * 2);
  u16* hB     = (u16*)alloc((size_t)N_NODES * 128 * 2);
  u16* nwT    = (u16*)alloc(64 * 128 * 2);
  u16* b2p    = (u16*)alloc(3 * 8 * 1536 * 8 * 2);
  float* wp   = (float*)alloc(3 * 128 * 384 * 4);
  float* sums = (float*)alloc(N_GRAPHS * 128 * 4);
  int* counts = (int*)alloc((size_t)N_NODES * 4);
  int* offs   = (int*)alloc((size_t)(N_NODES + 1) * 4);
  int* ssrc   = (int*)alloc((size_t)N_EDGES * 4);
  u16* rankb  = (u16*)alloc((size_t)N_EDGES * 2);
  int* bsum   = (int*)alloc(SCAN_BLOCKS * 4);
  int* bbase  = (int*)alloc(SCAN_BLOCKS * 4);
  int* flags  = (int*)alloc(2 * 4);

  hipMemsetAsync(counts, 0, (size_t)N_NODES * 4, stream);
  hipMemsetAsync(sums, 0, (size_t)N_GRAPHS * 128 * 4, stream);

  detect_i64_kernel<<<1, 64, 0, stream>>>(ei, batch, flags);
  hist_kernel<<<(N_EDGES + 255) / 256, 256, 0, stream>>>(ei, flags, counts, rankb);
  scanA_kernel<<<SCAN_BLOCKS, 1024, 0, stream>>>(counts, bsum);
  scanB_kernel<<<1, 64, 0, stream>>>(bsum, bbase, offs);
  scanC_kernel<<<SCAN_BLOCKS, 1024, 0, stream>>>(counts, bbase, offs);
  scatter_kernel<<<(N_EDGES + 255) / 256, 256, 0, stream>>>(ei, flags, offs, rankb, ssrc);

  transpose_kernel<<<(64 * 128 + 255) / 256, 256, 0, stream>>>(node_w, nwT, 64, 128);
  wprime_kernel<<<(3 * 128 * 384 + 255) / 256, 256, 0, stream>>>(ggnn_w, gru_w_ih, wp);
  for (int l = 0; l < 3; ++l)
    build_b2p_kernel<<<(8 * 1536 * 8 + 255) / 256, 256, 0, stream>>>(
        wp + l * 128 * 384, gru_w_hh, b2p + (size_t)l * 8 * 1536 * 8);

  const int GB = (N_NODES + 63) / 64;    // 1563
  const int GB32 = N_NODES / 32;         // 3125 blocks; 4 waves = 4 col-quarters of one strip
  nodeproj_gemm<<<GB, 256, 0, stream>>>(x, nwT, node_b, hA, N_NODES);

  u16* hcur = hA;
  u16* hnext = hB;
  for (int l = 0; l < 3; ++l) {
    agg_kernel<<<(N_NODES + 3) / 4, 256, 0, stream>>>(hcur, ssrc, offs, aggb);
    gru_gemm<<<GB32, 256, 0, stream>>>(aggb, hcur, b2p + (size_t)l * 8 * 1536 * 8,
                                       gru_b_ih, gru_b_hh, hnext, N_NODES);
    u16* tmp = hcur; hcur = hnext; hnext = tmp;
  }

  pool_kernel<<<(N_NODES + 127) / 128, 256, 0, stream>>>(hcur, batch, flags, sums);

  float* out_task = (float*)d_out;
  float* out_time = out_task + N_GRAPHS * 32;
  head2_kernel<<<N_GRAPHS, 256, 0, stream>>>(sums, batch, flags, doc, doc_w, doc_b, ln_g, ln_b,
                                             fus_w, fus_b, task_w, task_b, time_w, time_b,
                                             out_task, out_time);
}